// Round 4
// baseline (767.837 us; speedup 1.0000x reference)
//
#include <hip/hip_runtime.h>

// ---------------- constants ----------------
#define TT 1000
#define BB 2
#define DD 768
#define HH 12
#define DK 64
#define LL 2
#define WELEM 589824          // 768*768
#define PEROWS 255            // rel positions -127..127

typedef __bf16 bf16x8 __attribute__((ext_vector_type(8)));
typedef float floatx4 __attribute__((ext_vector_type(4)));

__device__ __constant__ int HALFW[12] = {3,7,15,31,63,127,3,7,15,31,63,127};

// ---------------- helpers ----------------
__device__ __forceinline__ float b2f(unsigned short u){
    union { unsigned int i; float f; } x; x.i = ((unsigned int)u) << 16; return x.f;
}
__device__ __forceinline__ unsigned short f2b(float f){
    union { float f; unsigned int i; } x; x.f = f;
    unsigned int i = x.i;
    i += 0x7fffu + ((i >> 16) & 1u);   // RNE
    return (unsigned short)(i >> 16);
}
__device__ __forceinline__ float blo(int w){ union{int i;float f;}x; x.i = w << 16; return x.f; }
__device__ __forceinline__ float bhi(int w){ union{int i;float f;}x; x.i = w & 0xffff0000; return x.f; }

__device__ __forceinline__ float dot8(float4 a0, float4 a1, int4 w){
    return a0.x*blo(w.x) + a0.y*bhi(w.x) + a0.z*blo(w.y) + a0.w*bhi(w.y)
         + a1.x*blo(w.z) + a1.y*bhi(w.z) + a1.z*blo(w.w) + a1.w*bhi(w.w);
}

// ---------------- input dtype detector ----------------
// If d_in[0] is fp32 (N(0,1) data), reading it as bf16 ushorts makes ~37% of
// even-index elements have exponent-field >= 160. If it is true bf16 N(0,1),
// the count is 0. Flag: 1 = inputs are fp32, 0 = inputs are bf16.
__global__ __launch_bounds__(256)
void detect_kernel(const unsigned short* __restrict__ x, int* __restrict__ flag){
    int tid = threadIdx.x;
    int cnt = 0;
    #pragma unroll
    for (int i=0;i<16;++i){
        unsigned short u = x[tid*16 + i];
        int e = (u >> 7) & 0xff;
        if (e >= 160) cnt++;
    }
    #pragma unroll
    for (int o=1;o<64;o<<=1) cnt += __shfl_xor(cnt, o);
    __shared__ int wsum[4];
    if ((tid&63)==0) wsum[tid>>6] = cnt;
    __syncthreads();
    if (tid==0) *flag = (wsum[0]+wsum[1]+wsum[2]+wsum[3] > 64) ? 1 : 0;
}

// ---------------- x scale: input -> fp32 * sqrt(D) ----------------
__global__ __launch_bounds__(256)
void scale_kernel(const int* __restrict__ fl, const void* __restrict__ x,
                  float* __restrict__ xc, int n){
    int fp32 = *fl;
    int i = blockIdx.x*256 + threadIdx.x;
    if (i < n){
        float v = fp32 ? ((const float*)x)[i] : b2f(((const unsigned short*)x)[i]);
        xc[i] = v * 27.712812921102035f;
    }
}

// ---------------- final cast fp32 -> output dtype ----------------
__global__ __launch_bounds__(256)
void cast_kernel(const int* __restrict__ fl, const float* __restrict__ xc,
                 void* __restrict__ o, int n){
    int fp32 = *fl;
    int i = blockIdx.x*256 + threadIdx.x;
    if (i < n){
        if (fp32) ((float*)o)[i] = xc[i];
        else      ((unsigned short*)o)[i] = f2b(xc[i]);
    }
}

// ---------------- pe rows for rel pos 127..-127 (pos = 127-row), bf16 ----------------
__global__ __launch_bounds__(384) void pe_kernel(unsigned short* __restrict__ pe){
    int row = blockIdx.x;            // 0..254
    int i = threadIdx.x;             // 0..383 (pair index)
    float pos = (float)(127 - row);
    float dv = expf((float)(2*i) * (-9.210340371976184f / 768.0f));
    float ang = pos * dv;
    pe[(size_t)row*DD + 2*i]   = f2b(sinf(ang));
    pe[(size_t)row*DD + 2*i+1] = f2b(cosf(ang));
}

// ---------------- LayerNorm: fp32 in -> bf16 out ----------------
__global__ __launch_bounds__(256)
void ln_kernel(const int* __restrict__ fl, const float* __restrict__ x,
               const void* __restrict__ g, const void* __restrict__ bb, long off,
               unsigned short* __restrict__ out){
    int fp32 = *fl;
    int row = blockIdx.x;
    const float* xr = x + (size_t)row*DD;
    int tid = threadIdx.x;
    float v0 = xr[tid], v1 = xr[tid+256], v2 = xr[tid+512];
    float s = v0+v1+v2, ss = v0*v0+v1*v1+v2*v2;
    #pragma unroll
    for (int o=1;o<64;o<<=1){ s += __shfl_xor(s,o); ss += __shfl_xor(ss,o); }
    __shared__ float rs[4], rss[4];
    int wv = tid>>6, lane = tid&63;
    if (lane==0){ rs[wv]=s; rss[wv]=ss; }
    __syncthreads();
    s  = rs[0]+rs[1]+rs[2]+rs[3];
    ss = rss[0]+rss[1]+rss[2]+rss[3];
    float mean = s * (1.0f/768.0f);
    float var  = ss * (1.0f/768.0f) - mean*mean;
    float inv  = 1.0f / sqrtf(var + 1e-5f);
    unsigned short* orow = out + (size_t)row*DD;
    #pragma unroll
    for (int k=0;k<3;++k){
        int i = tid + 256*k;
        float v = (k==0?v0:(k==1?v1:v2));
        float gv = fp32 ? ((const float*)g)[off+i]  : b2f(((const unsigned short*)g)[off+i]);
        float bv = fp32 ? ((const float*)bb)[off+i] : b2f(((const unsigned short*)bb)[off+i]);
        orow[i] = f2b((v - mean)*inv*gv + bv);
    }
}

// ---------------- GEMM: C = A(MxK,bf16) * B(KxN,input dtype) + bias ----------------
// B is in NATURAL (K,N) layout; transposed into LDS during staging.
// MODE 0: store bf16(acc+bias). MODE 1: store bf16(gelu(acc+bias)). MODE 2: resid += acc+bias.
template<int MODE>
__global__ __launch_bounds__(256)
void gemm_kernel(const int* __restrict__ fl, const unsigned short* __restrict__ A,
                 const void* __restrict__ B, long boff,
                 const void* __restrict__ bias, long bioff,
                 unsigned short* __restrict__ outb, float* __restrict__ resid,
                 int M, int N, int K){
    int fp32 = *fl;
    __shared__ __align__(16) unsigned short As[64*40];
    __shared__ __align__(16) unsigned short Bs[64*40];
    int tid = threadIdx.x;
    int m0 = blockIdx.x*64, n0 = blockIdx.y*64;
    int wv = tid>>6, lane = tid&63;
    int quad = lane>>4, l16 = lane&15;
    int r = tid>>2, c = tid&3;       // A staging: 64 rows x 4 chunks of 8
    int kr = tid>>3, c8 = tid&7;     // B staging: 32 k-rows x 8 chunks of 8
    const float*          Bf = (const float*)B + boff;
    const unsigned short* Bh = (const unsigned short*)B + boff;
    floatx4 acc[4] = {{0,0,0,0},{0,0,0,0},{0,0,0,0},{0,0,0,0}};
    for (int k0=0; k0<K; k0+=32){
        int gm = m0 + r;
        int4 av = (gm < M) ? *(const int4*)(A + (size_t)gm*K + k0 + c*8) : make_int4(0,0,0,0);
        *(int4*)(&As[r*40 + c*8]) = av;
        unsigned short bu[8];
        if (fp32){
            const float4* bp = (const float4*)(Bf + (size_t)(k0 + kr)*N + n0 + c8*8);
            float4 f0 = bp[0], f1 = bp[1];
            bu[0]=f2b(f0.x); bu[1]=f2b(f0.y); bu[2]=f2b(f0.z); bu[3]=f2b(f0.w);
            bu[4]=f2b(f1.x); bu[5]=f2b(f1.y); bu[6]=f2b(f1.z); bu[7]=f2b(f1.w);
        } else {
            union { int4 v; unsigned short u[8]; } t;
            t.v = *(const int4*)(Bh + (size_t)(k0 + kr)*N + n0 + c8*8);
            #pragma unroll
            for (int i=0;i<8;++i) bu[i] = t.u[i];
        }
        #pragma unroll
        for (int i=0;i<8;++i) Bs[(c8*8 + i)*40 + kr] = bu[i];   // Bs[n][k]
        __syncthreads();
        bf16x8 af = *(const bf16x8*)(&As[(16*wv + l16)*40 + 8*quad]);
        #pragma unroll
        for (int cc=0; cc<4; ++cc){
            bf16x8 bfv = *(const bf16x8*)(&Bs[(16*cc + l16)*40 + 8*quad]);
            acc[cc] = __builtin_amdgcn_mfma_f32_16x16x32_bf16(af, bfv, acc[cc], 0, 0, 0);
        }
        __syncthreads();
    }
    #pragma unroll
    for (int cc=0; cc<4; ++cc){
        int col = n0 + 16*cc + l16;
        float bf = 0.0f;
        if (bias) bf = fp32 ? ((const float*)bias)[bioff+col] : b2f(((const unsigned short*)bias)[bioff+col]);
        #pragma unroll
        for (int rr=0; rr<4; ++rr){
            int row = m0 + 16*wv + 4*quad + rr;
            if (row < M){
                float v = acc[cc][rr] + bf;
                size_t idx = (size_t)row*N + col;
                if (MODE == 0)      outb[idx] = f2b(v);
                else if (MODE == 1) outb[idx] = f2b(0.5f*v*(1.0f + erff(v*0.70710678118654752f)));
                else                resid[idx] += v;
            }
        }
    }
}

// ---------------- banded rel-pos attention ----------------
__global__ __launch_bounds__(256)
void attn_kernel(const int* __restrict__ fl,
                 const unsigned short* __restrict__ q, const unsigned short* __restrict__ k,
                 const unsigned short* __restrict__ v, const unsigned short* __restrict__ pp,
                 const void* __restrict__ pbu, const void* __restrict__ pbv, long pboff,
                 unsigned short* __restrict__ out){
    int fp32 = *fl;
    int t = blockIdx.x, b = blockIdx.y;
    int wv = threadIdx.x >> 6, lane = threadIdx.x & 63;
    int h = blockIdx.z*4 + wv;
    int w2 = HALFW[h];
    __shared__ __align__(16) float squ[4][64];
    __shared__ __align__(16) float sqv[4][64];
    __shared__ __align__(16) float sa[4][256];
    size_t qidx = (((size_t)(b*TT + t))*HH + h)*DK + lane;
    float qf = b2f(q[qidx]);
    long pi = pboff + h*DK + lane;
    float pbuv = fp32 ? ((const float*)pbu)[pi] : b2f(((const unsigned short*)pbu)[pi]);
    float pbvv = fp32 ? ((const float*)pbv)[pi] : b2f(((const unsigned short*)pbv)[pi]);
    squ[wv][lane] = qf + pbuv;
    sqv[wv][lane] = qf + pbvv;
    __syncthreads();
    const float4* qu4 = (const float4*)squ[wv];
    const float4* qv4 = (const float4*)sqv[wv];
    float scv[4];
    float mx = -INFINITY;
    #pragma unroll
    for (int j=0;j<4;++j){
        scv[j] = -INFINITY;
        if (j*64 <= 2*w2){
            int soff = j*64 + lane;
            int s = t - w2 + soff;
            if (soff <= 2*w2 && s >= 0 && s < TT){
                const int4* kr = (const int4*)(k + (((size_t)(b*TT + s))*HH + h)*DK);
                const int4* pr = (const int4*)(pp + ((size_t)(s - t + 127))*DD + h*DK);
                float acc = 0.0f;
                #pragma unroll
                for (int d8=0; d8<8; ++d8){
                    int4 kk = kr[d8];
                    int4 pq = pr[d8];
                    acc += dot8(qu4[2*d8], qu4[2*d8+1], kk);
                    acc += dot8(qv4[2*d8], qv4[2*d8+1], pq);
                }
                scv[j] = acc * 0.125f;
            }
        }
        mx = fmaxf(mx, scv[j]);
    }
    #pragma unroll
    for (int o=1;o<64;o<<=1) mx = fmaxf(mx, __shfl_xor(mx, o));
    float sum = 0.0f;
    #pragma unroll
    for (int j=0;j<4;++j){
        if (j*64 <= 2*w2){
            float e = expf(scv[j] - mx);   // exp(-inf)=0 for invalid lanes
            sum += e; scv[j] = e;
        }
    }
    #pragma unroll
    for (int o=1;o<64;o<<=1) sum += __shfl_xor(sum, o);
    float rinv = 1.0f / sum;
    #pragma unroll
    for (int j=0;j<4;++j)
        if (j*64 <= 2*w2) sa[wv][j*64 + lane] = scv[j]*rinv;
    __syncthreads();
    float oa = 0.0f;
    int nb = 2*w2;
    for (int sl=0; sl<=nb; ++sl){
        int s = t - w2 + sl;
        int sc = s < 0 ? 0 : (s > TT-1 ? TT-1 : s);
        oa += sa[wv][sl] * b2f(v[(((size_t)(b*TT + sc))*HH + h)*DK + lane]);
    }
    out[qidx] = f2b(oa);
}

// ---------------- launcher ----------------
extern "C" void kernel_launch(void* const* d_in, const int* in_sizes, int n_in,
                              void* d_out, int out_size, void* d_ws, size_t ws_size,
                              hipStream_t stream){
    const void* x    = d_in[0];
    const void* ln1g = d_in[2];
    const void* ln1b = d_in[3];
    const void* wq   = d_in[4];
    const void* bq   = d_in[5];
    const void* wk   = d_in[6];
    const void* bk   = d_in[7];
    const void* wvv  = d_in[8];
    const void* bv   = d_in[9];
    const void* wo   = d_in[10];
    const void* bo   = d_in[11];
    const void* wpos = d_in[12];
    const void* pbu  = d_in[13];
    const void* pbv  = d_in[14];
    const void* ln2g = d_in[15];
    const void* ln2b = d_in[16];
    const void* w1   = d_in[17];
    const void* b1   = d_in[18];
    const void* w2   = d_in[19];
    const void* b2   = d_in[20];

    const int NTOK = BB*TT;            // 2000
    const int NELEM = NTOK*DD;         // 1,536,000

    // ws layout — total ~15.0 MiB
    char* ws = (char*)d_ws;
    float*          x_cur = (float*)ws;                                   // 6,144,000 B
    unsigned short* qbuf  = (unsigned short*)(ws + 6144000);              // q / mlp hidden
    unsigned short* kbuf  = (unsigned short*)(ws + 9216000);
    unsigned short* vbuf  = (unsigned short*)(ws + 12288000);
    unsigned short* ppbuf = (unsigned short*)(ws + 15360000);             // 391,680 B
    int*            dflag = (int*)(ws + 15751680);
    // d_out (>=3,072,000 B) cycles: pe staging -> ln1 out -> attn out -> ln2 out;
    // all dead before the final cast overwrites d_out.
    unsigned short* hbuf  = (unsigned short*)d_out;
    unsigned short* pebuf = (unsigned short*)d_out;

    dim3 blk(256);
    detect_kernel<<<1, blk, 0, stream>>>((const unsigned short*)x, dflag);
    scale_kernel<<<(NELEM+255)/256, blk, 0, stream>>>(dflag, x, x_cur, NELEM);

    dim3 gBig((NTOK+63)/64, DD/64);    // 32 x 12
    dim3 gPe((PEROWS+63)/64, DD/64);   // 4 x 12

    for (int l = 0; l < LL; ++l){
        long wl = (long)l*WELEM;
        long dl = (long)l*DD;
        long pl = (long)l*HH*DK;

        pe_kernel<<<PEROWS, 384, 0, stream>>>(pebuf);
        gemm_kernel<0><<<gPe,  blk, 0, stream>>>(dflag, pebuf, wpos, wl, nullptr, 0, ppbuf, nullptr, PEROWS, DD, DD);

        ln_kernel<<<NTOK, blk, 0, stream>>>(dflag, x_cur, ln1g, ln1b, dl, hbuf);
        gemm_kernel<0><<<gBig, blk, 0, stream>>>(dflag, hbuf, wq, wl, bq, dl, qbuf, nullptr, NTOK, DD, DD);
        gemm_kernel<0><<<gBig, blk, 0, stream>>>(dflag, hbuf, wk, wl, bk, dl, kbuf, nullptr, NTOK, DD, DD);
        gemm_kernel<0><<<gBig, blk, 0, stream>>>(dflag, hbuf, wvv, wl, bv, dl, vbuf, nullptr, NTOK, DD, DD);

        attn_kernel<<<dim3(TT, BB, 3), blk, 0, stream>>>(dflag, qbuf, kbuf, vbuf, ppbuf,
                                                         pbu, pbv, pl, hbuf);

        gemm_kernel<2><<<gBig, blk, 0, stream>>>(dflag, hbuf, wo, wl, bo, dl, nullptr, x_cur, NTOK, DD, DD);

        ln_kernel<<<NTOK, blk, 0, stream>>>(dflag, x_cur, ln2g, ln2b, dl, hbuf);
        gemm_kernel<1><<<gBig, blk, 0, stream>>>(dflag, hbuf, w1, wl, b1, dl, qbuf, nullptr, NTOK, DD, DD);
        gemm_kernel<2><<<gBig, blk, 0, stream>>>(dflag, qbuf, w2, wl, b2, dl, nullptr, x_cur, NTOK, DD, DD);
    }
    cast_kernel<<<(NELEM+255)/256, blk, 0, stream>>>(dflag, x_cur, d_out, NELEM);
}

// Round 5
// 583.523 us; speedup vs baseline: 1.3159x; 1.3159x over previous
//
#include <hip/hip_runtime.h>

// ---------------- constants ----------------
#define TT 1000
#define BB 2
#define DD 768
#define HH 12
#define DK 64
#define LL 2
#define WELEM 589824          // 768*768
#define PEROWS 255            // rel positions -127..127

typedef __bf16 bf16x8 __attribute__((ext_vector_type(8)));
typedef float floatx4 __attribute__((ext_vector_type(4)));

__device__ __constant__ int HALFW[12] = {3,7,15,31,63,127,3,7,15,31,63,127};

// ---------------- helpers ----------------
__device__ __forceinline__ float b2f(unsigned short u){
    union { unsigned int i; float f; } x; x.i = ((unsigned int)u) << 16; return x.f;
}
__device__ __forceinline__ unsigned short f2b(float f){
    union { float f; unsigned int i; } x; x.f = f;
    unsigned int i = x.i;
    i += 0x7fffu + ((i >> 16) & 1u);   // RNE
    return (unsigned short)(i >> 16);
}
__device__ __forceinline__ float blo(int w){ union{int i;float f;}x; x.i = w << 16; return x.f; }
__device__ __forceinline__ float bhi(int w){ union{int i;float f;}x; x.i = w & 0xffff0000; return x.f; }

__device__ __forceinline__ float dot8(float4 a0, float4 a1, int4 w){
    return a0.x*blo(w.x) + a0.y*bhi(w.x) + a0.z*blo(w.y) + a0.w*bhi(w.y)
         + a1.x*blo(w.z) + a1.y*bhi(w.z) + a1.z*blo(w.w) + a1.w*bhi(w.w);
}

// ---------------- x scale: fp32 in -> fp32 * sqrt(D), into d_out (residual) ----------------
__global__ __launch_bounds__(256)
void scale_kernel(const float* __restrict__ x, float* __restrict__ xc, int n){
    int i = blockIdx.x*256 + threadIdx.x;
    if (i < n) xc[i] = x[i] * 27.712812921102035f;
}

// ---------------- pe rows for rel pos 127..-127 (pos = 127-row), bf16 ----------------
__global__ __launch_bounds__(384) void pe_kernel(unsigned short* __restrict__ pe){
    int row = blockIdx.x;            // 0..254
    int i = threadIdx.x;             // 0..383 (pair index)
    float pos = (float)(127 - row);
    float dv = expf((float)(2*i) * (-9.210340371976184f / 768.0f));
    float ang = pos * dv;
    pe[(size_t)row*DD + 2*i]   = f2b(sinf(ang));
    pe[(size_t)row*DD + 2*i+1] = f2b(cosf(ang));
}

// ---------------- weight convert+transpose: fp32 (K,N) -> bf16 (N,K) ----------------
__global__ __launch_bounds__(256)
void wconv_kernel(const float* s0, const float* s1, const float* s2, const float* s3,
                  const float* s4, const float* s5, const float* s6, long loff,
                  unsigned short* __restrict__ dst){
    const float* srcs[7] = {s0,s1,s2,s3,s4,s5,s6};
    int z = blockIdx.z;
    const float* src = srcs[z] + loff;
    unsigned short* d = dst + (size_t)z*WELEM;
    int k0 = blockIdx.x*64, n0 = blockIdx.y*64;
    __shared__ __align__(16) unsigned short tile[64][72];
    int r = threadIdx.x >> 2, c = threadIdx.x & 3;
    const float4* sp = (const float4*)(src + (size_t)(k0+r)*DD + n0 + c*16);
    float4 f0 = sp[0], f1 = sp[1], f2 = sp[2], f3 = sp[3];
    unsigned short u[16];
    u[0]=f2b(f0.x); u[1]=f2b(f0.y); u[2]=f2b(f0.z); u[3]=f2b(f0.w);
    u[4]=f2b(f1.x); u[5]=f2b(f1.y); u[6]=f2b(f1.z); u[7]=f2b(f1.w);
    u[8]=f2b(f2.x); u[9]=f2b(f2.y); u[10]=f2b(f2.z); u[11]=f2b(f2.w);
    u[12]=f2b(f3.x); u[13]=f2b(f3.y); u[14]=f2b(f3.z); u[15]=f2b(f3.w);
    *(int4*)&tile[r][c*16]   = *(int4*)&u[0];
    *(int4*)&tile[r][c*16+8] = *(int4*)&u[8];
    __syncthreads();
    unsigned short tmp[16];
    #pragma unroll
    for (int i=0;i<16;++i) tmp[i] = tile[c*16+i][r];
    int4* dp = (int4*)(d + (size_t)(n0+r)*DD + k0 + c*16);
    dp[0] = *(int4*)&tmp[0];
    dp[1] = *(int4*)&tmp[8];
}

// ---------------- LayerNorm: fp32 in -> bf16 out ----------------
__global__ __launch_bounds__(256)
void ln_kernel(const float* __restrict__ x, const float* __restrict__ g,
               const float* __restrict__ bb, unsigned short* __restrict__ out){
    int row = blockIdx.x;
    const float* xr = x + (size_t)row*DD;
    int tid = threadIdx.x;
    float v0 = xr[tid], v1 = xr[tid+256], v2 = xr[tid+512];
    float s = v0+v1+v2, ss = v0*v0+v1*v1+v2*v2;
    #pragma unroll
    for (int o=1;o<64;o<<=1){ s += __shfl_xor(s,o); ss += __shfl_xor(ss,o); }
    __shared__ float rs[4], rss[4];
    int wv = tid>>6, lane = tid&63;
    if (lane==0){ rs[wv]=s; rss[wv]=ss; }
    __syncthreads();
    s  = rs[0]+rs[1]+rs[2]+rs[3];
    ss = rss[0]+rss[1]+rss[2]+rss[3];
    float mean = s * (1.0f/768.0f);
    float var  = ss * (1.0f/768.0f) - mean*mean;
    float inv  = 1.0f / sqrtf(var + 1e-5f);
    unsigned short* orow = out + (size_t)row*DD;
    #pragma unroll
    for (int kk=0;kk<3;++kk){
        int i = tid + 256*kk;
        float v = (kk==0?v0:(kk==1?v1:v2));
        orow[i] = f2b((v - mean)*inv*g[i] + bb[i]);
    }
}

// ---------------- GEMM: C = A(Mx768,bf16) * Bt(768x768,bf16,(N,K)) + bias ----------------
// MODE 0: store bf16. MODE 1: store bf16(gelu). MODE 2: resid += . MODE 3: permuted (b,h,r,d) bf16.
template<int MODE>
__global__ __launch_bounds__(256)
void gemm_kernel(const unsigned short* __restrict__ A, const unsigned short* __restrict__ Bt,
                 const float* __restrict__ bias, unsigned short* __restrict__ outb,
                 float* __restrict__ resid, int M, int rpb){
    __shared__ __align__(16) unsigned short As[128*32];
    __shared__ __align__(16) unsigned short Bs[64*32];
    int tid = threadIdx.x;
    int m0 = blockIdx.x*128, n0 = blockIdx.y*64;
    int wv = tid>>6, lane = tid&63;
    int quad = lane>>4, l16 = lane&15;
    int ar = tid>>2;            // 0..63
    int ac = (tid&3)*8;         // k-elem offset {0,8,16,24}
    floatx4 acc[2][4];
    #pragma unroll
    for (int mi=0;mi<2;++mi)
        #pragma unroll
        for (int ni=0;ni<4;++ni) acc[mi][ni] = (floatx4){0.f,0.f,0.f,0.f};
    const unsigned short* Bp = Bt + (size_t)n0*768;
    int r0 = m0 + ar;       if (r0 > M-1) r0 = M-1;
    int r1 = m0 + 64 + ar;  if (r1 > M-1) r1 = M-1;
    const unsigned short* Ap0 = A + (size_t)r0*768 + ac;
    const unsigned short* Ap1 = A + (size_t)r1*768 + ac;
    const unsigned short* Bpp = Bp + (size_t)ar*768 + ac;
    for (int k0=0; k0<768; k0+=32){
        int4 a0 = *(const int4*)(Ap0 + k0);
        int4 a1 = *(const int4*)(Ap1 + k0);
        int4 b0 = *(const int4*)(Bpp + k0);
        *(int4*)&As[ar*32 + ac]      = a0;
        *(int4*)&As[(64+ar)*32 + ac] = a1;
        *(int4*)&Bs[ar*32 + ac]      = b0;
        __syncthreads();
        #pragma unroll
        for (int mi=0; mi<2; ++mi){
            bf16x8 af = *(const bf16x8*)&As[(32*wv + 16*mi + l16)*32 + 8*quad];
            #pragma unroll
            for (int ni=0; ni<4; ++ni){
                bf16x8 bfv = *(const bf16x8*)&Bs[(16*ni + l16)*32 + 8*quad];
                acc[mi][ni] = __builtin_amdgcn_mfma_f32_16x16x32_bf16(af, bfv, acc[mi][ni], 0, 0, 0);
            }
        }
        __syncthreads();
    }
    float bfv_[4];
    #pragma unroll
    for (int ni=0;ni<4;++ni) bfv_[ni] = bias ? bias[n0 + 16*ni + l16] : 0.0f;
    #pragma unroll
    for (int mi=0;mi<2;++mi){
        #pragma unroll
        for (int rr=0;rr<4;++rr){
            int row = m0 + 32*wv + 16*mi + 4*quad + rr;
            if (row >= M) continue;
            int bb_ = 0, r_ = row;
            if (MODE == 3){ bb_ = row / rpb; r_ = row - bb_*rpb; }
            #pragma unroll
            for (int ni=0;ni<4;++ni){
                int col = n0 + 16*ni + l16;
                float v = acc[mi][ni][rr] + bfv_[ni];
                if (MODE == 0)      outb[(size_t)row*768 + col] = f2b(v);
                else if (MODE == 1) outb[(size_t)row*768 + col] = f2b(0.5f*v*(1.0f + erff(v*0.70710678118654752f)));
                else if (MODE == 2) resid[(size_t)row*768 + col] += v;
                else {
                    int h = col >> 6, d = col & 63;
                    outb[(((size_t)(bb_*HH + h))*rpb + r_)*DK + d] = f2b(v);
                }
            }
        }
    }
}

// ---------------- banded rel-pos attention ----------------
// block = 4 waves, same head, 4 consecutive t. q/k/v in (b,h,t,d); pp in (h,n,d).
__global__ __launch_bounds__(256)
void attn_kernel(const unsigned short* __restrict__ q, const unsigned short* __restrict__ k,
                 const unsigned short* __restrict__ v, const unsigned short* __restrict__ pp,
                 const float* __restrict__ pbu, const float* __restrict__ pbv,
                 unsigned short* __restrict__ out){
    int b = blockIdx.y, h = blockIdx.z;
    int wv = threadIdx.x >> 6, lane = threadIdx.x & 63;
    int t = blockIdx.x*4 + wv;
    int w2 = HALFW[h];
    const unsigned short* kB = k + ((size_t)(b*HH + h))*TT*DK;
    const unsigned short* vB = v + ((size_t)(b*HH + h))*TT*DK;
    const unsigned short* qB = q + ((size_t)(b*HH + h))*TT*DK;
    const unsigned short* pB = pp + (size_t)h*PEROWS*DK;
    __shared__ __align__(16) float squ[4][64];
    __shared__ __align__(16) float sqv[4][64];
    __shared__ __align__(16) float sa[4][256];
    float qf = b2f(qB[(size_t)t*DK + lane]);
    squ[wv][lane] = qf + pbu[h*DK + lane];
    sqv[wv][lane] = qf + pbv[h*DK + lane];
    __syncthreads();
    const float4* qu4 = (const float4*)squ[wv];
    const float4* qv4 = (const float4*)sqv[wv];
    int nb = 2*w2;
    float scv[4];
    float mx = -INFINITY;
    #pragma unroll
    for (int j=0;j<4;++j){
        scv[j] = -INFINITY;
        if (j*64 <= nb){
            int soff = j*64 + lane;
            int s = t - w2 + soff;
            if (soff <= nb && s >= 0 && s < TT){
                const int4* kr = (const int4*)(kB + (size_t)s*DK);
                const int4* pr = (const int4*)(pB + (size_t)(s - t + 127)*DK);
                float acc = 0.0f;
                #pragma unroll
                for (int d8=0; d8<8; ++d8){
                    int4 kk = kr[d8];
                    int4 pq = pr[d8];
                    acc += dot8(qu4[2*d8], qu4[2*d8+1], kk);
                    acc += dot8(qv4[2*d8], qv4[2*d8+1], pq);
                }
                scv[j] = acc * 0.125f;
            }
        }
        mx = fmaxf(mx, scv[j]);
    }
    #pragma unroll
    for (int o=1;o<64;o<<=1) mx = fmaxf(mx, __shfl_xor(mx, o));
    float sum = 0.0f;
    #pragma unroll
    for (int j=0;j<4;++j){
        if (j*64 <= nb){
            float e = expf(scv[j] - mx);   // exp(-inf)=0 for invalid lanes
            sum += e; scv[j] = e;
        }
    }
    #pragma unroll
    for (int o=1;o<64;o<<=1) sum += __shfl_xor(sum, o);
    float rinv = 1.0f / sum;
    #pragma unroll
    for (int j=0;j<4;++j)
        if (j*64 <= nb) sa[wv][j*64 + lane] = scv[j]*rinv;
    __syncthreads();
    // PV over valid band only (probs outside are zero), 4 accumulators
    int slo = (t < w2) ? (w2 - t) : 0;
    int shi = (t + w2 > TT-1) ? (w2 + (TT-1) - t) : nb;
    const float* saw = sa[wv];
    const unsigned short* vr0 = vB + (size_t)(t - w2)*DK + lane;
    float oa0=0.f, oa1=0.f, oa2=0.f, oa3=0.f;
    int sl = slo;
    for (; sl + 3 <= shi; sl += 4){
        const unsigned short* vr = vr0 + (size_t)sl*DK;
        oa0 += saw[sl]   * b2f(vr[0]);
        oa1 += saw[sl+1] * b2f(vr[DK]);
        oa2 += saw[sl+2] * b2f(vr[2*DK]);
        oa3 += saw[sl+3] * b2f(vr[3*DK]);
    }
    for (; sl <= shi; ++sl)
        oa0 += saw[sl] * b2f(vr0[(size_t)sl*DK]);
    float oa = (oa0 + oa1) + (oa2 + oa3);
    // token-major output for the o-proj GEMM
    out[(((size_t)(b*TT + t))*HH + h)*DK + lane] = f2b(oa);
}

// ---------------- launcher ----------------
extern "C" void kernel_launch(void* const* d_in, const int* in_sizes, int n_in,
                              void* d_out, int out_size, void* d_ws, size_t ws_size,
                              hipStream_t stream){
    const float* x    = (const float*)d_in[0];
    const float* ln1g = (const float*)d_in[2];
    const float* ln1b = (const float*)d_in[3];
    const float* wq   = (const float*)d_in[4];
    const float* bq   = (const float*)d_in[5];
    const float* wk   = (const float*)d_in[6];
    const float* bk   = (const float*)d_in[7];
    const float* wvv  = (const float*)d_in[8];
    const float* bv   = (const float*)d_in[9];
    const float* wo   = (const float*)d_in[10];
    const float* bo   = (const float*)d_in[11];
    const float* wpos = (const float*)d_in[12];
    const float* pbu  = (const float*)d_in[13];
    const float* pbv  = (const float*)d_in[14];
    const float* ln2g = (const float*)d_in[15];
    const float* ln2b = (const float*)d_in[16];
    const float* w1   = (const float*)d_in[17];
    const float* b1   = (const float*)d_in[18];
    const float* w2   = (const float*)d_in[19];
    const float* b2   = (const float*)d_in[20];

    const int NTOK = BB*TT;            // 2000
    const int NELEM = NTOK*DD;         // 1,536,000

    // residual stream lives directly in d_out (fp32, 6,144,000 B)
    float* x_cur = (float*)d_out;

    // ws layout — total 20,937,216 B (~20.0 MiB)
    char* ws = (char*)d_ws;
    unsigned short* qbuf  = (unsigned short*)(ws);             // (b,h,t,d) q / mlp hidden
    unsigned short* kbuf  = (unsigned short*)(ws + 3072000);   // (b,h,t,d)
    unsigned short* vbuf  = (unsigned short*)(ws + 6144000);   // (b,h,t,d)
    unsigned short* hbuf  = (unsigned short*)(ws + 9216000);   // pe / ln out / attn out
    unsigned short* ppbuf = (unsigned short*)(ws + 12288000);  // (h,n,d) 391,680 B
    unsigned short* wtbuf = (unsigned short*)(ws + 12679680);  // 7 * 1,179,648 B
    #define WT(t_) (wtbuf + (size_t)(t_)*WELEM)

    dim3 blk(256);
    scale_kernel<<<(NELEM+255)/256, blk, 0, stream>>>(x, x_cur, NELEM);

    dim3 gBig(16, 12);                 // M=2000 tiles of 128
    dim3 gPe(2, 12);                   // M=255
    dim3 gW(12, 12, 7);

    for (int l = 0; l < LL; ++l){
        long wl = (long)l*WELEM;
        long dl = (long)l*DD;
        long pl = (long)l*HH*DK;

        wconv_kernel<<<gW, blk, 0, stream>>>(wq, wk, wvv, wo, wpos, w1, w2, wl, wtbuf);

        pe_kernel<<<PEROWS, 384, 0, stream>>>(hbuf);
        gemm_kernel<3><<<gPe, blk, 0, stream>>>(hbuf, WT(4), nullptr, ppbuf, nullptr, PEROWS, PEROWS);

        ln_kernel<<<NTOK, blk, 0, stream>>>(x_cur, ln1g + dl, ln1b + dl, hbuf);
        gemm_kernel<3><<<gBig, blk, 0, stream>>>(hbuf, WT(0), bq + dl, qbuf, nullptr, NTOK, TT);
        gemm_kernel<3><<<gBig, blk, 0, stream>>>(hbuf, WT(1), bk + dl, kbuf, nullptr, NTOK, TT);
        gemm_kernel<3><<<gBig, blk, 0, stream>>>(hbuf, WT(2), bv + dl, vbuf, nullptr, NTOK, TT);

        attn_kernel<<<dim3(TT/4, BB, HH), blk, 0, stream>>>(qbuf, kbuf, vbuf, ppbuf,
                                                            pbu + pl, pbv + pl, hbuf);

        gemm_kernel<2><<<gBig, blk, 0, stream>>>(hbuf, WT(3), bo + dl, nullptr, x_cur, NTOK, TT);

        ln_kernel<<<NTOK, blk, 0, stream>>>(x_cur, ln2g + dl, ln2b + dl, hbuf);
        gemm_kernel<1><<<gBig, blk, 0, stream>>>(hbuf, WT(5), b1 + dl, qbuf, nullptr, NTOK, TT);
        gemm_kernel<2><<<gBig, blk, 0, stream>>>(qbuf, WT(6), b2 + dl, nullptr, x_cur, NTOK, TT);
    }
}

// Round 6
// 501.872 us; speedup vs baseline: 1.5299x; 1.1627x over previous
//
#include <hip/hip_runtime.h>

// ---------------- constants ----------------
#define TT 1000
#define BB 2
#define DD 768
#define HH 12
#define DK 64
#define LL 2
#define WELEM 589824          // 768*768
#define PEROWS 255            // rel positions -127..127
#define TPAD 1024             // t-stride in kT layout
#define NPAD 256              // n-stride in ppT layout

typedef __bf16 bf16x8 __attribute__((ext_vector_type(8)));
typedef float floatx4 __attribute__((ext_vector_type(4)));

__device__ __constant__ int HALFW[12] = {3,7,15,31,63,127,3,7,15,31,63,127};

// ---------------- helpers ----------------
__device__ __forceinline__ float b2f(unsigned short u){
    union { unsigned int i; float f; } x; x.i = ((unsigned int)u) << 16; return x.f;
}
__device__ __forceinline__ unsigned short f2b(float f){
    union { float f; unsigned int i; } x; x.f = f;
    unsigned int i = x.i;
    i += 0x7fffu + ((i >> 16) & 1u);   // RNE
    return (unsigned short)(i >> 16);
}

// ---------------- x scale ----------------
__global__ __launch_bounds__(256)
void scale_kernel(const float* __restrict__ x, float* __restrict__ xc, int n){
    int i = blockIdx.x*256 + threadIdx.x;
    if (i < n) xc[i] = x[i] * 27.712812921102035f;
}

// ---------------- pe rows (pos = 127-row), bf16 ----------------
__global__ __launch_bounds__(384) void pe_kernel(unsigned short* __restrict__ pe){
    int row = blockIdx.x;
    int i = threadIdx.x;
    float pos = (float)(127 - row);
    float dv = expf((float)(2*i) * (-9.210340371976184f / 768.0f));
    float ang = pos * dv;
    pe[(size_t)row*DD + 2*i]   = f2b(sinf(ang));
    pe[(size_t)row*DD + 2*i+1] = f2b(cosf(ang));
}

// ---------------- weight convert+transpose: fp32 (K,N) -> bf16 (N,K) ----------------
__global__ __launch_bounds__(256)
void wconv_kernel(const float* s0, const float* s1, const float* s2, const float* s3,
                  const float* s4, const float* s5, const float* s6, long loff,
                  unsigned short* __restrict__ dst){
    const float* srcs[7] = {s0,s1,s2,s3,s4,s5,s6};
    int z = blockIdx.z;
    const float* src = srcs[z] + loff;
    unsigned short* d = dst + (size_t)z*WELEM;
    int k0 = blockIdx.x*64, n0 = blockIdx.y*64;
    __shared__ __align__(16) unsigned short tile[64][72];
    int r = threadIdx.x >> 2, c = threadIdx.x & 3;
    const float4* sp = (const float4*)(src + (size_t)(k0+r)*DD + n0 + c*16);
    float4 f0 = sp[0], f1 = sp[1], f2 = sp[2], f3 = sp[3];
    unsigned short u[16];
    u[0]=f2b(f0.x); u[1]=f2b(f0.y); u[2]=f2b(f0.z); u[3]=f2b(f0.w);
    u[4]=f2b(f1.x); u[5]=f2b(f1.y); u[6]=f2b(f1.z); u[7]=f2b(f1.w);
    u[8]=f2b(f2.x); u[9]=f2b(f2.y); u[10]=f2b(f2.z); u[11]=f2b(f2.w);
    u[12]=f2b(f3.x); u[13]=f2b(f3.y); u[14]=f2b(f3.z); u[15]=f2b(f3.w);
    *(int4*)&tile[r][c*16]   = *(int4*)&u[0];
    *(int4*)&tile[r][c*16+8] = *(int4*)&u[8];
    __syncthreads();
    unsigned short tmp[16];
    #pragma unroll
    for (int i=0;i<16;++i) tmp[i] = tile[c*16+i][r];
    int4* dp = (int4*)(d + (size_t)(n0+r)*DD + k0 + c*16);
    dp[0] = *(int4*)&tmp[0];
    dp[1] = *(int4*)&tmp[8];
}

// ---------------- LayerNorm: fp32 in -> bf16 out ----------------
__global__ __launch_bounds__(256)
void ln_kernel(const float* __restrict__ x, const float* __restrict__ g,
               const float* __restrict__ bb, unsigned short* __restrict__ out){
    int row = blockIdx.x;
    const float* xr = x + (size_t)row*DD;
    int tid = threadIdx.x;
    float v0 = xr[tid], v1 = xr[tid+256], v2 = xr[tid+512];
    float s = v0+v1+v2, ss = v0*v0+v1*v1+v2*v2;
    #pragma unroll
    for (int o=1;o<64;o<<=1){ s += __shfl_xor(s,o); ss += __shfl_xor(ss,o); }
    __shared__ float rs[4], rss[4];
    int wv = tid>>6, lane = tid&63;
    if (lane==0){ rs[wv]=s; rss[wv]=ss; }
    __syncthreads();
    s  = rs[0]+rs[1]+rs[2]+rs[3];
    ss = rss[0]+rss[1]+rss[2]+rss[3];
    float mean = s * (1.0f/768.0f);
    float var  = ss * (1.0f/768.0f) - mean*mean;
    float inv  = 1.0f / sqrtf(var + 1e-5f);
    unsigned short* orow = out + (size_t)row*DD;
    #pragma unroll
    for (int kk=0;kk<3;++kk){
        int i = tid + 256*kk;
        float v = (kk==0?v0:(kk==1?v1:v2));
        orow[i] = f2b((v - mean)*inv*g[i] + bb[i]);
    }
}

// ======== GEMM core macro: 128x64 tile, acc[2][4], A(Mx768) * Bt(rows n0..n0+63 of (N,768)) ========
#define GEMM_CORE(A_, Bt_, n0_, M_)                                              \
    int tid = threadIdx.x;                                                       \
    int m0 = blockIdx.x*128;                                                     \
    int wv = tid>>6, lane = tid&63;                                              \
    int quad = lane>>4, l16 = lane&15;                                           \
    int ar = tid>>2;                                                             \
    int ac = (tid&3)*8;                                                          \
    floatx4 acc[2][4];                                                           \
    _Pragma("unroll")                                                            \
    for (int mi=0;mi<2;++mi)                                                     \
        _Pragma("unroll")                                                        \
        for (int ni=0;ni<4;++ni) acc[mi][ni] = (floatx4){0.f,0.f,0.f,0.f};       \
    {                                                                            \
        const unsigned short* Bp = (Bt_) + (size_t)(n0_)*768;                    \
        int r0 = m0 + ar;       if (r0 > (M_)-1) r0 = (M_)-1;                    \
        int r1 = m0 + 64 + ar;  if (r1 > (M_)-1) r1 = (M_)-1;                    \
        const unsigned short* Ap0 = (A_) + (size_t)r0*768 + ac;                  \
        const unsigned short* Ap1 = (A_) + (size_t)r1*768 + ac;                  \
        const unsigned short* Bpp = Bp + (size_t)ar*768 + ac;                    \
        for (int k0=0; k0<768; k0+=32){                                          \
            int4 a0 = *(const int4*)(Ap0 + k0);                                  \
            int4 a1 = *(const int4*)(Ap1 + k0);                                  \
            int4 b0 = *(const int4*)(Bpp + k0);                                  \
            *(int4*)&As[ar*32 + ac]      = a0;                                   \
            *(int4*)&As[(64+ar)*32 + ac] = a1;                                   \
            *(int4*)&Bs[ar*32 + ac]      = b0;                                   \
            __syncthreads();                                                     \
            _Pragma("unroll")                                                    \
            for (int mi=0; mi<2; ++mi){                                          \
                bf16x8 af = *(const bf16x8*)&As[(32*wv + 16*mi + l16)*32 + 8*quad]; \
                _Pragma("unroll")                                                \
                for (int ni=0; ni<4; ++ni){                                      \
                    bf16x8 bfv = *(const bf16x8*)&Bs[(16*ni + l16)*32 + 8*quad]; \
                    acc[mi][ni] = __builtin_amdgcn_mfma_f32_16x16x32_bf16(af, bfv, acc[mi][ni], 0, 0, 0); \
                }                                                                \
            }                                                                    \
            __syncthreads();                                                     \
        }                                                                        \
    }

// ---------------- standalone GEMM (N=768): MODE 1 gelu bf16, MODE 2 resid+=, MODE 4 ppT scatter ----------------
template<int MODE>
__global__ __launch_bounds__(256)
void gemm_kernel(const unsigned short* __restrict__ A, const unsigned short* __restrict__ Bt,
                 const float* __restrict__ bias, unsigned short* __restrict__ outb,
                 float* __restrict__ resid, int M){
    __shared__ __align__(16) unsigned short As[128*32];
    __shared__ __align__(16) unsigned short Bs[64*32];
    int n0 = blockIdx.y*64;
    GEMM_CORE(A, Bt, n0, M)
    float bfv_[4];
    #pragma unroll
    for (int ni=0;ni<4;++ni) bfv_[ni] = bias ? bias[n0 + 16*ni + l16] : 0.0f;
    #pragma unroll
    for (int mi=0;mi<2;++mi){
        #pragma unroll
        for (int rr=0;rr<4;++rr){
            int row = m0 + 32*wv + 16*mi + 4*quad + rr;
            if (row >= M) continue;
            #pragma unroll
            for (int ni=0;ni<4;++ni){
                int col = n0 + 16*ni + l16;
                float v = acc[mi][ni][rr] + bfv_[ni];
                if (MODE == 1)      outb[(size_t)row*768 + col] = f2b(0.5f*v*(1.0f + erff(v*0.70710678118654752f)));
                else if (MODE == 2) resid[(size_t)row*768 + col] += v;
                else                outb[(size_t)col*NPAD + row] = f2b(v);   // ppT (h*64+d, n)
            }
        }
    }
}

// ---------------- fused QKV GEMM (N=2304): q,v -> (b,h,t,d); k -> (b,h,d,t) via LDS transpose ----------------
__global__ __launch_bounds__(256)
void gemm_qkv_kernel(const unsigned short* __restrict__ A, const unsigned short* __restrict__ Bt,
                     const float* __restrict__ bq, const float* __restrict__ bk, const float* __restrict__ bv,
                     unsigned short* __restrict__ qout, unsigned short* __restrict__ kout,
                     unsigned short* __restrict__ vout){
    __shared__ __align__(16) unsigned short sh[10240];   // As 128*32 | Bs 64*32 ; reused as 128x66 transpose
    unsigned short* As = sh;
    unsigned short* Bs = sh + 128*32;
    int n0 = blockIdx.y*64;
    GEMM_CORE(A, Bt, n0, 2000)
    int sec = blockIdx.y / 12;            // 0=q 1=k 2=v
    int col0 = n0 - sec*768;              // multiple of 64
    int h = col0 >> 6;
    const float* bias = (sec==0) ? bq : (sec==1) ? bk : bv;
    float bfv_[4];
    #pragma unroll
    for (int ni=0;ni<4;++ni) bfv_[ni] = bias[col0 + 16*ni + l16];
    if (sec != 1){
        unsigned short* outp = (sec==0) ? qout : vout;
        #pragma unroll
        for (int mi=0;mi<2;++mi){
            #pragma unroll
            for (int rr=0;rr<4;++rr){
                int row = m0 + 32*wv + 16*mi + 4*quad + rr;
                if (row >= 2000) continue;
                int b = row / TT, tl = row - b*TT;
                #pragma unroll
                for (int ni=0;ni<4;++ni){
                    int d = 16*ni + l16;
                    outp[(((size_t)(b*HH + h))*TT + tl)*DK + d] = f2b(acc[mi][ni][rr] + bfv_[ni]);
                }
            }
        }
    } else {
        // K: write acc tile to LDS (stride 66, conflict-free readback), then coalesced (d,t) store
        #pragma unroll
        for (int mi=0;mi<2;++mi)
            #pragma unroll
            for (int rr=0;rr<4;++rr){
                int rt = 32*wv + 16*mi + 4*quad + rr;
                #pragma unroll
                for (int ni=0;ni<4;++ni)
                    sh[rt*66 + 16*ni + l16] = f2b(acc[mi][ni][rr] + bfv_[ni]);
            }
        __syncthreads();
        unsigned short* kB = kout + ((size_t)h)*DK*TPAD;   // + b*HH*DK*TPAD per row
        #pragma unroll
        for (int it=0; it<32; ++it){
            int idx = it*256 + tid;
            int d = idx >> 7, rt = idx & 127;
            int row = m0 + rt;
            if (row < 2000){
                int b = row / TT, tl = row - b*TT;
                kB[((size_t)(b*HH*DK) + d)*TPAD + tl] = sh[rt*66 + d];
            }
        }
    }
}

// ---------------- banded rel-pos attention, coalesced score loads ----------------
// block = 4 waves, same head, 4 consecutive t. q/v in (b,h,t,d); kT in (b,h,d,t); ppT in (h,d,n).
__global__ __launch_bounds__(256)
void attn_kernel(const unsigned short* __restrict__ q, const unsigned short* __restrict__ kT,
                 const unsigned short* __restrict__ v, const unsigned short* __restrict__ ppT,
                 const float* __restrict__ pbu, const float* __restrict__ pbv,
                 unsigned short* __restrict__ out){
    int b = blockIdx.y, h = blockIdx.z;
    int wv = threadIdx.x >> 6, lane = threadIdx.x & 63;
    int t = blockIdx.x*4 + wv;
    int w2 = HALFW[h];
    const unsigned short* qB = q  + ((size_t)(b*HH + h))*TT*DK;
    const unsigned short* vB = v  + ((size_t)(b*HH + h))*TT*DK;
    const unsigned short* kB = kT + ((size_t)(b*HH + h))*DK*TPAD;  // [d][t]
    const unsigned short* pB = ppT + (size_t)h*DK*NPAD;            // [d][n]
    __shared__ __align__(16) float squ[4][64];
    __shared__ __align__(16) float sqv[4][64];
    __shared__ __align__(16) float sa[4][256];
    float qf = b2f(qB[(size_t)t*DK + lane]);
    squ[wv][lane] = qf + pbu[h*DK + lane];
    sqv[wv][lane] = qf + pbv[h*DK + lane];
    __syncthreads();
    const float4* U4 = (const float4*)squ[wv];
    const float4* V4 = (const float4*)sqv[wv];
    int nb = 2*w2;
    float scv[4];
    float mx = -INFINITY;
    #pragma unroll
    for (int j=0;j<4;++j){
        scv[j] = -INFINITY;
        if (j*64 <= nb){
            int soff = j*64 + lane;
            int s = t - w2 + soff;
            if (soff <= nb && s >= 0 && s < TT){
                int n = s - t + 127;
                const unsigned short* kp = kB + s;   // lane-consecutive s -> coalesced
                const unsigned short* pq = pB + n;   // lane-consecutive n -> coalesced
                float a1 = 0.0f, a2 = 0.0f;
                #pragma unroll 4
                for (int d4=0; d4<16; ++d4){
                    float4 u  = U4[d4];
                    float4 vv = V4[d4];
                    const unsigned short* kpp = kp + (d4 << 12);   // d4*4*TPAD
                    const unsigned short* pqq = pq + (d4 << 10);   // d4*4*NPAD
                    a1 += u.x*b2f(kpp[0])      + u.y*b2f(kpp[TPAD])
                        + u.z*b2f(kpp[2*TPAD]) + u.w*b2f(kpp[3*TPAD]);
                    a2 += vv.x*b2f(pqq[0])      + vv.y*b2f(pqq[NPAD])
                        + vv.z*b2f(pqq[2*NPAD]) + vv.w*b2f(pqq[3*NPAD]);
                }
                scv[j] = (a1 + a2) * 0.125f;
            }
        }
        mx = fmaxf(mx, scv[j]);
    }
    #pragma unroll
    for (int o=1;o<64;o<<=1) mx = fmaxf(mx, __shfl_xor(mx, o));
    float sum = 0.0f;
    #pragma unroll
    for (int j=0;j<4;++j){
        if (j*64 <= nb){
            float e = expf(scv[j] - mx);
            sum += e; scv[j] = e;
        }
    }
    #pragma unroll
    for (int o=1;o<64;o<<=1) sum += __shfl_xor(sum, o);
    float rinv = 1.0f / sum;
    #pragma unroll
    for (int j=0;j<4;++j)
        if (j*64 <= nb) sa[wv][j*64 + lane] = scv[j]*rinv;
    __syncthreads();
    int slo = (t < w2) ? (w2 - t) : 0;
    int shi = (t + w2 > TT-1) ? (w2 + (TT-1) - t) : nb;
    const float* saw = sa[wv];
    const unsigned short* vr0 = vB + (long)(t - w2)*DK + lane;
    float oa0=0.f, oa1=0.f, oa2=0.f, oa3=0.f;
    int sl = slo;
    for (; sl + 3 <= shi; sl += 4){
        const unsigned short* vr = vr0 + (long)sl*DK;
        oa0 += saw[sl]   * b2f(vr[0]);
        oa1 += saw[sl+1] * b2f(vr[DK]);
        oa2 += saw[sl+2] * b2f(vr[2*DK]);
        oa3 += saw[sl+3] * b2f(vr[3*DK]);
    }
    for (; sl <= shi; ++sl)
        oa0 += saw[sl] * b2f(vr0[(long)sl*DK]);
    float oa = (oa0 + oa1) + (oa2 + oa3);
    out[(((size_t)(b*TT + t))*HH + h)*DK + lane] = f2b(oa);   // token-major for o-proj
}

// ---------------- launcher ----------------
extern "C" void kernel_launch(void* const* d_in, const int* in_sizes, int n_in,
                              void* d_out, int out_size, void* d_ws, size_t ws_size,
                              hipStream_t stream){
    const float* x    = (const float*)d_in[0];
    const float* ln1g = (const float*)d_in[2];
    const float* ln1b = (const float*)d_in[3];
    const float* wq   = (const float*)d_in[4];
    const float* bq   = (const float*)d_in[5];
    const float* wk   = (const float*)d_in[6];
    const float* bk   = (const float*)d_in[7];
    const float* wvv  = (const float*)d_in[8];
    const float* bv   = (const float*)d_in[9];
    const float* wo   = (const float*)d_in[10];
    const float* bo   = (const float*)d_in[11];
    const float* wpos = (const float*)d_in[12];
    const float* pbu  = (const float*)d_in[13];
    const float* pbv  = (const float*)d_in[14];
    const float* ln2g = (const float*)d_in[15];
    const float* ln2b = (const float*)d_in[16];
    const float* w1   = (const float*)d_in[17];
    const float* b1   = (const float*)d_in[18];
    const float* w2   = (const float*)d_in[19];
    const float* b2   = (const float*)d_in[20];

    const int NTOK = BB*TT;            // 2000
    const int NELEM = NTOK*DD;         // 1,536,000

    float* x_cur = (float*)d_out;      // residual lives in d_out (fp32)

    // ws layout — total ~21.1 MB (same scale as round-5's passing 20.9 MB)
    char* ws = (char*)d_ws;
    unsigned short* qbuf  = (unsigned short*)(ws);             // (b,h,t,d) q / mlp hidden
    unsigned short* kbuf  = (unsigned short*)(ws + 3072000);   // (b,h,d,t) TPAD  3,145,728 B
    unsigned short* vbuf  = (unsigned short*)(ws + 6217728);   // (b,h,t,d)       3,072,000 B
    unsigned short* hbuf  = (unsigned short*)(ws + 9289728);   // pe / ln out / attn out
    unsigned short* ppbuf = (unsigned short*)(ws + 12361728);  // (h,d,n) NPAD      393,216 B
    unsigned short* wtbuf = (unsigned short*)(ws + 12754944);  // 7 * 1,179,648 B
    #define WT(t_) (wtbuf + (size_t)(t_)*WELEM)

    dim3 blk(256);
    scale_kernel<<<(NELEM+255)/256, blk, 0, stream>>>(x, x_cur, NELEM);

    dim3 gBig(16, 12);                 // 128x64 tiles, N=768
    dim3 gQKV(16, 36);                 // 128x64 tiles, N=2304
    dim3 gPe(2, 12);
    dim3 gW(12, 12, 7);

    for (int l = 0; l < LL; ++l){
        long wl = (long)l*WELEM;
        long dl = (long)l*DD;
        long pl = (long)l*HH*DK;

        wconv_kernel<<<gW, blk, 0, stream>>>(wq, wk, wvv, wo, wpos, w1, w2, wl, wtbuf);

        pe_kernel<<<PEROWS, 384, 0, stream>>>(hbuf);
        gemm_kernel<4><<<gPe, blk, 0, stream>>>(hbuf, WT(4), nullptr, ppbuf, nullptr, PEROWS);

        ln_kernel<<<NTOK, blk, 0, stream>>>(x_cur, ln1g + dl, ln1b + dl, hbuf);
        gemm_qkv_kernel<<<gQKV, blk, 0, stream>>>(hbuf, WT(0), bq + dl, bk + dl, bv + dl,
                                                  qbuf, kbuf, vbuf);

        attn_kernel<<<dim3(TT/4, BB, HH), blk, 0, stream>>>(qbuf, kbuf, vbuf, ppbuf,
                                                            pbu + pl, pbv + pl, hbuf);

        gemm_kernel<2><<<gBig, blk, 0, stream>>>(hbuf, WT(3), bo + dl, nullptr, x_cur, NTOK);

        ln_kernel<<<NTOK, blk, 0, stream>>>(x_cur, ln2g + dl, ln2b + dl, hbuf);
        gemm_kernel<1><<<gBig, blk, 0, stream>>>(hbuf, WT(5), b1 + dl, qbuf, nullptr, NTOK);
        gemm_kernel<2><<<gBig, blk, 0, stream>>>(qbuf, WT(6), b2 + dl, nullptr, x_cur, NTOK);
    }
}

// Round 7
// 406.652 us; speedup vs baseline: 1.8882x; 1.2342x over previous
//
#include <hip/hip_runtime.h>

// ---------------- constants ----------------
#define TT 1000
#define BB 2
#define DD 768
#define HH 12
#define DK 64
#define LL 2
#define WELEM 589824          // 768*768
#define PEROWS 255            // rel positions -127..127
#define VTP 1312              // t-stride in vT layout (with 128 margin both sides)

typedef __bf16 bf16x8 __attribute__((ext_vector_type(8)));
typedef float floatx4 __attribute__((ext_vector_type(4)));

__device__ __constant__ int HALFW[12] = {3,7,15,31,63,127,3,7,15,31,63,127};

// ---------------- helpers ----------------
__device__ __forceinline__ float b2f(unsigned short u){
    union { unsigned int i; float f; } x; x.i = ((unsigned int)u) << 16; return x.f;
}
__device__ __forceinline__ unsigned short f2b(float f){
    union { float f; unsigned int i; } x; x.f = f;
    unsigned int i = x.i;
    i += 0x7fffu + ((i >> 16) & 1u);   // RNE
    return (unsigned short)(i >> 16);
}

// ---------------- x scale ----------------
__global__ __launch_bounds__(256)
void scale_kernel(const float* __restrict__ x, float* __restrict__ xc, int n){
    int i = blockIdx.x*256 + threadIdx.x;
    if (i < n) xc[i] = x[i] * 27.712812921102035f;
}

// ---------------- pe rows (pos = 127-row), bf16 ----------------
__global__ __launch_bounds__(384) void pe_kernel(unsigned short* __restrict__ pe){
    int row = blockIdx.x;
    int i = threadIdx.x;
    float pos = (float)(127 - row);
    float dv = expf((float)(2*i) * (-9.210340371976184f / 768.0f));
    float ang = pos * dv;
    pe[(size_t)row*DD + 2*i]   = f2b(sinf(ang));
    pe[(size_t)row*DD + 2*i+1] = f2b(cosf(ang));
}

// ---------------- weight convert+transpose: fp32 (K,N) -> bf16 (N,K) ----------------
__global__ __launch_bounds__(256)
void wconv_kernel(const float* s0, const float* s1, const float* s2, const float* s3,
                  const float* s4, const float* s5, const float* s6, long loff,
                  unsigned short* __restrict__ dst){
    const float* srcs[7] = {s0,s1,s2,s3,s4,s5,s6};
    int z = blockIdx.z;
    const float* src = srcs[z] + loff;
    unsigned short* d = dst + (size_t)z*WELEM;
    int k0 = blockIdx.x*64, n0 = blockIdx.y*64;
    __shared__ __align__(16) unsigned short tile[64][72];
    int r = threadIdx.x >> 2, c = threadIdx.x & 3;
    const float4* sp = (const float4*)(src + (size_t)(k0+r)*DD + n0 + c*16);
    float4 f0 = sp[0], f1 = sp[1], f2 = sp[2], f3 = sp[3];
    unsigned short u[16];
    u[0]=f2b(f0.x); u[1]=f2b(f0.y); u[2]=f2b(f0.z); u[3]=f2b(f0.w);
    u[4]=f2b(f1.x); u[5]=f2b(f1.y); u[6]=f2b(f1.z); u[7]=f2b(f1.w);
    u[8]=f2b(f2.x); u[9]=f2b(f2.y); u[10]=f2b(f2.z); u[11]=f2b(f2.w);
    u[12]=f2b(f3.x); u[13]=f2b(f3.y); u[14]=f2b(f3.z); u[15]=f2b(f3.w);
    *(int4*)&tile[r][c*16]   = *(int4*)&u[0];
    *(int4*)&tile[r][c*16+8] = *(int4*)&u[8];
    __syncthreads();
    unsigned short tmp[16];
    #pragma unroll
    for (int i=0;i<16;++i) tmp[i] = tile[c*16+i][r];
    int4* dp = (int4*)(d + (size_t)(n0+r)*DD + k0 + c*16);
    dp[0] = *(int4*)&tmp[0];
    dp[1] = *(int4*)&tmp[8];
}

// ---------------- LayerNorm: fp32 in -> bf16 out ----------------
__global__ __launch_bounds__(256)
void ln_kernel(const float* __restrict__ x, const float* __restrict__ g,
               const float* __restrict__ bb, unsigned short* __restrict__ out){
    int row = blockIdx.x;
    const float* xr = x + (size_t)row*DD;
    int tid = threadIdx.x;
    float v0 = xr[tid], v1 = xr[tid+256], v2 = xr[tid+512];
    float s = v0+v1+v2, ss = v0*v0+v1*v1+v2*v2;
    #pragma unroll
    for (int o=1;o<64;o<<=1){ s += __shfl_xor(s,o); ss += __shfl_xor(ss,o); }
    __shared__ float rs[4], rss[4];
    int wv = tid>>6, lane = tid&63;
    if (lane==0){ rs[wv]=s; rss[wv]=ss; }
    __syncthreads();
    s  = rs[0]+rs[1]+rs[2]+rs[3];
    ss = rss[0]+rss[1]+rss[2]+rss[3];
    float mean = s * (1.0f/768.0f);
    float var  = ss * (1.0f/768.0f) - mean*mean;
    float inv  = 1.0f / sqrtf(var + 1e-5f);
    unsigned short* orow = out + (size_t)row*DD;
    #pragma unroll
    for (int kk=0;kk<3;++kk){
        int i = tid + 256*kk;
        float v = (kk==0?v0:(kk==1?v1:v2));
        orow[i] = f2b((v - mean)*inv*g[i] + bb[i]);
    }
}

// ======== GEMM core macro: 128x64 tile, acc[2][4] ========
#define GEMM_CORE(A_, Bt_, n0_, M_)                                              \
    int tid = threadIdx.x;                                                       \
    int m0 = blockIdx.x*128;                                                     \
    int wv = tid>>6, lane = tid&63;                                              \
    int quad = lane>>4, l16 = lane&15;                                           \
    int ar = tid>>2;                                                             \
    int ac = (tid&3)*8;                                                          \
    floatx4 acc[2][4];                                                           \
    _Pragma("unroll")                                                            \
    for (int mi=0;mi<2;++mi)                                                     \
        _Pragma("unroll")                                                        \
        for (int ni=0;ni<4;++ni) acc[mi][ni] = (floatx4){0.f,0.f,0.f,0.f};       \
    {                                                                            \
        const unsigned short* Bp = (Bt_) + (size_t)(n0_)*768;                    \
        int r0 = m0 + ar;       if (r0 > (M_)-1) r0 = (M_)-1;                    \
        int r1 = m0 + 64 + ar;  if (r1 > (M_)-1) r1 = (M_)-1;                    \
        const unsigned short* Ap0 = (A_) + (size_t)r0*768 + ac;                  \
        const unsigned short* Ap1 = (A_) + (size_t)r1*768 + ac;                  \
        const unsigned short* Bpp = Bp + (size_t)ar*768 + ac;                    \
        for (int k0=0; k0<768; k0+=32){                                          \
            int4 a0 = *(const int4*)(Ap0 + k0);                                  \
            int4 a1 = *(const int4*)(Ap1 + k0);                                  \
            int4 b0 = *(const int4*)(Bpp + k0);                                  \
            *(int4*)&As[ar*32 + ac]      = a0;                                   \
            *(int4*)&As[(64+ar)*32 + ac] = a1;                                   \
            *(int4*)&Bs[ar*32 + ac]      = b0;                                   \
            __syncthreads();                                                     \
            _Pragma("unroll")                                                    \
            for (int mi=0; mi<2; ++mi){                                          \
                bf16x8 af = *(const bf16x8*)&As[(32*wv + 16*mi + l16)*32 + 8*quad]; \
                _Pragma("unroll")                                                \
                for (int ni=0; ni<4; ++ni){                                      \
                    bf16x8 bfv = *(const bf16x8*)&Bs[(16*ni + l16)*32 + 8*quad]; \
                    acc[mi][ni] = __builtin_amdgcn_mfma_f32_16x16x32_bf16(af, bfv, acc[mi][ni], 0, 0, 0); \
                }                                                                \
            }                                                                    \
            __syncthreads();                                                     \
        }                                                                        \
    }

// ---------------- standalone GEMM (N=768) ----------------
// MODE 1: bf16(gelu). MODE 2: resid +=. MODE 3: (b,h,r,d) scatter (rpb rows per batch).
template<int MODE>
__global__ __launch_bounds__(256)
void gemm_kernel(const unsigned short* __restrict__ A, const unsigned short* __restrict__ Bt,
                 const float* __restrict__ bias, unsigned short* __restrict__ outb,
                 float* __restrict__ resid, int M, int rpb){
    __shared__ __align__(16) unsigned short As[128*32];
    __shared__ __align__(16) unsigned short Bs[64*32];
    int n0 = blockIdx.y*64;
    GEMM_CORE(A, Bt, n0, M)
    float bfv_[4];
    #pragma unroll
    for (int ni=0;ni<4;++ni) bfv_[ni] = bias ? bias[n0 + 16*ni + l16] : 0.0f;
    #pragma unroll
    for (int mi=0;mi<2;++mi){
        #pragma unroll
        for (int rr=0;rr<4;++rr){
            int row = m0 + 32*wv + 16*mi + 4*quad + rr;
            if (row >= M) continue;
            int bb_ = 0, r_ = row;
            if (MODE == 3){ bb_ = row / rpb; r_ = row - bb_*rpb; }
            #pragma unroll
            for (int ni=0;ni<4;++ni){
                int col = n0 + 16*ni + l16;
                float v = acc[mi][ni][rr] + bfv_[ni];
                if (MODE == 1)      outb[(size_t)row*768 + col] = f2b(0.5f*v*(1.0f + erff(v*0.70710678118654752f)));
                else if (MODE == 2) resid[(size_t)row*768 + col] += v;
                else {
                    int h = col >> 6, d = col & 63;
                    outb[(((size_t)(bb_*HH + h))*rpb + r_)*DK + d] = f2b(v);
                }
            }
        }
    }
}

// ---------------- fused QKV GEMM: q,k -> (b,h,t,d); v -> (b,h,d,t+128) margin layout ----------------
__global__ __launch_bounds__(256)
void gemm_qkv_kernel(const unsigned short* __restrict__ A, const unsigned short* __restrict__ Bt,
                     const float* __restrict__ bq, const float* __restrict__ bk, const float* __restrict__ bv,
                     unsigned short* __restrict__ qout, unsigned short* __restrict__ kout,
                     unsigned short* __restrict__ vout){
    __shared__ __align__(16) unsigned short sh[10240];
    unsigned short* As = sh;
    unsigned short* Bs = sh + 128*32;
    int n0 = blockIdx.y*64;
    GEMM_CORE(A, Bt, n0, 2000)
    int sec = blockIdx.y / 12;            // 0=q 1=k 2=v
    int col0 = n0 - sec*768;
    int h = col0 >> 6;
    const float* bias = (sec==0) ? bq : (sec==1) ? bk : bv;
    float bfv_[4];
    #pragma unroll
    for (int ni=0;ni<4;++ni) bfv_[ni] = bias[col0 + 16*ni + l16];
    if (sec != 2){
        unsigned short* outp = (sec==0) ? qout : kout;
        #pragma unroll
        for (int mi=0;mi<2;++mi){
            #pragma unroll
            for (int rr=0;rr<4;++rr){
                int row = m0 + 32*wv + 16*mi + 4*quad + rr;
                if (row >= 2000) continue;
                int b = row / TT, tl = row - b*TT;
                #pragma unroll
                for (int ni=0;ni<4;++ni){
                    int d = 16*ni + l16;
                    outp[(((size_t)(b*HH + h))*TT + tl)*DK + d] = f2b(acc[mi][ni][rr] + bfv_[ni]);
                }
            }
        }
    } else {
        // V: acc tile -> LDS (stride 66), then coalesced (d, t+128) store
        #pragma unroll
        for (int mi=0;mi<2;++mi)
            #pragma unroll
            for (int rr=0;rr<4;++rr){
                int rt = 32*wv + 16*mi + 4*quad + rr;
                #pragma unroll
                for (int ni=0;ni<4;++ni)
                    sh[rt*66 + 16*ni + l16] = f2b(acc[mi][ni][rr] + bfv_[ni]);
            }
        __syncthreads();
        #pragma unroll
        for (int it=0; it<32; ++it){
            int idx = it*256 + tid;
            int d = idx >> 7, rt = idx & 127;
            int row = m0 + rt;
            if (row < 2000){
                int b = row / TT, tl = row - b*TT;
                vout[(((size_t)(b*HH + h))*DK + d)*VTP + tl + 128] = sh[rt*66 + d];
            }
        }
    }
}

// ---------------- MFMA banded rel-pos attention ----------------
// 1 wave per 16-row t-tile. q,k (b,h,t,d); vT (b,h,d,t+128); pp (h,n,d).
__global__ __launch_bounds__(64)
void attn_kernel(const unsigned short* __restrict__ q, const unsigned short* __restrict__ k,
                 const unsigned short* __restrict__ vT, const unsigned short* __restrict__ pp,
                 const float* __restrict__ pbu, const float* __restrict__ pbv,
                 unsigned short* __restrict__ out){
    int b = blockIdx.y, h = blockIdx.z;
    int t0 = blockIdx.x * 16;
    int w2 = HALFW[h];
    int lane = threadIdx.x;
    int l16 = lane & 15, quad = lane >> 4;

    const unsigned short* qB = q  + ((size_t)(b*HH + h))*TT*DK;
    const unsigned short* kB = k  + ((size_t)(b*HH + h))*TT*DK;
    const unsigned short* vB = vT + ((size_t)(b*HH + h))*DK*VTP;
    const unsigned short* pB = pp + (size_t)h*PEROWS*DK;

    __shared__ __align__(16) float bd[16*260];
    __shared__ __align__(16) unsigned short pl[16*328];

    // Q fragments: bf16(q + pbu), bf16(q + pbv); A-layout m=l16, k=quad*8+j
    int tq = t0 + l16; if (tq > TT-1) tq = TT-1;
    union { int4 i; unsigned short u[8]; } r0, r1;
    r0.i = *(const int4*)(qB + (size_t)tq*DK + quad*8);
    r1.i = *(const int4*)(qB + (size_t)tq*DK + 32 + quad*8);
    const float* pu = pbu + h*DK + quad*8;
    const float* pv = pbv + h*DK + quad*8;
    union { unsigned short u[8]; bf16x8 v; } qu0, qu1, qv0, qv1;
    #pragma unroll
    for (int i=0;i<8;++i){
        float a0 = b2f(r0.u[i]), a1 = b2f(r1.u[i]);
        qu0.u[i] = f2b(a0 + pu[i]);
        qu1.u[i] = f2b(a1 + pu[32+i]);
        qv0.u[i] = f2b(a0 + pv[i]);
        qv1.u[i] = f2b(a1 + pv[32+i]);
    }

    // BD = Qv @ pp^T over n-window [127-w2, 127+w2]
    int Nn = 2*w2 + 1;
    int ntiles = (Nn + 15) >> 4;
    for (int ti = 0; ti < ntiles; ++ti){
        int n = 127 - w2 + ti*16 + l16; if (n > PEROWS-1) n = PEROWS-1;
        const unsigned short* pr = pB + (size_t)n*DK + quad*8;
        bf16x8 pb0 = *(const bf16x8*)pr;
        bf16x8 pb1 = *(const bf16x8*)(pr + 32);
        floatx4 a = {0.f,0.f,0.f,0.f};
        a = __builtin_amdgcn_mfma_f32_16x16x32_bf16(qv0.v, pb0, a, 0,0,0);
        a = __builtin_amdgcn_mfma_f32_16x16x32_bf16(qv1.v, pb1, a, 0,0,0);
        #pragma unroll
        for (int r=0;r<4;++r) bd[(quad*4+r)*260 + ti*16 + l16] = a[r];
    }
    __syncthreads();

    // AC = Qu @ K^T over s-window [t0-w2, t0+15+w2]; combine with shifted BD
    int Ns = 2*w2 + 16;
    int stiles = (Ns + 15) >> 4;
    int s_lo = t0 - w2;
    float scv[17][4];
    float mx[4] = {-1e30f,-1e30f,-1e30f,-1e30f};
    #pragma unroll
    for (int ti = 0; ti < 17; ++ti){
        if (ti < stiles){
            int s = s_lo + ti*16 + l16;
            int sc = s < 0 ? 0 : (s > TT-1 ? TT-1 : s);
            const unsigned short* kr = kB + (size_t)sc*DK + quad*8;
            bf16x8 kb0 = *(const bf16x8*)kr;
            bf16x8 kb1 = *(const bf16x8*)(kr + 32);
            floatx4 a = {0.f,0.f,0.f,0.f};
            a = __builtin_amdgcn_mfma_f32_16x16x32_bf16(qu0.v, kb0, a, 0,0,0);
            a = __builtin_amdgcn_mfma_f32_16x16x32_bf16(qu1.v, kb1, a, 0,0,0);
            #pragma unroll
            for (int r=0;r<4;++r){
                int row = quad*4 + r;
                int nrel = ti*16 + l16 - row;
                bool ok = (nrel >= 0) && (nrel <= 2*w2) && (s >= 0) && (s <= TT-1);
                int idx = row*260 + nrel;
                idx = idx < 0 ? 0 : (idx > 16*260-1 ? 16*260-1 : idx);
                float bdv = bd[idx];
                float sc_ = ok ? (a[r] + bdv) * 0.125f : -1e30f;
                scv[ti][r] = sc_;
                mx[r] = fmaxf(mx[r], sc_);
            }
        } else {
            #pragma unroll
            for (int r=0;r<4;++r) scv[ti][r] = -1e30f;
        }
    }
    // row-max / row-sum butterflies across the 16 lanes of each quad
    #pragma unroll
    for (int off=1; off<16; off<<=1){
        #pragma unroll
        for (int r=0;r<4;++r) mx[r] = fmaxf(mx[r], __shfl_xor(mx[r], off));
    }
    float sm[4] = {0.f,0.f,0.f,0.f};
    #pragma unroll
    for (int ti=0; ti<17; ++ti){
        if (ti < stiles){
            #pragma unroll
            for (int r=0;r<4;++r){
                float e = __expf(scv[ti][r] - mx[r]);
                sm[r] += e; scv[ti][r] = e;
            }
        }
    }
    #pragma unroll
    for (int off=1; off<16; off<<=1){
        #pragma unroll
        for (int r=0;r<4;++r) sm[r] += __shfl_xor(sm[r], off);
    }
    float rinv[4];
    #pragma unroll
    for (int r=0;r<4;++r) rinv[r] = sm[r] > 0.f ? 1.0f/sm[r] : 0.0f;

    // P (normalized, bf16) into LDS at absolute-aligned columns
    int s0a = s_lo & ~31;            // floor to 32 (works for negatives)
    int pad_lo = s_lo - s0a;         // 0..31
    int ktiles = (pad_lo + Ns + 31) >> 5;    // <= 10; cols <= 320 <= 328
    for (int row = 0; row < 16; ++row){
        for (int c4 = lane*4; c4 < ktiles*32; c4 += 256)
            *(unsigned long long*)&pl[row*328 + c4] = 0ULL;
    }
    #pragma unroll
    for (int ti=0; ti<17; ++ti){
        if (ti < stiles){
            #pragma unroll
            for (int r=0;r<4;++r)
                pl[(quad*4+r)*328 + pad_lo + ti*16 + l16] = f2b(scv[ti][r]*rinv[r]);
        }
    }
    __syncthreads();

    // PV = P @ V  (V from transposed margin layout; masked P entries are exactly 0)
    floatx4 oacc[4];
    #pragma unroll
    for (int dt=0; dt<4; ++dt) oacc[dt] = (floatx4){0.f,0.f,0.f,0.f};
    for (int kt = 0; kt < ktiles; ++kt){
        bf16x8 pa = *(const bf16x8*)&pl[l16*328 + kt*32 + quad*8];
        int sidx = s0a + kt*32 + quad*8 + 128;
        #pragma unroll
        for (int dt=0; dt<4; ++dt){
            bf16x8 vb = *(const bf16x8*)(vB + (size_t)(dt*16 + l16)*VTP + sidx);
            oacc[dt] = __builtin_amdgcn_mfma_f32_16x16x32_bf16(pa, vb, oacc[dt], 0,0,0);
        }
    }
    #pragma unroll
    for (int r=0;r<4;++r){
        int t = t0 + quad*4 + r;
        if (t <= TT-1){
            unsigned short* orow = out + (((size_t)(b*TT + t))*HH + h)*DK;
            #pragma unroll
            for (int dt=0; dt<4; ++dt)
                orow[dt*16 + l16] = f2b(oacc[dt][r]);
        }
    }
}

// ---------------- launcher ----------------
extern "C" void kernel_launch(void* const* d_in, const int* in_sizes, int n_in,
                              void* d_out, int out_size, void* d_ws, size_t ws_size,
                              hipStream_t stream){
    const float* x    = (const float*)d_in[0];
    const float* ln1g = (const float*)d_in[2];
    const float* ln1b = (const float*)d_in[3];
    const float* wq   = (const float*)d_in[4];
    const float* bq   = (const float*)d_in[5];
    const float* wk   = (const float*)d_in[6];
    const float* bk   = (const float*)d_in[7];
    const float* wvv  = (const float*)d_in[8];
    const float* bv   = (const float*)d_in[9];
    const float* wo   = (const float*)d_in[10];
    const float* bo   = (const float*)d_in[11];
    const float* wpos = (const float*)d_in[12];
    const float* pbu  = (const float*)d_in[13];
    const float* pbv  = (const float*)d_in[14];
    const float* ln2g = (const float*)d_in[15];
    const float* ln2b = (const float*)d_in[16];
    const float* w1   = (const float*)d_in[17];
    const float* b1   = (const float*)d_in[18];
    const float* w2   = (const float*)d_in[19];
    const float* b2   = (const float*)d_in[20];

    const int NTOK = BB*TT;            // 2000
    const int NELEM = NTOK*DD;         // 1,536,000

    float* x_cur = (float*)d_out;      // residual in d_out (fp32)

    // ws layout — total 21,895,680 B
    char* ws = (char*)d_ws;
    unsigned short* qbuf  = (unsigned short*)(ws);              // (b,h,t,d) q / mlp hidden
    unsigned short* kbuf  = (unsigned short*)(ws + 3072000);    // (b,h,t,d)
    unsigned short* vTbuf = (unsigned short*)(ws + 6144000);    // (b,h,d,t+128) 4,030,464 B
    unsigned short* hbuf  = (unsigned short*)(ws + 10174464);   // pe / ln out / attn out
    unsigned short* ppbuf = (unsigned short*)(ws + 13246464);   // (h,n,d) 391,680 B
    unsigned short* wtbuf = (unsigned short*)(ws + 13638144);   // 7 * 1,179,648 B
    #define WT(t_) (wtbuf + (size_t)(t_)*WELEM)

    dim3 blk(256);
    scale_kernel<<<(NELEM+255)/256, blk, 0, stream>>>(x, x_cur, NELEM);

    dim3 gBig(16, 12);
    dim3 gQKV(16, 36);
    dim3 gPe(2, 12);
    dim3 gW(12, 12, 7);
    dim3 gAttn(63, BB, HH);            // 16-row t-tiles

    for (int l = 0; l < LL; ++l){
        long wl = (long)l*WELEM;
        long dl = (long)l*DD;
        long pl_ = (long)l*HH*DK;

        wconv_kernel<<<gW, blk, 0, stream>>>(wq, wk, wvv, wo, wpos, w1, w2, wl, wtbuf);

        pe_kernel<<<PEROWS, 384, 0, stream>>>(hbuf);
        gemm_kernel<3><<<gPe, blk, 0, stream>>>(hbuf, WT(4), nullptr, ppbuf, nullptr, PEROWS, PEROWS);

        ln_kernel<<<NTOK, blk, 0, stream>>>(x_cur, ln1g + dl, ln1b + dl, hbuf);
        gemm_qkv_kernel<<<gQKV, blk, 0, stream>>>(hbuf, WT(0), bq + dl, bk + dl, bv + dl,
                                                  qbuf, kbuf, vTbuf);

        attn_kernel<<<gAttn, dim3(64), 0, stream>>>(qbuf, kbuf, vTbuf, ppbuf,
                                                    pbu + pl_, pbv + pl_, hbuf);

        gemm_kernel<2><<<gBig, blk, 0, stream>>>(hbuf, WT(3), bo + dl, nullptr, x_cur, NTOK, TT);

        ln_kernel<<<NTOK, blk, 0, stream>>>(x_cur, ln2g + dl, ln2b + dl, hbuf);
        gemm_kernel<1><<<gBig, blk, 0, stream>>>(hbuf, WT(5), b1 + dl, qbuf, nullptr, NTOK, TT);
        gemm_kernel<2><<<gBig, blk, 0, stream>>>(qbuf, WT(6), b2 + dl, nullptr, x_cur, NTOK, TT);
    }
}

// Round 8
// 388.262 us; speedup vs baseline: 1.9776x; 1.0474x over previous
//
#include <hip/hip_runtime.h>

// ---------------- constants ----------------
#define TT 1000
#define BB 2
#define DD 768
#define HH 12
#define DK 64
#define LL 2
#define WELEM 589824          // 768*768
#define PEROWS 255            // rel positions -127..127
#define VTP 1312              // t-stride in vT layout (with 128 margin both sides)
#define LDSZ 13824            // per-buffer elems: 128*72 + 64*72

typedef __bf16 bf16x8 __attribute__((ext_vector_type(8)));
typedef float floatx4 __attribute__((ext_vector_type(4)));

__device__ __constant__ int HALFW[12] = {3,7,15,31,63,127,3,7,15,31,63,127};

// ---------------- helpers ----------------
__device__ __forceinline__ float b2f(unsigned short u){
    union { unsigned int i; float f; } x; x.i = ((unsigned int)u) << 16; return x.f;
}
__device__ __forceinline__ unsigned short f2b(float f){
    union { float f; unsigned int i; } x; x.f = f;
    unsigned int i = x.i;
    i += 0x7fffu + ((i >> 16) & 1u);   // RNE
    return (unsigned short)(i >> 16);
}

// ---------------- x scale ----------------
__global__ __launch_bounds__(256)
void scale_kernel(const float* __restrict__ x, float* __restrict__ xc, int n){
    int i = blockIdx.x*256 + threadIdx.x;
    if (i < n) xc[i] = x[i] * 27.712812921102035f;
}

// ---------------- pe rows (pos = 127-row), bf16 ----------------
__global__ __launch_bounds__(384) void pe_kernel(unsigned short* __restrict__ pe){
    int row = blockIdx.x;
    int i = threadIdx.x;
    float pos = (float)(127 - row);
    float dv = expf((float)(2*i) * (-9.210340371976184f / 768.0f));
    float ang = pos * dv;
    pe[(size_t)row*DD + 2*i]   = f2b(sinf(ang));
    pe[(size_t)row*DD + 2*i+1] = f2b(cosf(ang));
}

// ---------------- weight convert+transpose: fp32 (K,N) -> bf16 (N,K), 14 slices ----------------
// slice z: layer = z/7, mat = z%7; dst slot = z (so q,k,v of one layer are adjacent)
__global__ __launch_bounds__(256)
void wconv_kernel(const float* s0, const float* s1, const float* s2, const float* s3,
                  const float* s4, const float* s5, const float* s6,
                  unsigned short* __restrict__ dst){
    const float* srcs[7] = {s0,s1,s2,s3,s4,s5,s6};
    int z = blockIdx.z;
    const float* src = srcs[z % 7] + (size_t)(z / 7)*WELEM;
    unsigned short* d = dst + (size_t)z*WELEM;
    int k0 = blockIdx.x*64, n0 = blockIdx.y*64;
    __shared__ __align__(16) unsigned short tile[64][72];
    int r = threadIdx.x >> 2, c = threadIdx.x & 3;
    const float4* sp = (const float4*)(src + (size_t)(k0+r)*DD + n0 + c*16);
    float4 f0 = sp[0], f1 = sp[1], f2 = sp[2], f3 = sp[3];
    unsigned short u[16];
    u[0]=f2b(f0.x); u[1]=f2b(f0.y); u[2]=f2b(f0.z); u[3]=f2b(f0.w);
    u[4]=f2b(f1.x); u[5]=f2b(f1.y); u[6]=f2b(f1.z); u[7]=f2b(f1.w);
    u[8]=f2b(f2.x); u[9]=f2b(f2.y); u[10]=f2b(f2.z); u[11]=f2b(f2.w);
    u[12]=f2b(f3.x); u[13]=f2b(f3.y); u[14]=f2b(f3.z); u[15]=f2b(f3.w);
    *(int4*)&tile[r][c*16]   = *(int4*)&u[0];
    *(int4*)&tile[r][c*16+8] = *(int4*)&u[8];
    __syncthreads();
    unsigned short tmp[16];
    #pragma unroll
    for (int i=0;i<16;++i) tmp[i] = tile[c*16+i][r];
    int4* dp = (int4*)(d + (size_t)(n0+r)*DD + k0 + c*16);
    dp[0] = *(int4*)&tmp[0];
    dp[1] = *(int4*)&tmp[8];
}

// ---------------- LayerNorm: fp32 in -> bf16 out ----------------
__global__ __launch_bounds__(256)
void ln_kernel(const float* __restrict__ x, const float* __restrict__ g,
               const float* __restrict__ bb, unsigned short* __restrict__ out){
    int row = blockIdx.x;
    const float* xr = x + (size_t)row*DD;
    int tid = threadIdx.x;
    float v0 = xr[tid], v1 = xr[tid+256], v2 = xr[tid+512];
    float s = v0+v1+v2, ss = v0*v0+v1*v1+v2*v2;
    #pragma unroll
    for (int o=1;o<64;o<<=1){ s += __shfl_xor(s,o); ss += __shfl_xor(ss,o); }
    __shared__ float rs[4], rss[4];
    int wv = tid>>6, lane = tid&63;
    if (lane==0){ rs[wv]=s; rss[wv]=ss; }
    __syncthreads();
    s  = rs[0]+rs[1]+rs[2]+rs[3];
    ss = rss[0]+rss[1]+rss[2]+rss[3];
    float mean = s * (1.0f/768.0f);
    float var  = ss * (1.0f/768.0f) - mean*mean;
    float inv  = 1.0f / sqrtf(var + 1e-5f);
    unsigned short* orow = out + (size_t)row*DD;
    #pragma unroll
    for (int kk=0;kk<3;++kk){
        int i = tid + 256*kk;
        float v = (kk==0?v0:(kk==1?v1:v2));
        orow[i] = f2b((v - mean)*inv*g[i] + bb[i]);
    }
}

// ======== pipelined GEMM core: 128x64 tile, BK=64, dbuf LDS (stride 72), reg prefetch ========
#define GEMM_PIPE(A_, Bt_, n0_, M_)                                             \
    int tid = threadIdx.x;                                                      \
    int m0 = blockIdx.x*128;                                                    \
    int wv = tid>>6, lane = tid&63;                                             \
    int quad = lane>>4, l16 = lane&15;                                          \
    int ar = tid>>2;                                                            \
    int ac = (tid&3)*16;                                                        \
    floatx4 acc[2][4];                                                          \
    _Pragma("unroll")                                                           \
    for (int mi=0;mi<2;++mi)                                                    \
      _Pragma("unroll")                                                         \
      for (int ni=0;ni<4;++ni) acc[mi][ni] = (floatx4){0.f,0.f,0.f,0.f};        \
    {                                                                           \
      int r0 = m0 + ar;      if (r0 > (M_)-1) r0 = (M_)-1;                      \
      int r1 = m0 + 64 + ar; if (r1 > (M_)-1) r1 = (M_)-1;                      \
      const unsigned short* Ap0 = (A_) + (size_t)r0*768 + ac;                   \
      const unsigned short* Ap1 = (A_) + (size_t)r1*768 + ac;                   \
      const unsigned short* Bpp = (Bt_) + (size_t)((n0_)+ar)*768 + ac;          \
      int4 pa0 = *(const int4*)Ap0, pa1 = *(const int4*)(Ap0+8);                \
      int4 pa2 = *(const int4*)Ap1, pa3 = *(const int4*)(Ap1+8);                \
      int4 pb0 = *(const int4*)Bpp, pb1 = *(const int4*)(Bpp+8);                \
      for (int s=0; s<12; ++s){                                                 \
        unsigned short* Asb = sh + (s&1)*LDSZ;                                  \
        unsigned short* Bsb = Asb + 9216;                                       \
        *(int4*)&Asb[ar*72 + ac]        = pa0;                                  \
        *(int4*)&Asb[ar*72 + ac + 8]    = pa1;                                  \
        *(int4*)&Asb[(64+ar)*72 + ac]   = pa2;                                  \
        *(int4*)&Asb[(64+ar)*72 + ac+8] = pa3;                                  \
        *(int4*)&Bsb[ar*72 + ac]        = pb0;                                  \
        *(int4*)&Bsb[ar*72 + ac + 8]    = pb1;                                  \
        __syncthreads();                                                        \
        if (s < 11){                                                            \
          int off = (s+1)*64;                                                   \
          pa0 = *(const int4*)(Ap0+off); pa1 = *(const int4*)(Ap0+off+8);       \
          pa2 = *(const int4*)(Ap1+off); pa3 = *(const int4*)(Ap1+off+8);       \
          pb0 = *(const int4*)(Bpp+off); pb1 = *(const int4*)(Bpp+off+8);       \
        }                                                                       \
        _Pragma("unroll")                                                       \
        for (int kh=0; kh<2; ++kh){                                             \
          bf16x8 af0 = *(const bf16x8*)&Asb[(32*wv + l16)*72 + kh*32 + quad*8]; \
          bf16x8 af1 = *(const bf16x8*)&Asb[(32*wv + 16 + l16)*72 + kh*32 + quad*8]; \
          _Pragma("unroll")                                                     \
          for (int ni=0; ni<4; ++ni){                                           \
            bf16x8 bfv = *(const bf16x8*)&Bsb[(16*ni + l16)*72 + kh*32 + quad*8]; \
            acc[0][ni] = __builtin_amdgcn_mfma_f32_16x16x32_bf16(af0, bfv, acc[0][ni], 0,0,0); \
            acc[1][ni] = __builtin_amdgcn_mfma_f32_16x16x32_bf16(af1, bfv, acc[1][ni], 0,0,0); \
          }                                                                     \
        }                                                                       \
      }                                                                         \
    }

// ---------------- standalone GEMM (N=768) ----------------
// MODE 1: bf16(gelu). MODE 2: resid +=. MODE 3: (b,h,r,d) scatter (rpb rows per batch).
template<int MODE>
__global__ __launch_bounds__(256)
void gemm_kernel(const unsigned short* __restrict__ A, const unsigned short* __restrict__ Bt,
                 const float* __restrict__ bias, unsigned short* __restrict__ outb,
                 float* __restrict__ resid, int M, int rpb){
    __shared__ __align__(16) unsigned short sh[2*LDSZ];
    int n0 = blockIdx.y*64;
    GEMM_PIPE(A, Bt, n0, M)
    float bfv_[4];
    #pragma unroll
    for (int ni=0;ni<4;++ni) bfv_[ni] = bias ? bias[n0 + 16*ni + l16] : 0.0f;
    #pragma unroll
    for (int mi=0;mi<2;++mi){
        #pragma unroll
        for (int rr=0;rr<4;++rr){
            int row = m0 + 32*wv + 16*mi + 4*quad + rr;
            if (row >= M) continue;
            int bb_ = 0, r_ = row;
            if (MODE == 3){ bb_ = row / rpb; r_ = row - bb_*rpb; }
            #pragma unroll
            for (int ni=0;ni<4;++ni){
                int col = n0 + 16*ni + l16;
                float v = acc[mi][ni][rr] + bfv_[ni];
                if (MODE == 1)      outb[(size_t)row*768 + col] = f2b(0.5f*v*(1.0f + erff(v*0.70710678118654752f)));
                else if (MODE == 2) resid[(size_t)row*768 + col] += v;
                else {
                    int h = col >> 6, d = col & 63;
                    outb[(((size_t)(bb_*HH + h))*rpb + r_)*DK + d] = f2b(v);
                }
            }
        }
    }
}

// ---------------- fused QKV GEMM: q,k -> (b,h,t,d); v -> (b,h,d,t+128) margin layout ----------------
__global__ __launch_bounds__(256)
void gemm_qkv_kernel(const unsigned short* __restrict__ A, const unsigned short* __restrict__ Bt,
                     const float* __restrict__ bq, const float* __restrict__ bk, const float* __restrict__ bv,
                     unsigned short* __restrict__ qout, unsigned short* __restrict__ kout,
                     unsigned short* __restrict__ vout){
    __shared__ __align__(16) unsigned short sh[2*LDSZ];
    int n0 = blockIdx.y*64;
    GEMM_PIPE(A, Bt, n0, 2000)
    int sec = blockIdx.y / 12;            // 0=q 1=k 2=v
    int col0 = n0 - sec*768;
    int h = col0 >> 6;
    const float* bias = (sec==0) ? bq : (sec==1) ? bk : bv;
    float bfv_[4];
    #pragma unroll
    for (int ni=0;ni<4;++ni) bfv_[ni] = bias[col0 + 16*ni + l16];
    if (sec != 2){
        unsigned short* outp = (sec==0) ? qout : kout;
        #pragma unroll
        for (int mi=0;mi<2;++mi){
            #pragma unroll
            for (int rr=0;rr<4;++rr){
                int row = m0 + 32*wv + 16*mi + 4*quad + rr;
                if (row >= 2000) continue;
                int b = row / TT, tl = row - b*TT;
                #pragma unroll
                for (int ni=0;ni<4;++ni){
                    int d = 16*ni + l16;
                    outp[(((size_t)(b*HH + h))*TT + tl)*DK + d] = f2b(acc[mi][ni][rr] + bfv_[ni]);
                }
            }
        }
    } else {
        // V: acc tile -> LDS buf0 region (stride 66; last K-step used buf1 -> safe), then (d,t+128) store
        #pragma unroll
        for (int mi=0;mi<2;++mi)
            #pragma unroll
            for (int rr=0;rr<4;++rr){
                int rt = 32*wv + 16*mi + 4*quad + rr;
                #pragma unroll
                for (int ni=0;ni<4;++ni)
                    sh[rt*66 + 16*ni + l16] = f2b(acc[mi][ni][rr] + bfv_[ni]);
            }
        __syncthreads();
        #pragma unroll
        for (int it=0; it<32; ++it){
            int idx = it*256 + tid;
            int d = idx >> 7, rt = idx & 127;
            int row = m0 + rt;
            if (row < 2000){
                int b = row / TT, tl = row - b*TT;
                vout[(((size_t)(b*HH + h))*DK + d)*VTP + tl + 128] = sh[rt*66 + d];
            }
        }
    }
}

// ---------------- MFMA banded rel-pos attention (unchanged from round 7) ----------------
__global__ __launch_bounds__(64)
void attn_kernel(const unsigned short* __restrict__ q, const unsigned short* __restrict__ k,
                 const unsigned short* __restrict__ vT, const unsigned short* __restrict__ pp,
                 const float* __restrict__ pbu, const float* __restrict__ pbv,
                 unsigned short* __restrict__ out){
    int b = blockIdx.y, h = blockIdx.z;
    int t0 = blockIdx.x * 16;
    int w2 = HALFW[h];
    int lane = threadIdx.x;
    int l16 = lane & 15, quad = lane >> 4;

    const unsigned short* qB = q  + ((size_t)(b*HH + h))*TT*DK;
    const unsigned short* kB = k  + ((size_t)(b*HH + h))*TT*DK;
    const unsigned short* vB = vT + ((size_t)(b*HH + h))*DK*VTP;
    const unsigned short* pB = pp + (size_t)h*PEROWS*DK;

    __shared__ __align__(16) float bd[16*260];
    __shared__ __align__(16) unsigned short pl[16*328];

    int tq = t0 + l16; if (tq > TT-1) tq = TT-1;
    union { int4 i; unsigned short u[8]; } r0, r1;
    r0.i = *(const int4*)(qB + (size_t)tq*DK + quad*8);
    r1.i = *(const int4*)(qB + (size_t)tq*DK + 32 + quad*8);
    const float* pu = pbu + h*DK + quad*8;
    const float* pv = pbv + h*DK + quad*8;
    union { unsigned short u[8]; bf16x8 v; } qu0, qu1, qv0, qv1;
    #pragma unroll
    for (int i=0;i<8;++i){
        float a0 = b2f(r0.u[i]), a1 = b2f(r1.u[i]);
        qu0.u[i] = f2b(a0 + pu[i]);
        qu1.u[i] = f2b(a1 + pu[32+i]);
        qv0.u[i] = f2b(a0 + pv[i]);
        qv1.u[i] = f2b(a1 + pv[32+i]);
    }

    int Nn = 2*w2 + 1;
    int ntiles = (Nn + 15) >> 4;
    for (int ti = 0; ti < ntiles; ++ti){
        int n = 127 - w2 + ti*16 + l16; if (n > PEROWS-1) n = PEROWS-1;
        const unsigned short* pr = pB + (size_t)n*DK + quad*8;
        bf16x8 pb0 = *(const bf16x8*)pr;
        bf16x8 pb1 = *(const bf16x8*)(pr + 32);
        floatx4 a = {0.f,0.f,0.f,0.f};
        a = __builtin_amdgcn_mfma_f32_16x16x32_bf16(qv0.v, pb0, a, 0,0,0);
        a = __builtin_amdgcn_mfma_f32_16x16x32_bf16(qv1.v, pb1, a, 0,0,0);
        #pragma unroll
        for (int r=0;r<4;++r) bd[(quad*4+r)*260 + ti*16 + l16] = a[r];
    }
    __syncthreads();

    int Ns = 2*w2 + 16;
    int stiles = (Ns + 15) >> 4;
    int s_lo = t0 - w2;
    float scv[17][4];
    float mx[4] = {-1e30f,-1e30f,-1e30f,-1e30f};
    #pragma unroll
    for (int ti = 0; ti < 17; ++ti){
        if (ti < stiles){
            int s = s_lo + ti*16 + l16;
            int sc = s < 0 ? 0 : (s > TT-1 ? TT-1 : s);
            const unsigned short* kr = kB + (size_t)sc*DK + quad*8;
            bf16x8 kb0 = *(const bf16x8*)kr;
            bf16x8 kb1 = *(const bf16x8*)(kr + 32);
            floatx4 a = {0.f,0.f,0.f,0.f};
            a = __builtin_amdgcn_mfma_f32_16x16x32_bf16(qu0.v, kb0, a, 0,0,0);
            a = __builtin_amdgcn_mfma_f32_16x16x32_bf16(qu1.v, kb1, a, 0,0,0);
            #pragma unroll
            for (int r=0;r<4;++r){
                int row = quad*4 + r;
                int nrel = ti*16 + l16 - row;
                bool ok = (nrel >= 0) && (nrel <= 2*w2) && (s >= 0) && (s <= TT-1);
                int idx = row*260 + nrel;
                idx = idx < 0 ? 0 : (idx > 16*260-1 ? 16*260-1 : idx);
                float bdv = bd[idx];
                float sc_ = ok ? (a[r] + bdv) * 0.125f : -1e30f;
                scv[ti][r] = sc_;
                mx[r] = fmaxf(mx[r], sc_);
            }
        } else {
            #pragma unroll
            for (int r=0;r<4;++r) scv[ti][r] = -1e30f;
        }
    }
    #pragma unroll
    for (int off=1; off<16; off<<=1){
        #pragma unroll
        for (int r=0;r<4;++r) mx[r] = fmaxf(mx[r], __shfl_xor(mx[r], off));
    }
    float sm[4] = {0.f,0.f,0.f,0.f};
    #pragma unroll
    for (int ti=0; ti<17; ++ti){
        if (ti < stiles){
            #pragma unroll
            for (int r=0;r<4;++r){
                float e = __expf(scv[ti][r] - mx[r]);
                sm[r] += e; scv[ti][r] = e;
            }
        }
    }
    #pragma unroll
    for (int off=1; off<16; off<<=1){
        #pragma unroll
        for (int r=0;r<4;++r) sm[r] += __shfl_xor(sm[r], off);
    }
    float rinv[4];
    #pragma unroll
    for (int r=0;r<4;++r) rinv[r] = sm[r] > 0.f ? 1.0f/sm[r] : 0.0f;

    int s0a = s_lo & ~31;
    int pad_lo = s_lo - s0a;
    int ktiles = (pad_lo + Ns + 31) >> 5;
    for (int row = 0; row < 16; ++row){
        for (int c4 = lane*4; c4 < ktiles*32; c4 += 256)
            *(unsigned long long*)&pl[row*328 + c4] = 0ULL;
    }
    #pragma unroll
    for (int ti=0; ti<17; ++ti){
        if (ti < stiles){
            #pragma unroll
            for (int r=0;r<4;++r)
                pl[(quad*4+r)*328 + pad_lo + ti*16 + l16] = f2b(scv[ti][r]*rinv[r]);
        }
    }
    __syncthreads();

    floatx4 oacc[4];
    #pragma unroll
    for (int dt=0; dt<4; ++dt) oacc[dt] = (floatx4){0.f,0.f,0.f,0.f};
    for (int kt = 0; kt < ktiles; ++kt){
        bf16x8 pa = *(const bf16x8*)&pl[l16*328 + kt*32 + quad*8];
        int sidx = s0a + kt*32 + quad*8 + 128;
        #pragma unroll
        for (int dt=0; dt<4; ++dt){
            bf16x8 vb = *(const bf16x8*)(vB + (size_t)(dt*16 + l16)*VTP + sidx);
            oacc[dt] = __builtin_amdgcn_mfma_f32_16x16x32_bf16(pa, vb, oacc[dt], 0,0,0);
        }
    }
    #pragma unroll
    for (int r=0;r<4;++r){
        int t = t0 + quad*4 + r;
        if (t <= TT-1){
            unsigned short* orow = out + (((size_t)(b*TT + t))*HH + h)*DK;
            #pragma unroll
            for (int dt=0; dt<4; ++dt)
                orow[dt*16 + l16] = f2b(oacc[dt][r]);
        }
    }
}

// ---------------- launcher ----------------
extern "C" void kernel_launch(void* const* d_in, const int* in_sizes, int n_in,
                              void* d_out, int out_size, void* d_ws, size_t ws_size,
                              hipStream_t stream){
    const float* x    = (const float*)d_in[0];
    const float* ln1g = (const float*)d_in[2];
    const float* ln1b = (const float*)d_in[3];
    const float* wq   = (const float*)d_in[4];
    const float* bq   = (const float*)d_in[5];
    const float* wk   = (const float*)d_in[6];
    const float* bk   = (const float*)d_in[7];
    const float* wvv  = (const float*)d_in[8];
    const float* bv   = (const float*)d_in[9];
    const float* wo   = (const float*)d_in[10];
    const float* bo   = (const float*)d_in[11];
    const float* wpos = (const float*)d_in[12];
    const float* pbu  = (const float*)d_in[13];
    const float* pbv  = (const float*)d_in[14];
    const float* ln2g = (const float*)d_in[15];
    const float* ln2b = (const float*)d_in[16];
    const float* w1   = (const float*)d_in[17];
    const float* b1   = (const float*)d_in[18];
    const float* w2   = (const float*)d_in[19];
    const float* b2   = (const float*)d_in[20];

    const int NTOK = BB*TT;            // 2000
    const int NELEM = NTOK*DD;         // 1,536,000

    float* x_cur = (float*)d_out;      // residual in d_out (fp32)

    // ws layout — total 30,544,896 B (ws is ~268 MB per harness fill counters)
    char* ws = (char*)d_ws;
    unsigned short* qbuf  = (unsigned short*)(ws);              // (b,h,t,d) q / mlp hidden
    unsigned short* kbuf  = (unsigned short*)(ws + 3072000);    // (b,h,t,d)
    unsigned short* vTbuf = (unsigned short*)(ws + 6144000);    // (b,h,d,t+128) 4,030,464 B
    unsigned short* hbuf  = (unsigned short*)(ws + 10174464);   // ln out / attn out
    unsigned short* ppbuf = (unsigned short*)(ws + 13246464);   // (h,n,d) 391,680 B
    unsigned short* pebuf = (unsigned short*)(ws + 13638144);   // 391,680 B
    unsigned short* wtbuf = (unsigned short*)(ws + 14029824);   // 14 * 1,179,648 B
    #define WT(t_,l_) (wtbuf + (size_t)((l_)*7 + (t_))*WELEM)

    dim3 blk(256);
    scale_kernel<<<(NELEM+255)/256, blk, 0, stream>>>(x, x_cur, NELEM);
    wconv_kernel<<<dim3(12,12,14), blk, 0, stream>>>(wq, wk, wvv, wo, wpos, w1, w2, wtbuf);
    pe_kernel<<<PEROWS, 384, 0, stream>>>(pebuf);

    dim3 gBig(16, 12);
    dim3 gQKV(16, 36);
    dim3 gPe(2, 12);
    dim3 gAttn(63, BB, HH);

    for (int l = 0; l < LL; ++l){
        long dl = (long)l*DD;
        long pl_ = (long)l*HH*DK;

        gemm_kernel<3><<<gPe, blk, 0, stream>>>(pebuf, WT(4,l), nullptr, ppbuf, nullptr, PEROWS, PEROWS);

        ln_kernel<<<NTOK, blk, 0, stream>>>(x_cur, ln1g + dl, ln1b + dl, hbuf);
        gemm_qkv_kernel<<<gQKV, blk, 0, stream>>>(hbuf, WT(0,l), bq + dl, bk + dl, bv + dl,
                                                  qbuf, kbuf, vTbuf);

        attn_kernel<<<gAttn, dim3(64), 0, stream>>>(qbuf, kbuf, vTbuf, ppbuf,
                                                    pbu + pl_, pbv + pl_, hbuf);

        gemm_kernel<2><<<gBig, blk, 0, stream>>>(hbuf, WT(3,l), bo + dl, nullptr, x_cur, NTOK, TT);

        ln_kernel<<<NTOK, blk, 0, stream>>>(x_cur, ln2g + dl, ln2b + dl, hbuf);
        gemm_kernel<1><<<gBig, blk, 0, stream>>>(hbuf, WT(5,l), b1 + dl, qbuf, nullptr, NTOK, TT);
        gemm_kernel<2><<<gBig, blk, 0, stream>>>(qbuf, WT(6,l), b2 + dl, nullptr, x_cur, NTOK, TT);
    }
}

// Round 9
// 358.948 us; speedup vs baseline: 2.1391x; 1.0817x over previous
//
#include <hip/hip_runtime.h>

// ---------------- constants ----------------
#define TT 1000
#define BB 2
#define DD 768
#define HH 12
#define DK 64
#define LL 2
#define WELEM 589824          // 768*768
#define PEROWS 255            // rel positions -127..127
#define VTP 1312              // t-stride in vT layout (with 128 margin both sides)
#define LDSZ 13824            // per-buffer elems: 128*72 + 64*72

typedef __bf16 bf16x8 __attribute__((ext_vector_type(8)));
typedef float floatx4 __attribute__((ext_vector_type(4)));

__device__ __constant__ int HALFW[12] = {3,7,15,31,63,127,3,7,15,31,63,127};

// ---------------- helpers ----------------
__device__ __forceinline__ float b2f(unsigned short u){
    union { unsigned int i; float f; } x; x.i = ((unsigned int)u) << 16; return x.f;
}
__device__ __forceinline__ unsigned short f2b(float f){
    union { float f; unsigned int i; } x; x.f = f;
    unsigned int i = x.i;
    i += 0x7fffu + ((i >> 16) & 1u);   // RNE
    return (unsigned short)(i >> 16);
}

// ---------------- x scale (float4) ----------------
__global__ __launch_bounds__(256)
void scale_kernel(const float* __restrict__ x, float* __restrict__ xc, int n4){
    int i = blockIdx.x*256 + threadIdx.x;
    if (i < n4){
        float4 v = ((const float4*)x)[i];
        v.x *= 27.712812921102035f; v.y *= 27.712812921102035f;
        v.z *= 27.712812921102035f; v.w *= 27.712812921102035f;
        ((float4*)xc)[i] = v;
    }
}

// ---------------- pe rows (pos = 127-row), bf16 ----------------
__global__ __launch_bounds__(384) void pe_kernel(unsigned short* __restrict__ pe){
    int row = blockIdx.x;
    int i = threadIdx.x;
    float pos = (float)(127 - row);
    float dv = expf((float)(2*i) * (-9.210340371976184f / 768.0f));
    float ang = pos * dv;
    pe[(size_t)row*DD + 2*i]   = f2b(sinf(ang));
    pe[(size_t)row*DD + 2*i+1] = f2b(cosf(ang));
}

// ---------------- weight convert+transpose: fp32 (K,N) -> bf16 (N,K), 14 slices ----------------
__global__ __launch_bounds__(256)
void wconv_kernel(const float* s0, const float* s1, const float* s2, const float* s3,
                  const float* s4, const float* s5, const float* s6,
                  unsigned short* __restrict__ dst){
    const float* srcs[7] = {s0,s1,s2,s3,s4,s5,s6};
    int z = blockIdx.z;
    const float* src = srcs[z % 7] + (size_t)(z / 7)*WELEM;
    unsigned short* d = dst + (size_t)z*WELEM;
    int k0 = blockIdx.x*64, n0 = blockIdx.y*64;
    __shared__ __align__(16) unsigned short tile[64][72];
    int r = threadIdx.x >> 2, c = threadIdx.x & 3;
    const float4* sp = (const float4*)(src + (size_t)(k0+r)*DD + n0 + c*16);
    float4 f0 = sp[0], f1 = sp[1], f2 = sp[2], f3 = sp[3];
    unsigned short u[16];
    u[0]=f2b(f0.x); u[1]=f2b(f0.y); u[2]=f2b(f0.z); u[3]=f2b(f0.w);
    u[4]=f2b(f1.x); u[5]=f2b(f1.y); u[6]=f2b(f1.z); u[7]=f2b(f1.w);
    u[8]=f2b(f2.x); u[9]=f2b(f2.y); u[10]=f2b(f2.z); u[11]=f2b(f2.w);
    u[12]=f2b(f3.x); u[13]=f2b(f3.y); u[14]=f2b(f3.z); u[15]=f2b(f3.w);
    *(int4*)&tile[r][c*16]   = *(int4*)&u[0];
    *(int4*)&tile[r][c*16+8] = *(int4*)&u[8];
    __syncthreads();
    unsigned short tmp[16];
    #pragma unroll
    for (int i=0;i<16;++i) tmp[i] = tile[c*16+i][r];
    int4* dp = (int4*)(d + (size_t)(n0+r)*DD + k0 + c*16);
    dp[0] = *(int4*)&tmp[0];
    dp[1] = *(int4*)&tmp[8];
}

// ---------------- LayerNorm: fp32 in -> bf16 out ----------------
__global__ __launch_bounds__(256)
void ln_kernel(const float* __restrict__ x, const float* __restrict__ g,
               const float* __restrict__ bb, unsigned short* __restrict__ out){
    int row = blockIdx.x;
    const float* xr = x + (size_t)row*DD;
    int tid = threadIdx.x;
    float v0 = xr[tid], v1 = xr[tid+256], v2 = xr[tid+512];
    float s = v0+v1+v2, ss = v0*v0+v1*v1+v2*v2;
    #pragma unroll
    for (int o=1;o<64;o<<=1){ s += __shfl_xor(s,o); ss += __shfl_xor(ss,o); }
    __shared__ float rs[4], rss[4];
    int wv = tid>>6, lane = tid&63;
    if (lane==0){ rs[wv]=s; rss[wv]=ss; }
    __syncthreads();
    s  = rs[0]+rs[1]+rs[2]+rs[3];
    ss = rss[0]+rss[1]+rss[2]+rss[3];
    float mean = s * (1.0f/768.0f);
    float var  = ss * (1.0f/768.0f) - mean*mean;
    float inv  = 1.0f / sqrtf(var + 1e-5f);
    unsigned short* orow = out + (size_t)row*DD;
    #pragma unroll
    for (int kk=0;kk<3;++kk){
        int i = tid + 256*kk;
        float v = (kk==0?v0:(kk==1?v1:v2));
        orow[i] = f2b((v - mean)*inv*g[i] + bb[i]);
    }
}

// ======== pipelined GEMM core: 128x64 tile, BK=64, dbuf LDS (stride 72), reg prefetch ========
#define GEMM_PIPE(A_, Bt_, n0_, M_)                                             \
    int tid = threadIdx.x;                                                      \
    int m0 = blockIdx.x*128;                                                    \
    int wv = tid>>6, lane = tid&63;                                             \
    int quad = lane>>4, l16 = lane&15;                                          \
    int ar = tid>>2;                                                            \
    int ac = (tid&3)*16;                                                        \
    floatx4 acc[2][4];                                                          \
    _Pragma("unroll")                                                           \
    for (int mi=0;mi<2;++mi)                                                    \
      _Pragma("unroll")                                                         \
      for (int ni=0;ni<4;++ni) acc[mi][ni] = (floatx4){0.f,0.f,0.f,0.f};        \
    {                                                                           \
      int r0 = m0 + ar;      if (r0 > (M_)-1) r0 = (M_)-1;                      \
      int r1 = m0 + 64 + ar; if (r1 > (M_)-1) r1 = (M_)-1;                      \
      const unsigned short* Ap0 = (A_) + (size_t)r0*768 + ac;                   \
      const unsigned short* Ap1 = (A_) + (size_t)r1*768 + ac;                   \
      const unsigned short* Bpp = (Bt_) + (size_t)((n0_)+ar)*768 + ac;          \
      int4 pa0 = *(const int4*)Ap0, pa1 = *(const int4*)(Ap0+8);                \
      int4 pa2 = *(const int4*)Ap1, pa3 = *(const int4*)(Ap1+8);                \
      int4 pb0 = *(const int4*)Bpp, pb1 = *(const int4*)(Bpp+8);                \
      for (int s=0; s<12; ++s){                                                 \
        unsigned short* Asb = sh + (s&1)*LDSZ;                                  \
        unsigned short* Bsb = Asb + 9216;                                       \
        *(int4*)&Asb[ar*72 + ac]        = pa0;                                  \
        *(int4*)&Asb[ar*72 + ac + 8]    = pa1;                                  \
        *(int4*)&Asb[(64+ar)*72 + ac]   = pa2;                                  \
        *(int4*)&Asb[(64+ar)*72 + ac+8] = pa3;                                  \
        *(int4*)&Bsb[ar*72 + ac]        = pb0;                                  \
        *(int4*)&Bsb[ar*72 + ac + 8]    = pb1;                                  \
        __syncthreads();                                                        \
        if (s < 11){                                                            \
          int off = (s+1)*64;                                                   \
          pa0 = *(const int4*)(Ap0+off); pa1 = *(const int4*)(Ap0+off+8);       \
          pa2 = *(const int4*)(Ap1+off); pa3 = *(const int4*)(Ap1+off+8);       \
          pb0 = *(const int4*)(Bpp+off); pb1 = *(const int4*)(Bpp+off+8);       \
        }                                                                       \
        _Pragma("unroll")                                                       \
        for (int kh=0; kh<2; ++kh){                                             \
          bf16x8 af0 = *(const bf16x8*)&Asb[(32*wv + l16)*72 + kh*32 + quad*8]; \
          bf16x8 af1 = *(const bf16x8*)&Asb[(32*wv + 16 + l16)*72 + kh*32 + quad*8]; \
          _Pragma("unroll")                                                     \
          for (int ni=0; ni<4; ++ni){                                           \
            bf16x8 bfv = *(const bf16x8*)&Bsb[(16*ni + l16)*72 + kh*32 + quad*8]; \
            acc[0][ni] = __builtin_amdgcn_mfma_f32_16x16x32_bf16(af0, bfv, acc[0][ni], 0,0,0); \
            acc[1][ni] = __builtin_amdgcn_mfma_f32_16x16x32_bf16(af1, bfv, acc[1][ni], 0,0,0); \
          }                                                                     \
        }                                                                       \
      }                                                                         \
    }

// ---------------- standalone GEMM (N=768) ----------------
// MODE 1: bf16(gelu). MODE 2: resid +=. MODE 3: (b,h,r,d) scatter (rpb rows per batch).
template<int MODE>
__global__ __launch_bounds__(256)
void gemm_kernel(const unsigned short* __restrict__ A, const unsigned short* __restrict__ Bt,
                 const float* __restrict__ bias, unsigned short* __restrict__ outb,
                 float* __restrict__ resid, int M, int rpb){
    __shared__ __align__(16) unsigned short sh[2*LDSZ];
    int n0 = blockIdx.y*64;
    GEMM_PIPE(A, Bt, n0, M)
    float bfv_[4];
    #pragma unroll
    for (int ni=0;ni<4;++ni) bfv_[ni] = bias ? bias[n0 + 16*ni + l16] : 0.0f;
    #pragma unroll
    for (int mi=0;mi<2;++mi){
        #pragma unroll
        for (int rr=0;rr<4;++rr){
            int row = m0 + 32*wv + 16*mi + 4*quad + rr;
            if (row >= M) continue;
            int bb_ = 0, r_ = row;
            if (MODE == 3){ bb_ = row / rpb; r_ = row - bb_*rpb; }
            #pragma unroll
            for (int ni=0;ni<4;++ni){
                int col = n0 + 16*ni + l16;
                float v = acc[mi][ni][rr] + bfv_[ni];
                if (MODE == 1)      outb[(size_t)row*768 + col] = f2b(0.5f*v*(1.0f + erff(v*0.70710678118654752f)));
                else if (MODE == 2) resid[(size_t)row*768 + col] += v;
                else {
                    int h = col >> 6, d = col & 63;
                    outb[(((size_t)(bb_*HH + h))*rpb + r_)*DK + d] = f2b(v);
                }
            }
        }
    }
}

// ---------------- fused QKV GEMM: q,k -> (b,h,t,d); v -> (b,h,d,t+128) margin layout ----------------
__global__ __launch_bounds__(256)
void gemm_qkv_kernel(const unsigned short* __restrict__ A, const unsigned short* __restrict__ Bt,
                     const float* __restrict__ bq, const float* __restrict__ bk, const float* __restrict__ bv,
                     unsigned short* __restrict__ qout, unsigned short* __restrict__ kout,
                     unsigned short* __restrict__ vout){
    __shared__ __align__(16) unsigned short sh[2*LDSZ];
    int n0 = blockIdx.y*64;
    GEMM_PIPE(A, Bt, n0, 2000)
    int sec = blockIdx.y / 12;            // 0=q 1=k 2=v
    int col0 = n0 - sec*768;
    int h = col0 >> 6;
    const float* bias = (sec==0) ? bq : (sec==1) ? bk : bv;
    float bfv_[4];
    #pragma unroll
    for (int ni=0;ni<4;++ni) bfv_[ni] = bias[col0 + 16*ni + l16];
    if (sec != 2){
        unsigned short* outp = (sec==0) ? qout : kout;
        #pragma unroll
        for (int mi=0;mi<2;++mi){
            #pragma unroll
            for (int rr=0;rr<4;++rr){
                int row = m0 + 32*wv + 16*mi + 4*quad + rr;
                if (row >= 2000) continue;
                int b = row / TT, tl = row - b*TT;
                #pragma unroll
                for (int ni=0;ni<4;++ni){
                    int d = 16*ni + l16;
                    outp[(((size_t)(b*HH + h))*TT + tl)*DK + d] = f2b(acc[mi][ni][rr] + bfv_[ni]);
                }
            }
        }
    } else {
        // V: acc tile -> LDS (stride 66; last K-step used buf1 -> safe), then (d,t+128) store
        #pragma unroll
        for (int mi=0;mi<2;++mi)
            #pragma unroll
            for (int rr=0;rr<4;++rr){
                int rt = 32*wv + 16*mi + 4*quad + rr;
                #pragma unroll
                for (int ni=0;ni<4;++ni)
                    sh[rt*66 + 16*ni + l16] = f2b(acc[mi][ni][rr] + bfv_[ni]);
            }
        __syncthreads();
        #pragma unroll
        for (int it=0; it<32; ++it){
            int idx = it*256 + tid;
            int d = idx >> 7, rt = idx & 127;
            int row = m0 + rt;
            if (row < 2000){
                int b = row / TT, tl = row - b*TT;
                vout[(((size_t)(b*HH + h))*DK + d)*VTP + tl + 128] = sh[rt*66 + d];
            }
        }
    }
}

// ---------------- MFMA banded rel-pos attention: 4 waves cooperate on one 16-row t-tile ----------------
__global__ __launch_bounds__(256)
void attn_kernel(const unsigned short* __restrict__ q, const unsigned short* __restrict__ k,
                 const unsigned short* __restrict__ vT, const unsigned short* __restrict__ pp,
                 const float* __restrict__ pbu, const float* __restrict__ pbv,
                 unsigned short* __restrict__ out){
    int b = blockIdx.y, h = blockIdx.z;
    int t0 = blockIdx.x * 16;
    int w2 = HALFW[h];
    int tid = threadIdx.x;
    int wv = tid >> 6, lane = tid & 63;
    int l16 = lane & 15, quad = lane >> 4;

    const unsigned short* qB = q  + ((size_t)(b*HH + h))*TT*DK;
    const unsigned short* kB = k  + ((size_t)(b*HH + h))*TT*DK;
    const unsigned short* vB = vT + ((size_t)(b*HH + h))*DK*VTP;
    const unsigned short* pB = pp + (size_t)h*PEROWS*DK;

    __shared__ __align__(16) float bd[16*260];
    __shared__ __align__(16) unsigned short pl[16*328];
    __shared__ float mxs[4][16];
    __shared__ float sms[4][16];

    // Q fragments (each wave computes the same — cheap)
    int tq = t0 + l16; if (tq > TT-1) tq = TT-1;
    union { int4 i; unsigned short u[8]; } r0, r1;
    r0.i = *(const int4*)(qB + (size_t)tq*DK + quad*8);
    r1.i = *(const int4*)(qB + (size_t)tq*DK + 32 + quad*8);
    const float* pu = pbu + h*DK + quad*8;
    const float* pv = pbv + h*DK + quad*8;
    union { unsigned short u[8]; bf16x8 v; } qu0, qu1, qv0, qv1;
    #pragma unroll
    for (int i=0;i<8;++i){
        float a0 = b2f(r0.u[i]), a1 = b2f(r1.u[i]);
        qu0.u[i] = f2b(a0 + pu[i]);
        qu1.u[i] = f2b(a1 + pu[32+i]);
        qv0.u[i] = f2b(a0 + pv[i]);
        qv1.u[i] = f2b(a1 + pv[32+i]);
    }

    // BD = Qv @ pp^T over n-window, tiles strided across waves
    int Nn = 2*w2 + 1;
    int ntiles = (Nn + 15) >> 4;
    for (int ti = wv; ti < ntiles; ti += 4){
        int n = 127 - w2 + ti*16 + l16; if (n > PEROWS-1) n = PEROWS-1;
        const unsigned short* pr = pB + (size_t)n*DK + quad*8;
        bf16x8 pb0 = *(const bf16x8*)pr;
        bf16x8 pb1 = *(const bf16x8*)(pr + 32);
        floatx4 a = {0.f,0.f,0.f,0.f};
        a = __builtin_amdgcn_mfma_f32_16x16x32_bf16(qv0.v, pb0, a, 0,0,0);
        a = __builtin_amdgcn_mfma_f32_16x16x32_bf16(qv1.v, pb1, a, 0,0,0);
        #pragma unroll
        for (int r=0;r<4;++r) bd[(quad*4+r)*260 + ti*16 + l16] = a[r];
    }
    // cooperative zero-fill of pl (read only after barrier 2)
    for (int i = tid; i < 16*328/4; i += 256)
        ((unsigned long long*)pl)[i] = 0ULL;
    __syncthreads();                                     // barrier 1: bd + pl zeros visible

    // AC = Qu @ K^T; s-tiles strided across waves (max 5 per wave, fixed unroll)
    int Ns = 2*w2 + 16;
    int stiles = (Ns + 15) >> 4;
    int s_lo = t0 - w2;
    float scv[5][4];
    float mx[4] = {-1e30f,-1e30f,-1e30f,-1e30f};
    #pragma unroll
    for (int ii = 0; ii < 5; ++ii){
        int ti = wv + ii*4;
        if (ti < stiles){
            int s = s_lo + ti*16 + l16;
            int sc = s < 0 ? 0 : (s > TT-1 ? TT-1 : s);
            const unsigned short* kr = kB + (size_t)sc*DK + quad*8;
            bf16x8 kb0 = *(const bf16x8*)kr;
            bf16x8 kb1 = *(const bf16x8*)(kr + 32);
            floatx4 a = {0.f,0.f,0.f,0.f};
            a = __builtin_amdgcn_mfma_f32_16x16x32_bf16(qu0.v, kb0, a, 0,0,0);
            a = __builtin_amdgcn_mfma_f32_16x16x32_bf16(qu1.v, kb1, a, 0,0,0);
            #pragma unroll
            for (int r=0;r<4;++r){
                int row = quad*4 + r;
                int nrel = ti*16 + l16 - row;
                bool ok = (nrel >= 0) && (nrel <= 2*w2) && (s >= 0) && (s <= TT-1);
                int idx = row*260 + nrel;
                idx = idx < 0 ? 0 : (idx > 16*260-1 ? 16*260-1 : idx);
                float bdv = bd[idx];
                float sc_ = ok ? (a[r] + bdv) * 0.125f : -1e30f;
                scv[ii][r] = sc_;
                mx[r] = fmaxf(mx[r], sc_);
            }
        } else {
            #pragma unroll
            for (int r=0;r<4;++r) scv[ii][r] = -1e30f;
        }
    }
    #pragma unroll
    for (int off=1; off<16; off<<=1){
        #pragma unroll
        for (int r=0;r<4;++r) mx[r] = fmaxf(mx[r], __shfl_xor(mx[r], off));
    }
    if (l16 == 0){
        #pragma unroll
        for (int r=0;r<4;++r) mxs[wv][quad*4+r] = mx[r];
    }
    __syncthreads();                                     // barrier 2: mxs visible, pl zeros stable
    float gmx[4];
    #pragma unroll
    for (int r=0;r<4;++r){
        int row = quad*4 + r;
        gmx[r] = fmaxf(fmaxf(mxs[0][row], mxs[1][row]), fmaxf(mxs[2][row], mxs[3][row]));
    }

    int s0a = s_lo & ~31;
    int pad_lo = s_lo - s0a;
    int ktiles = (pad_lo + Ns + 31) >> 5;

    float sm[4] = {0.f,0.f,0.f,0.f};
    #pragma unroll
    for (int ii = 0; ii < 5; ++ii){
        int ti = wv + ii*4;
        if (ti < stiles){
            #pragma unroll
            for (int r=0;r<4;++r){
                float e = __expf(scv[ii][r] - gmx[r]);   // masked entries: exp(-1e30-g)=0
                sm[r] += e;
                pl[(quad*4+r)*328 + pad_lo + ti*16 + l16] = f2b(e);
            }
        }
    }
    #pragma unroll
    for (int off=1; off<16; off<<=1){
        #pragma unroll
        for (int r=0;r<4;++r) sm[r] += __shfl_xor(sm[r], off);
    }
    if (l16 == 0){
        #pragma unroll
        for (int r=0;r<4;++r) sms[wv][quad*4+r] = sm[r];
    }
    __syncthreads();                                     // barrier 3: pl e-values + sms visible

    // PV: wave wv owns d-block dt=wv; P unnormalized, apply rinv at the end
    floatx4 oacc = {0.f,0.f,0.f,0.f};
    for (int kt = 0; kt < ktiles; ++kt){
        bf16x8 pa = *(const bf16x8*)&pl[l16*328 + kt*32 + quad*8];
        int sidx = s0a + kt*32 + quad*8 + 128;
        bf16x8 vb = *(const bf16x8*)(vB + (size_t)(wv*16 + l16)*VTP + sidx);
        oacc = __builtin_amdgcn_mfma_f32_16x16x32_bf16(pa, vb, oacc, 0,0,0);
    }
    #pragma unroll
    for (int r=0;r<4;++r){
        int row = quad*4 + r;
        float sum = sms[0][row] + sms[1][row] + sms[2][row] + sms[3][row];
        float rinv = sum > 0.f ? 1.0f/sum : 0.0f;
        int t = t0 + row;
        if (t <= TT-1)
            out[(((size_t)(b*TT + t))*HH + h)*DK + wv*16 + l16] = f2b(oacc[r] * rinv);
    }
}

// ---------------- launcher ----------------
extern "C" void kernel_launch(void* const* d_in, const int* in_sizes, int n_in,
                              void* d_out, int out_size, void* d_ws, size_t ws_size,
                              hipStream_t stream){
    const float* x    = (const float*)d_in[0];
    const float* ln1g = (const float*)d_in[2];
    const float* ln1b = (const float*)d_in[3];
    const float* wq   = (const float*)d_in[4];
    const float* bq   = (const float*)d_in[5];
    const float* wk   = (const float*)d_in[6];
    const float* bk   = (const float*)d_in[7];
    const float* wvv  = (const float*)d_in[8];
    const float* bv   = (const float*)d_in[9];
    const float* wo   = (const float*)d_in[10];
    const float* bo   = (const float*)d_in[11];
    const float* wpos = (const float*)d_in[12];
    const float* pbu  = (const float*)d_in[13];
    const float* pbv  = (const float*)d_in[14];
    const float* ln2g = (const float*)d_in[15];
    const float* ln2b = (const float*)d_in[16];
    const float* w1   = (const float*)d_in[17];
    const float* b1   = (const float*)d_in[18];
    const float* w2   = (const float*)d_in[19];
    const float* b2   = (const float*)d_in[20];

    const int NTOK = BB*TT;            // 2000
    const int NELEM = NTOK*DD;         // 1,536,000

    float* x_cur = (float*)d_out;      // residual in d_out (fp32)

    // ws layout — total 30,544,896 B (ws is ~268 MB per harness fill counters)
    char* ws = (char*)d_ws;
    unsigned short* qbuf  = (unsigned short*)(ws);              // (b,h,t,d) q / mlp hidden
    unsigned short* kbuf  = (unsigned short*)(ws + 3072000);    // (b,h,t,d)
    unsigned short* vTbuf = (unsigned short*)(ws + 6144000);    // (b,h,d,t+128) 4,030,464 B
    unsigned short* hbuf  = (unsigned short*)(ws + 10174464);   // ln out / attn out
    unsigned short* ppbuf = (unsigned short*)(ws + 13246464);   // (h,n,d) 391,680 B
    unsigned short* pebuf = (unsigned short*)(ws + 13638144);   // 391,680 B
    unsigned short* wtbuf = (unsigned short*)(ws + 14029824);   // 14 * 1,179,648 B
    #define WT(t_,l_) (wtbuf + (size_t)((l_)*7 + (t_))*WELEM)

    dim3 blk(256);
    scale_kernel<<<(NELEM/4+255)/256, blk, 0, stream>>>(x, x_cur, NELEM/4);
    wconv_kernel<<<dim3(12,12,14), blk, 0, stream>>>(wq, wk, wvv, wo, wpos, w1, w2, wtbuf);
    pe_kernel<<<PEROWS, 384, 0, stream>>>(pebuf);

    dim3 gBig(16, 12);
    dim3 gQKV(16, 36);
    dim3 gPe(2, 12);
    dim3 gAttn(63, BB, HH);

    for (int l = 0; l < LL; ++l){
        long dl = (long)l*DD;
        long pl_ = (long)l*HH*DK;

        gemm_kernel<3><<<gPe, blk, 0, stream>>>(pebuf, WT(4,l), nullptr, ppbuf, nullptr, PEROWS, PEROWS);

        ln_kernel<<<NTOK, blk, 0, stream>>>(x_cur, ln1g + dl, ln1b + dl, hbuf);
        gemm_qkv_kernel<<<gQKV, blk, 0, stream>>>(hbuf, WT(0,l), bq + dl, bk + dl, bv + dl,
                                                  qbuf, kbuf, vTbuf);

        attn_kernel<<<gAttn, blk, 0, stream>>>(qbuf, kbuf, vTbuf, ppbuf,
                                               pbu + pl_, pbv + pl_, hbuf);

        gemm_kernel<2><<<gBig, blk, 0, stream>>>(hbuf, WT(3,l), bo + dl, nullptr, x_cur, NTOK, TT);

        ln_kernel<<<NTOK, blk, 0, stream>>>(x_cur, ln2g + dl, ln2b + dl, hbuf);
        gemm_kernel<1><<<gBig, blk, 0, stream>>>(hbuf, WT(5,l), b1 + dl, qbuf, nullptr, NTOK, TT);
        gemm_kernel<2><<<gBig, blk, 0, stream>>>(qbuf, WT(6,l), b2 + dl, nullptr, x_cur, NTOK, TT);
    }
}

// Round 10
// 352.440 us; speedup vs baseline: 2.1786x; 1.0185x over previous
//
#include <hip/hip_runtime.h>

// ---------------- constants ----------------
#define TT 1000
#define BB 2
#define DD 768
#define HH 12
#define DK 64
#define LL 2
#define WELEM 589824          // 768*768
#define PEROWS 255            // rel positions -127..127
#define VTP 1312              // t-stride in vT layout (with 128 margin both sides)
#define LDSZ 13824            // per-buffer elems: 128*72 + 64*72
#define PPL 195840            // per-layer pp elems: HH*PEROWS*DK

typedef __bf16 bf16x8 __attribute__((ext_vector_type(8)));
typedef float floatx4 __attribute__((ext_vector_type(4)));

__device__ __constant__ int HALFW[12] = {3,7,15,31,63,127,3,7,15,31,63,127};
__device__ __constant__ int HORD[12]  = {5,11,4,10,3,9,2,8,1,7,0,6};   // heavy bands first

// ---------------- helpers ----------------
__device__ __forceinline__ float b2f(unsigned short u){
    union { unsigned int i; float f; } x; x.i = ((unsigned int)u) << 16; return x.f;
}
__device__ __forceinline__ unsigned short f2b(float f){
    union { float f; unsigned int i; } x; x.f = f;
    unsigned int i = x.i;
    i += 0x7fffu + ((i >> 16) & 1u);   // RNE
    return (unsigned short)(i >> 16);
}

// ---------------- x scale (float4) ----------------
__global__ __launch_bounds__(256)
void scale_kernel(const float* __restrict__ x, float* __restrict__ xc, int n4){
    int i = blockIdx.x*256 + threadIdx.x;
    if (i < n4){
        float4 v = ((const float4*)x)[i];
        v.x *= 27.712812921102035f; v.y *= 27.712812921102035f;
        v.z *= 27.712812921102035f; v.w *= 27.712812921102035f;
        ((float4*)xc)[i] = v;
    }
}

// ---------------- pe rows (pos = 127-row), bf16 ----------------
__global__ __launch_bounds__(384) void pe_kernel(unsigned short* __restrict__ pe){
    int row = blockIdx.x;
    int i = threadIdx.x;
    float pos = (float)(127 - row);
    float dv = expf((float)(2*i) * (-9.210340371976184f / 768.0f));
    float ang = pos * dv;
    pe[(size_t)row*DD + 2*i]   = f2b(sinf(ang));
    pe[(size_t)row*DD + 2*i+1] = f2b(cosf(ang));
}

// ---------------- weight convert+transpose: fp32 (K,N) -> bf16 (N,K), 14 slices ----------------
__global__ __launch_bounds__(256)
void wconv_kernel(const float* s0, const float* s1, const float* s2, const float* s3,
                  const float* s4, const float* s5, const float* s6,
                  unsigned short* __restrict__ dst){
    const float* srcs[7] = {s0,s1,s2,s3,s4,s5,s6};
    int z = blockIdx.z;
    const float* src = srcs[z % 7] + (size_t)(z / 7)*WELEM;
    unsigned short* d = dst + (size_t)z*WELEM;
    int k0 = blockIdx.x*64, n0 = blockIdx.y*64;
    __shared__ __align__(16) unsigned short tile[64][72];
    int r = threadIdx.x >> 2, c = threadIdx.x & 3;
    const float4* sp = (const float4*)(src + (size_t)(k0+r)*DD + n0 + c*16);
    float4 f0 = sp[0], f1 = sp[1], f2 = sp[2], f3 = sp[3];
    unsigned short u[16];
    u[0]=f2b(f0.x); u[1]=f2b(f0.y); u[2]=f2b(f0.z); u[3]=f2b(f0.w);
    u[4]=f2b(f1.x); u[5]=f2b(f1.y); u[6]=f2b(f1.z); u[7]=f2b(f1.w);
    u[8]=f2b(f2.x); u[9]=f2b(f2.y); u[10]=f2b(f2.z); u[11]=f2b(f2.w);
    u[12]=f2b(f3.x); u[13]=f2b(f3.y); u[14]=f2b(f3.z); u[15]=f2b(f3.w);
    *(int4*)&tile[r][c*16]   = *(int4*)&u[0];
    *(int4*)&tile[r][c*16+8] = *(int4*)&u[8];
    __syncthreads();
    unsigned short tmp[16];
    #pragma unroll
    for (int i=0;i<16;++i) tmp[i] = tile[c*16+i][r];
    int4* dp = (int4*)(d + (size_t)(n0+r)*DD + k0 + c*16);
    dp[0] = *(int4*)&tmp[0];
    dp[1] = *(int4*)&tmp[8];
}

// ---------------- LayerNorm: fp32 in -> bf16 out ----------------
__global__ __launch_bounds__(256)
void ln_kernel(const float* __restrict__ x, const float* __restrict__ g,
               const float* __restrict__ bb, unsigned short* __restrict__ out){
    int row = blockIdx.x;
    const float* xr = x + (size_t)row*DD;
    int tid = threadIdx.x;
    float v0 = xr[tid], v1 = xr[tid+256], v2 = xr[tid+512];
    float s = v0+v1+v2, ss = v0*v0+v1*v1+v2*v2;
    #pragma unroll
    for (int o=1;o<64;o<<=1){ s += __shfl_xor(s,o); ss += __shfl_xor(ss,o); }
    __shared__ float rs[4], rss[4];
    int wv = tid>>6, lane = tid&63;
    if (lane==0){ rs[wv]=s; rss[wv]=ss; }
    __syncthreads();
    s  = rs[0]+rs[1]+rs[2]+rs[3];
    ss = rss[0]+rss[1]+rss[2]+rss[3];
    float mean = s * (1.0f/768.0f);
    float var  = ss * (1.0f/768.0f) - mean*mean;
    float inv  = 1.0f / sqrtf(var + 1e-5f);
    unsigned short* orow = out + (size_t)row*DD;
    #pragma unroll
    for (int kk=0;kk<3;++kk){
        int i = tid + 256*kk;
        float v = (kk==0?v0:(kk==1?v1:v2));
        orow[i] = f2b((v - mean)*inv*g[i] + bb[i]);
    }
}

// ======== pipelined GEMM core: 128x64 tile, BK=64, dbuf LDS (stride 72), reg prefetch ========
// K0_: starting k offset; NS_: number of 64-wide K steps.
#define GEMM_PIPE(A_, Bt_, n0_, M_, K0_, NS_)                                   \
    int tid = threadIdx.x;                                                      \
    int m0 = blockIdx.x*128;                                                    \
    int wv = tid>>6, lane = tid&63;                                             \
    int quad = lane>>4, l16 = lane&15;                                          \
    int ar = tid>>2;                                                            \
    int ac = (tid&3)*16;                                                        \
    floatx4 acc[2][4];                                                          \
    _Pragma("unroll")                                                           \
    for (int mi=0;mi<2;++mi)                                                    \
      _Pragma("unroll")                                                         \
      for (int ni=0;ni<4;++ni) acc[mi][ni] = (floatx4){0.f,0.f,0.f,0.f};        \
    {                                                                           \
      int r0 = m0 + ar;      if (r0 > (M_)-1) r0 = (M_)-1;                      \
      int r1 = m0 + 64 + ar; if (r1 > (M_)-1) r1 = (M_)-1;                      \
      const unsigned short* Ap0 = (A_) + (size_t)r0*768 + (K0_) + ac;           \
      const unsigned short* Ap1 = (A_) + (size_t)r1*768 + (K0_) + ac;           \
      const unsigned short* Bpp = (Bt_) + (size_t)((n0_)+ar)*768 + (K0_) + ac;  \
      int4 pa0 = *(const int4*)Ap0, pa1 = *(const int4*)(Ap0+8);                \
      int4 pa2 = *(const int4*)Ap1, pa3 = *(const int4*)(Ap1+8);                \
      int4 pb0 = *(const int4*)Bpp, pb1 = *(const int4*)(Bpp+8);                \
      for (int s=0; s<(NS_); ++s){                                              \
        unsigned short* Asb = sh + (s&1)*LDSZ;                                  \
        unsigned short* Bsb = Asb + 9216;                                       \
        *(int4*)&Asb[ar*72 + ac]        = pa0;                                  \
        *(int4*)&Asb[ar*72 + ac + 8]    = pa1;                                  \
        *(int4*)&Asb[(64+ar)*72 + ac]   = pa2;                                  \
        *(int4*)&Asb[(64+ar)*72 + ac+8] = pa3;                                  \
        *(int4*)&Bsb[ar*72 + ac]        = pb0;                                  \
        *(int4*)&Bsb[ar*72 + ac + 8]    = pb1;                                  \
        __syncthreads();                                                        \
        if (s < (NS_)-1){                                                       \
          int off = (s+1)*64;                                                   \
          pa0 = *(const int4*)(Ap0+off); pa1 = *(const int4*)(Ap0+off+8);       \
          pa2 = *(const int4*)(Ap1+off); pa3 = *(const int4*)(Ap1+off+8);       \
          pb0 = *(const int4*)(Bpp+off); pb1 = *(const int4*)(Bpp+off+8);       \
        }                                                                       \
        _Pragma("unroll")                                                       \
        for (int kh=0; kh<2; ++kh){                                             \
          bf16x8 af0 = *(const bf16x8*)&Asb[(32*wv + l16)*72 + kh*32 + quad*8]; \
          bf16x8 af1 = *(const bf16x8*)&Asb[(32*wv + 16 + l16)*72 + kh*32 + quad*8]; \
          _Pragma("unroll")                                                     \
          for (int ni=0; ni<4; ++ni){                                           \
            bf16x8 bfv = *(const bf16x8*)&Bsb[(16*ni + l16)*72 + kh*32 + quad*8]; \
            acc[0][ni] = __builtin_amdgcn_mfma_f32_16x16x32_bf16(af0, bfv, acc[0][ni], 0,0,0); \
            acc[1][ni] = __builtin_amdgcn_mfma_f32_16x16x32_bf16(af1, bfv, acc[1][ni], 0,0,0); \
          }                                                                     \
        }                                                                       \
      }                                                                         \
    }

// ---------------- standalone GEMM (N=768) ----------------
// MODE 1: bf16(gelu), 12 steps. MODE 2: split-K over z (6 steps), atomicAdd into resid.
// MODE 3: pe-projection, z = layer, (h,n,d) scatter.
template<int MODE>
__global__ __launch_bounds__(256)
void gemm_kernel(const unsigned short* __restrict__ A, const unsigned short* __restrict__ Bt,
                 const float* __restrict__ bias, unsigned short* __restrict__ outb,
                 float* __restrict__ resid, int M){
    __shared__ __align__(16) unsigned short sh[2*LDSZ];
    int n0 = blockIdx.y*64;
    int zz = blockIdx.z;
    const unsigned short* Bt_ = Bt;
    unsigned short* outb_ = outb;
    int k0 = 0, ns = 12;
    if (MODE == 2){ k0 = zz*384; ns = 6; }
    if (MODE == 3){ Bt_ = Bt + (size_t)zz*7*WELEM; outb_ = outb + (size_t)zz*PPL; }
    GEMM_PIPE(A, Bt_, n0, M, k0, ns)
    float bfv_[4];
    #pragma unroll
    for (int ni=0;ni<4;++ni)
        bfv_[ni] = (bias && (MODE != 2 || zz == 0)) ? bias[n0 + 16*ni + l16] : 0.0f;
    #pragma unroll
    for (int mi=0;mi<2;++mi){
        #pragma unroll
        for (int rr=0;rr<4;++rr){
            int row = m0 + 32*wv + 16*mi + 4*quad + rr;
            if (row >= M) continue;
            #pragma unroll
            for (int ni=0;ni<4;++ni){
                int col = n0 + 16*ni + l16;
                float v = acc[mi][ni][rr] + bfv_[ni];
                if (MODE == 1)      outb_[(size_t)row*768 + col] = f2b(0.5f*v*(1.0f + erff(v*0.70710678118654752f)));
                else if (MODE == 2) atomicAdd(&resid[(size_t)row*768 + col], v);
                else {
                    int h = col >> 6, d = col & 63;
                    outb_[((size_t)h*PEROWS + row)*DK + d] = f2b(v);
                }
            }
        }
    }
}

// ---------------- fused QKV GEMM: q,k -> (b,h,t,d); v -> (b,h,d,t+128) margin layout ----------------
__global__ __launch_bounds__(256)
void gemm_qkv_kernel(const unsigned short* __restrict__ A, const unsigned short* __restrict__ Bt,
                     const float* __restrict__ bq, const float* __restrict__ bk, const float* __restrict__ bv,
                     unsigned short* __restrict__ qout, unsigned short* __restrict__ kout,
                     unsigned short* __restrict__ vout){
    __shared__ __align__(16) unsigned short sh[2*LDSZ];
    int n0 = blockIdx.y*64;
    GEMM_PIPE(A, Bt, n0, 2000, 0, 12)
    int sec = blockIdx.y / 12;            // 0=q 1=k 2=v
    int col0 = n0 - sec*768;
    int h = col0 >> 6;
    const float* bias = (sec==0) ? bq : (sec==1) ? bk : bv;
    float bfv_[4];
    #pragma unroll
    for (int ni=0;ni<4;++ni) bfv_[ni] = bias[col0 + 16*ni + l16];
    if (sec != 2){
        unsigned short* outp = (sec==0) ? qout : kout;
        #pragma unroll
        for (int mi=0;mi<2;++mi){
            #pragma unroll
            for (int rr=0;rr<4;++rr){
                int row = m0 + 32*wv + 16*mi + 4*quad + rr;
                if (row >= 2000) continue;
                int b = row / TT, tl = row - b*TT;
                #pragma unroll
                for (int ni=0;ni<4;++ni){
                    int d = 16*ni + l16;
                    outp[(((size_t)(b*HH + h))*TT + tl)*DK + d] = f2b(acc[mi][ni][rr] + bfv_[ni]);
                }
            }
        }
    } else {
        // V: acc tile -> LDS (stride 66; last K-step used buf1 -> safe), then (d,t+128) store
        #pragma unroll
        for (int mi=0;mi<2;++mi)
            #pragma unroll
            for (int rr=0;rr<4;++rr){
                int rt = 32*wv + 16*mi + 4*quad + rr;
                #pragma unroll
                for (int ni=0;ni<4;++ni)
                    sh[rt*66 + 16*ni + l16] = f2b(acc[mi][ni][rr] + bfv_[ni]);
            }
        __syncthreads();
        #pragma unroll
        for (int it=0; it<32; ++it){
            int idx = it*256 + tid;
            int d = idx >> 7, rt = idx & 127;
            int row = m0 + rt;
            if (row < 2000){
                int b = row / TT, tl = row - b*TT;
                vout[(((size_t)(b*HH + h))*DK + d)*VTP + tl + 128] = sh[rt*66 + d];
            }
        }
    }
}

// ---------------- MFMA banded rel-pos attention: 4 waves cooperate on one 16-row t-tile ----------------
__global__ __launch_bounds__(256)
void attn_kernel(const unsigned short* __restrict__ q, const unsigned short* __restrict__ k,
                 const unsigned short* __restrict__ vT, const unsigned short* __restrict__ pp,
                 const float* __restrict__ pbu, const float* __restrict__ pbv,
                 unsigned short* __restrict__ out){
    int b = blockIdx.y, h = HORD[blockIdx.z];
    int t0 = blockIdx.x * 16;
    int w2 = HALFW[h];
    int tid = threadIdx.x;
    int wv = tid >> 6, lane = tid & 63;
    int l16 = lane & 15, quad = lane >> 4;

    const unsigned short* qB = q  + ((size_t)(b*HH + h))*TT*DK;
    const unsigned short* kB = k  + ((size_t)(b*HH + h))*TT*DK;
    const unsigned short* vB = vT + ((size_t)(b*HH + h))*DK*VTP;
    const unsigned short* pB = pp + (size_t)h*PEROWS*DK;

    __shared__ __align__(16) float bd[16*260];
    __shared__ __align__(16) unsigned short pl[16*328];
    __shared__ float mxs[4][16];
    __shared__ float sms[4][16];

    int tq = t0 + l16; if (tq > TT-1) tq = TT-1;
    union { int4 i; unsigned short u[8]; } r0, r1;
    r0.i = *(const int4*)(qB + (size_t)tq*DK + quad*8);
    r1.i = *(const int4*)(qB + (size_t)tq*DK + 32 + quad*8);
    const float* pu = pbu + h*DK + quad*8;
    const float* pv = pbv + h*DK + quad*8;
    union { unsigned short u[8]; bf16x8 v; } qu0, qu1, qv0, qv1;
    #pragma unroll
    for (int i=0;i<8;++i){
        float a0 = b2f(r0.u[i]), a1 = b2f(r1.u[i]);
        qu0.u[i] = f2b(a0 + pu[i]);
        qu1.u[i] = f2b(a1 + pu[32+i]);
        qv0.u[i] = f2b(a0 + pv[i]);
        qv1.u[i] = f2b(a1 + pv[32+i]);
    }

    int Nn = 2*w2 + 1;
    int ntiles = (Nn + 15) >> 4;
    for (int ti = wv; ti < ntiles; ti += 4){
        int n = 127 - w2 + ti*16 + l16; if (n > PEROWS-1) n = PEROWS-1;
        const unsigned short* pr = pB + (size_t)n*DK + quad*8;
        bf16x8 pb0 = *(const bf16x8*)pr;
        bf16x8 pb1 = *(const bf16x8*)(pr + 32);
        floatx4 a = {0.f,0.f,0.f,0.f};
        a = __builtin_amdgcn_mfma_f32_16x16x32_bf16(qv0.v, pb0, a, 0,0,0);
        a = __builtin_amdgcn_mfma_f32_16x16x32_bf16(qv1.v, pb1, a, 0,0,0);
        #pragma unroll
        for (int r=0;r<4;++r) bd[(quad*4+r)*260 + ti*16 + l16] = a[r];
    }
    for (int i = tid; i < 16*328/4; i += 256)
        ((unsigned long long*)pl)[i] = 0ULL;
    __syncthreads();                                     // barrier 1

    int Ns = 2*w2 + 16;
    int stiles = (Ns + 15) >> 4;
    int s_lo = t0 - w2;
    float scv[5][4];
    float mx[4] = {-1e30f,-1e30f,-1e30f,-1e30f};
    #pragma unroll
    for (int ii = 0; ii < 5; ++ii){
        int ti = wv + ii*4;
        if (ti < stiles){
            int s = s_lo + ti*16 + l16;
            int sc = s < 0 ? 0 : (s > TT-1 ? TT-1 : s);
            const unsigned short* kr = kB + (size_t)sc*DK + quad*8;
            bf16x8 kb0 = *(const bf16x8*)kr;
            bf16x8 kb1 = *(const bf16x8*)(kr + 32);
            floatx4 a = {0.f,0.f,0.f,0.f};
            a = __builtin_amdgcn_mfma_f32_16x16x32_bf16(qu0.v, kb0, a, 0,0,0);
            a = __builtin_amdgcn_mfma_f32_16x16x32_bf16(qu1.v, kb1, a, 0,0,0);
            #pragma unroll
            for (int r=0;r<4;++r){
                int row = quad*4 + r;
                int nrel = ti*16 + l16 - row;
                bool ok = (nrel >= 0) && (nrel <= 2*w2) && (s >= 0) && (s <= TT-1);
                int idx = row*260 + nrel;
                idx = idx < 0 ? 0 : (idx > 16*260-1 ? 16*260-1 : idx);
                float bdv = bd[idx];
                float sc_ = ok ? (a[r] + bdv) * 0.125f : -1e30f;
                scv[ii][r] = sc_;
                mx[r] = fmaxf(mx[r], sc_);
            }
        } else {
            #pragma unroll
            for (int r=0;r<4;++r) scv[ii][r] = -1e30f;
        }
    }
    #pragma unroll
    for (int off=1; off<16; off<<=1){
        #pragma unroll
        for (int r=0;r<4;++r) mx[r] = fmaxf(mx[r], __shfl_xor(mx[r], off));
    }
    if (l16 == 0){
        #pragma unroll
        for (int r=0;r<4;++r) mxs[wv][quad*4+r] = mx[r];
    }
    __syncthreads();                                     // barrier 2
    float gmx[4];
    #pragma unroll
    for (int r=0;r<4;++r){
        int row = quad*4 + r;
        gmx[r] = fmaxf(fmaxf(mxs[0][row], mxs[1][row]), fmaxf(mxs[2][row], mxs[3][row]));
    }

    int s0a = s_lo & ~31;
    int pad_lo = s_lo - s0a;
    int ktiles = (pad_lo + Ns + 31) >> 5;

    float sm[4] = {0.f,0.f,0.f,0.f};
    #pragma unroll
    for (int ii = 0; ii < 5; ++ii){
        int ti = wv + ii*4;
        if (ti < stiles){
            #pragma unroll
            for (int r=0;r<4;++r){
                float e = __expf(scv[ii][r] - gmx[r]);
                sm[r] += e;
                pl[(quad*4+r)*328 + pad_lo + ti*16 + l16] = f2b(e);
            }
        }
    }
    #pragma unroll
    for (int off=1; off<16; off<<=1){
        #pragma unroll
        for (int r=0;r<4;++r) sm[r] += __shfl_xor(sm[r], off);
    }
    if (l16 == 0){
        #pragma unroll
        for (int r=0;r<4;++r) sms[wv][quad*4+r] = sm[r];
    }
    __syncthreads();                                     // barrier 3

    floatx4 oacc = {0.f,0.f,0.f,0.f};
    for (int kt = 0; kt < ktiles; ++kt){
        bf16x8 pa = *(const bf16x8*)&pl[l16*328 + kt*32 + quad*8];
        int sidx = s0a + kt*32 + quad*8 + 128;
        bf16x8 vb = *(const bf16x8*)(vB + (size_t)(wv*16 + l16)*VTP + sidx);
        oacc = __builtin_amdgcn_mfma_f32_16x16x32_bf16(pa, vb, oacc, 0,0,0);
    }
    #pragma unroll
    for (int r=0;r<4;++r){
        int row = quad*4 + r;
        float sum = sms[0][row] + sms[1][row] + sms[2][row] + sms[3][row];
        float rinv = sum > 0.f ? 1.0f/sum : 0.0f;
        int t = t0 + row;
        if (t <= TT-1)
            out[(((size_t)(b*TT + t))*HH + h)*DK + wv*16 + l16] = f2b(oacc[r] * rinv);
    }
}

// ---------------- launcher ----------------
extern "C" void kernel_launch(void* const* d_in, const int* in_sizes, int n_in,
                              void* d_out, int out_size, void* d_ws, size_t ws_size,
                              hipStream_t stream){
    const float* x    = (const float*)d_in[0];
    const float* ln1g = (const float*)d_in[2];
    const float* ln1b = (const float*)d_in[3];
    const float* wq   = (const float*)d_in[4];
    const float* bq   = (const float*)d_in[5];
    const float* wk   = (const float*)d_in[6];
    const float* bk   = (const float*)d_in[7];
    const float* wvv  = (const float*)d_in[8];
    const float* bv   = (const float*)d_in[9];
    const float* wo   = (const float*)d_in[10];
    const float* bo   = (const float*)d_in[11];
    const float* wpos = (const float*)d_in[12];
    const float* pbu  = (const float*)d_in[13];
    const float* pbv  = (const float*)d_in[14];
    const float* ln2g = (const float*)d_in[15];
    const float* ln2b = (const float*)d_in[16];
    const float* w1   = (const float*)d_in[17];
    const float* b1   = (const float*)d_in[18];
    const float* w2   = (const float*)d_in[19];
    const float* b2   = (const float*)d_in[20];

    const int NTOK = BB*TT;            // 2000
    const int NELEM = NTOK*DD;         // 1,536,000

    float* x_cur = (float*)d_out;      // residual in d_out (fp32)

    // ws layout — total 30,936,576 B
    char* ws = (char*)d_ws;
    unsigned short* qbuf  = (unsigned short*)(ws);              // (b,h,t,d) q / mlp hidden
    unsigned short* kbuf  = (unsigned short*)(ws + 3072000);    // (b,h,t,d)
    unsigned short* vTbuf = (unsigned short*)(ws + 6144000);    // (b,h,d,t+128) 4,030,464 B
    unsigned short* hbuf  = (unsigned short*)(ws + 10174464);   // ln out / attn out
    unsigned short* ppbuf = (unsigned short*)(ws + 13246464);   // (l,h,n,d) 783,360 B
    unsigned short* pebuf = (unsigned short*)(ws + 14029824);   // 391,680 B
    unsigned short* wtbuf = (unsigned short*)(ws + 14421504);   // 14 * 1,179,648 B
    #define WT(t_,l_) (wtbuf + (size_t)((l_)*7 + (t_))*WELEM)

    dim3 blk(256);
    scale_kernel<<<(NELEM/4+255)/256, blk, 0, stream>>>(x, x_cur, NELEM/4);
    wconv_kernel<<<dim3(12,12,14), blk, 0, stream>>>(wq, wk, wvv, wo, wpos, w1, w2, wtbuf);
    pe_kernel<<<PEROWS, 384, 0, stream>>>(pebuf);
    // both layers' pos projections in one dispatch (z = layer)
    gemm_kernel<3><<<dim3(2,12,2), blk, 0, stream>>>(pebuf, WT(4,0), nullptr, ppbuf, nullptr, PEROWS);

    dim3 gBig(16, 12);
    dim3 gSplit(16, 12, 2);
    dim3 gQKV(16, 36);
    dim3 gAttn(63, BB, HH);

    for (int l = 0; l < LL; ++l){
        long dl = (long)l*DD;
        long pl_ = (long)l*HH*DK;

        ln_kernel<<<NTOK, blk, 0, stream>>>(x_cur, ln1g + dl, ln1b + dl, hbuf);
        gemm_qkv_kernel<<<gQKV, blk, 0, stream>>>(hbuf, WT(0,l), bq + dl, bk + dl, bv + dl,
                                                  qbuf, kbuf, vTbuf);

        attn_kernel<<<gAttn, blk, 0, stream>>>(qbuf, kbuf, vTbuf, ppbuf + (size_t)l*PPL,
                                               pbu + pl_, pbv + pl_, hbuf);

        gemm_kernel<2><<<gSplit, blk, 0, stream>>>(hbuf, WT(3,l), bo + dl, nullptr, x_cur, NTOK);

        ln_kernel<<<NTOK, blk, 0, stream>>>(x_cur, ln2g + dl, ln2b + dl, hbuf);
        gemm_kernel<1><<<gBig, blk, 0, stream>>>(hbuf, WT(5,l), b1 + dl, qbuf, nullptr, NTOK);
        gemm_kernel<2><<<gSplit, blk, 0, stream>>>(qbuf, WT(6,l), b2 + dl, nullptr, x_cur, NTOK);
    }
}

// Round 11
// 339.960 us; speedup vs baseline: 2.2586x; 1.0367x over previous
//
#include <hip/hip_runtime.h>

// ---------------- constants ----------------
#define TT 1000
#define BB 2
#define DD 768
#define HH 12
#define DK 64
#define LL 2
#define WELEM 589824          // 768*768
#define PEROWS 255            // rel positions -127..127
#define VTP 1312              // t-stride in vT layout (with 128 margin both sides)
#define LDSZ 13824            // per-buffer elems: 128*72 + 64*72
#define PPL 195840            // per-layer pp elems: HH*PEROWS*DK

typedef __bf16 bf16x8 __attribute__((ext_vector_type(8)));
typedef float floatx4 __attribute__((ext_vector_type(4)));

__device__ __constant__ int HALFW[12] = {3,7,15,31,63,127,3,7,15,31,63,127};
__device__ __constant__ int HORD[12]  = {5,11,4,10,3,9,2,8,1,7,0,6};   // heavy bands first

// ---------------- helpers ----------------
__device__ __forceinline__ float b2f(unsigned short u){
    union { unsigned int i; float f; } x; x.i = ((unsigned int)u) << 16; return x.f;
}
__device__ __forceinline__ unsigned short f2b(float f){
    union { float f; unsigned int i; } x; x.f = f;
    unsigned int i = x.i;
    i += 0x7fffu + ((i >> 16) & 1u);   // RNE
    return (unsigned short)(i >> 16);
}

// ---------------- merged preamble: z<14 wconv slice; z=14 x-scale; z=15 pe ----------------
__global__ __launch_bounds__(256)
void prep_kernel(const float* s0, const float* s1, const float* s2, const float* s3,
                 const float* s4, const float* s5, const float* s6,
                 unsigned short* __restrict__ dst,
                 const float* __restrict__ x, float* __restrict__ xc,
                 unsigned short* __restrict__ pe){
    int z = blockIdx.z;
    int tid = threadIdx.x;
    if (z < 14){
        const float* srcs[7] = {s0,s1,s2,s3,s4,s5,s6};
        const float* src = srcs[z % 7] + (size_t)(z / 7)*WELEM;
        unsigned short* d = dst + (size_t)z*WELEM;
        int k0 = blockIdx.x*64, n0 = blockIdx.y*64;
        __shared__ __align__(16) unsigned short tile[64][72];
        int r = tid >> 2, c = tid & 3;
        const float4* sp = (const float4*)(src + (size_t)(k0+r)*DD + n0 + c*16);
        float4 f0 = sp[0], f1 = sp[1], f2 = sp[2], f3 = sp[3];
        unsigned short u[16];
        u[0]=f2b(f0.x); u[1]=f2b(f0.y); u[2]=f2b(f0.z); u[3]=f2b(f0.w);
        u[4]=f2b(f1.x); u[5]=f2b(f1.y); u[6]=f2b(f1.z); u[7]=f2b(f1.w);
        u[8]=f2b(f2.x); u[9]=f2b(f2.y); u[10]=f2b(f2.z); u[11]=f2b(f2.w);
        u[12]=f2b(f3.x); u[13]=f2b(f3.y); u[14]=f2b(f3.z); u[15]=f2b(f3.w);
        *(int4*)&tile[r][c*16]   = *(int4*)&u[0];
        *(int4*)&tile[r][c*16+8] = *(int4*)&u[8];
        __syncthreads();
        unsigned short tmp[16];
        #pragma unroll
        for (int i=0;i<16;++i) tmp[i] = tile[c*16+i][r];
        int4* dp = (int4*)(d + (size_t)(n0+r)*DD + k0 + c*16);
        dp[0] = *(int4*)&tmp[0];
        dp[1] = *(int4*)&tmp[8];
    } else if (z == 14){
        int id = blockIdx.y*12 + blockIdx.x;          // 0..143
        for (int i = id*256 + tid; i < 384000; i += 36864){
            float4 v = ((const float4*)x)[i];
            v.x *= 27.712812921102035f; v.y *= 27.712812921102035f;
            v.z *= 27.712812921102035f; v.w *= 27.712812921102035f;
            ((float4*)xc)[i] = v;
        }
    } else {
        int bid = blockIdx.y*12 + blockIdx.x;         // 0..143
        #pragma unroll
        for (int rr = 0; rr < 2; ++rr){
            int row = bid*2 + rr;
            if (row < PEROWS){
                float pos = (float)(127 - row);
                int i = tid;
                float dv = expf((float)(2*i) * (-9.210340371976184f / 768.0f));
                float ang = pos * dv;
                pe[(size_t)row*DD + 2*i]   = f2b(sinf(ang));
                pe[(size_t)row*DD + 2*i+1] = f2b(cosf(ang));
                if (tid < 128){
                    int j = 256 + tid;
                    float dv2 = expf((float)(2*j) * (-9.210340371976184f / 768.0f));
                    float an2 = pos * dv2;
                    pe[(size_t)row*DD + 2*j]   = f2b(sinf(an2));
                    pe[(size_t)row*DD + 2*j+1] = f2b(cosf(an2));
                }
            }
        }
    }
}

// ---------------- LayerNorm: fp32 in -> bf16 out ----------------
__global__ __launch_bounds__(256)
void ln_kernel(const float* __restrict__ x, const float* __restrict__ g,
               const float* __restrict__ bb, unsigned short* __restrict__ out){
    int row = blockIdx.x;
    const float* xr = x + (size_t)row*DD;
    int tid = threadIdx.x;
    float v0 = xr[tid], v1 = xr[tid+256], v2 = xr[tid+512];
    float s = v0+v1+v2, ss = v0*v0+v1*v1+v2*v2;
    #pragma unroll
    for (int o=1;o<64;o<<=1){ s += __shfl_xor(s,o); ss += __shfl_xor(ss,o); }
    __shared__ float rs[4], rss[4];
    int wv = tid>>6, lane = tid&63;
    if (lane==0){ rs[wv]=s; rss[wv]=ss; }
    __syncthreads();
    s  = rs[0]+rs[1]+rs[2]+rs[3];
    ss = rss[0]+rss[1]+rss[2]+rss[3];
    float mean = s * (1.0f/768.0f);
    float var  = ss * (1.0f/768.0f) - mean*mean;
    float inv  = 1.0f / sqrtf(var + 1e-5f);
    unsigned short* orow = out + (size_t)row*DD;
    #pragma unroll
    for (int kk=0;kk<3;++kk){
        int i = tid + 256*kk;
        float v = (kk==0?v0:(kk==1?v1:v2));
        orow[i] = f2b((v - mean)*inv*g[i] + bb[i]);
    }
}

// ======== pipelined GEMM core: 128x64 tile, BK=64, dbuf LDS (stride 72), reg prefetch ========
#define GEMM_PIPE(A_, Bt_, n0_, M_, K0_, NS_)                                   \
    int tid = threadIdx.x;                                                      \
    int m0 = blockIdx.x*128;                                                    \
    int wv = tid>>6, lane = tid&63;                                             \
    int quad = lane>>4, l16 = lane&15;                                          \
    int ar = tid>>2;                                                            \
    int ac = (tid&3)*16;                                                        \
    floatx4 acc[2][4];                                                          \
    _Pragma("unroll")                                                           \
    for (int mi=0;mi<2;++mi)                                                    \
      _Pragma("unroll")                                                         \
      for (int ni=0;ni<4;++ni) acc[mi][ni] = (floatx4){0.f,0.f,0.f,0.f};        \
    {                                                                           \
      int r0 = m0 + ar;      if (r0 > (M_)-1) r0 = (M_)-1;                      \
      int r1 = m0 + 64 + ar; if (r1 > (M_)-1) r1 = (M_)-1;                      \
      const unsigned short* Ap0 = (A_) + (size_t)r0*768 + (K0_) + ac;           \
      const unsigned short* Ap1 = (A_) + (size_t)r1*768 + (K0_) + ac;           \
      const unsigned short* Bpp = (Bt_) + (size_t)((n0_)+ar)*768 + (K0_) + ac;  \
      int4 pa0 = *(const int4*)Ap0, pa1 = *(const int4*)(Ap0+8);                \
      int4 pa2 = *(const int4*)Ap1, pa3 = *(const int4*)(Ap1+8);                \
      int4 pb0 = *(const int4*)Bpp, pb1 = *(const int4*)(Bpp+8);                \
      for (int s=0; s<(NS_); ++s){                                              \
        unsigned short* Asb = sh + (s&1)*LDSZ;                                  \
        unsigned short* Bsb = Asb + 9216;                                       \
        *(int4*)&Asb[ar*72 + ac]        = pa0;                                  \
        *(int4*)&Asb[ar*72 + ac + 8]    = pa1;                                  \
        *(int4*)&Asb[(64+ar)*72 + ac]   = pa2;                                  \
        *(int4*)&Asb[(64+ar)*72 + ac+8] = pa3;                                  \
        *(int4*)&Bsb[ar*72 + ac]        = pb0;                                  \
        *(int4*)&Bsb[ar*72 + ac + 8]    = pb1;                                  \
        __syncthreads();                                                        \
        if (s < (NS_)-1){                                                       \
          int off = (s+1)*64;                                                   \
          pa0 = *(const int4*)(Ap0+off); pa1 = *(const int4*)(Ap0+off+8);       \
          pa2 = *(const int4*)(Ap1+off); pa3 = *(const int4*)(Ap1+off+8);       \
          pb0 = *(const int4*)(Bpp+off); pb1 = *(const int4*)(Bpp+off+8);       \
        }                                                                       \
        _Pragma("unroll")                                                       \
        for (int kh=0; kh<2; ++kh){                                             \
          bf16x8 af0 = *(const bf16x8*)&Asb[(32*wv + l16)*72 + kh*32 + quad*8]; \
          bf16x8 af1 = *(const bf16x8*)&Asb[(32*wv + 16 + l16)*72 + kh*32 + quad*8]; \
          _Pragma("unroll")                                                     \
          for (int ni=0; ni<4; ++ni){                                           \
            bf16x8 bfv = *(const bf16x8*)&Bsb[(16*ni + l16)*72 + kh*32 + quad*8]; \
            acc[0][ni] = __builtin_amdgcn_mfma_f32_16x16x32_bf16(af0, bfv, acc[0][ni], 0,0,0); \
            acc[1][ni] = __builtin_amdgcn_mfma_f32_16x16x32_bf16(af1, bfv, acc[1][ni], 0,0,0); \
          }                                                                     \
        }                                                                       \
      }                                                                         \
    }

// ---------------- standalone GEMM (N=768) ----------------
// MODE 1: bf16(gelu). MODE 2: resid += (plain, single-z). MODE 3: pe-projection, z = layer.
template<int MODE>
__global__ __launch_bounds__(256)
void gemm_kernel(const unsigned short* __restrict__ A, const unsigned short* __restrict__ Bt,
                 const float* __restrict__ bias, unsigned short* __restrict__ outb,
                 float* __restrict__ resid, int M){
    __shared__ __align__(16) unsigned short sh[2*LDSZ];
    int n0 = blockIdx.y*64;
    int zz = blockIdx.z;
    const unsigned short* Bt_ = Bt;
    unsigned short* outb_ = outb;
    if (MODE == 3){ Bt_ = Bt + (size_t)zz*7*WELEM; outb_ = outb + (size_t)zz*PPL; }
    GEMM_PIPE(A, Bt_, n0, M, 0, 12)
    float bfv_[4];
    #pragma unroll
    for (int ni=0;ni<4;++ni) bfv_[ni] = bias ? bias[n0 + 16*ni + l16] : 0.0f;
    #pragma unroll
    for (int mi=0;mi<2;++mi){
        #pragma unroll
        for (int rr=0;rr<4;++rr){
            int row = m0 + 32*wv + 16*mi + 4*quad + rr;
            if (row >= M) continue;
            #pragma unroll
            for (int ni=0;ni<4;++ni){
                int col = n0 + 16*ni + l16;
                float v = acc[mi][ni][rr] + bfv_[ni];
                if (MODE == 1)      outb_[(size_t)row*768 + col] = f2b(0.5f*v*(1.0f + erff(v*0.70710678118654752f)));
                else if (MODE == 2) resid[(size_t)row*768 + col] += v;
                else {
                    int h = col >> 6, d = col & 63;
                    outb_[((size_t)h*PEROWS + row)*DK + d] = f2b(v);
                }
            }
        }
    }
}

// ---------------- fused QKV GEMM: q,k -> (b,h,t,d); v -> (b,h,d,t+128) margin layout ----------------
__global__ __launch_bounds__(256)
void gemm_qkv_kernel(const unsigned short* __restrict__ A, const unsigned short* __restrict__ Bt,
                     const float* __restrict__ bq, const float* __restrict__ bk, const float* __restrict__ bv,
                     unsigned short* __restrict__ qout, unsigned short* __restrict__ kout,
                     unsigned short* __restrict__ vout){
    __shared__ __align__(16) unsigned short sh[2*LDSZ];
    int n0 = blockIdx.y*64;
    GEMM_PIPE(A, Bt, n0, 2000, 0, 12)
    int sec = blockIdx.y / 12;            // 0=q 1=k 2=v
    int col0 = n0 - sec*768;
    int h = col0 >> 6;
    const float* bias = (sec==0) ? bq : (sec==1) ? bk : bv;
    float bfv_[4];
    #pragma unroll
    for (int ni=0;ni<4;++ni) bfv_[ni] = bias[col0 + 16*ni + l16];
    if (sec != 2){
        unsigned short* outp = (sec==0) ? qout : kout;
        #pragma unroll
        for (int mi=0;mi<2;++mi){
            #pragma unroll
            for (int rr=0;rr<4;++rr){
                int row = m0 + 32*wv + 16*mi + 4*quad + rr;
                if (row >= 2000) continue;
                int b = row / TT, tl = row - b*TT;
                #pragma unroll
                for (int ni=0;ni<4;++ni){
                    int d = 16*ni + l16;
                    outp[(((size_t)(b*HH + h))*TT + tl)*DK + d] = f2b(acc[mi][ni][rr] + bfv_[ni]);
                }
            }
        }
    } else {
        // V: acc tile -> LDS (stride 66; last K-step used buf1 -> safe), then (d,t+128) store
        #pragma unroll
        for (int mi=0;mi<2;++mi)
            #pragma unroll
            for (int rr=0;rr<4;++rr){
                int rt = 32*wv + 16*mi + 4*quad + rr;
                #pragma unroll
                for (int ni=0;ni<4;++ni)
                    sh[rt*66 + 16*ni + l16] = f2b(acc[mi][ni][rr] + bfv_[ni]);
            }
        __syncthreads();
        #pragma unroll
        for (int it=0; it<32; ++it){
            int idx = it*256 + tid;
            int d = idx >> 7, rt = idx & 127;
            int row = m0 + rt;
            if (row < 2000){
                int b = row / TT, tl = row - b*TT;
                vout[(((size_t)(b*HH + h))*DK + d)*VTP + tl + 128] = sh[rt*66 + d];
            }
        }
    }
}

// ---------------- MFMA banded rel-pos attention: 4 waves cooperate on one 16-row t-tile ----------------
__global__ __launch_bounds__(256)
void attn_kernel(const unsigned short* __restrict__ q, const unsigned short* __restrict__ k,
                 const unsigned short* __restrict__ vT, const unsigned short* __restrict__ pp,
                 const float* __restrict__ pbu, const float* __restrict__ pbv,
                 unsigned short* __restrict__ out){
    int b = blockIdx.y, h = HORD[blockIdx.z];
    int t0 = blockIdx.x * 16;
    int w2 = HALFW[h];
    int tid = threadIdx.x;
    int wv = tid >> 6, lane = tid & 63;
    int l16 = lane & 15, quad = lane >> 4;

    const unsigned short* qB = q  + ((size_t)(b*HH + h))*TT*DK;
    const unsigned short* kB = k  + ((size_t)(b*HH + h))*TT*DK;
    const unsigned short* vB = vT + ((size_t)(b*HH + h))*DK*VTP;
    const unsigned short* pB = pp + (size_t)h*PEROWS*DK;

    __shared__ __align__(16) float bd[16*260];
    __shared__ __align__(16) unsigned short pl[16*328];
    __shared__ float mxs[4][16];
    __shared__ float sms[4][16];

    int tq = t0 + l16; if (tq > TT-1) tq = TT-1;
    union { int4 i; unsigned short u[8]; } r0, r1;
    r0.i = *(const int4*)(qB + (size_t)tq*DK + quad*8);
    r1.i = *(const int4*)(qB + (size_t)tq*DK + 32 + quad*8);
    const float* pu = pbu + h*DK + quad*8;
    const float* pv = pbv + h*DK + quad*8;
    union { unsigned short u[8]; bf16x8 v; } qu0, qu1, qv0, qv1;
    #pragma unroll
    for (int i=0;i<8;++i){
        float a0 = b2f(r0.u[i]), a1 = b2f(r1.u[i]);
        qu0.u[i] = f2b(a0 + pu[i]);
        qu1.u[i] = f2b(a1 + pu[32+i]);
        qv0.u[i] = f2b(a0 + pv[i]);
        qv1.u[i] = f2b(a1 + pv[32+i]);
    }

    int Nn = 2*w2 + 1;
    int ntiles = (Nn + 15) >> 4;
    for (int ti = wv; ti < ntiles; ti += 4){
        int n = 127 - w2 + ti*16 + l16; if (n > PEROWS-1) n = PEROWS-1;
        const unsigned short* pr = pB + (size_t)n*DK + quad*8;
        bf16x8 pb0 = *(const bf16x8*)pr;
        bf16x8 pb1 = *(const bf16x8*)(pr + 32);
        floatx4 a = {0.f,0.f,0.f,0.f};
        a = __builtin_amdgcn_mfma_f32_16x16x32_bf16(qv0.v, pb0, a, 0,0,0);
        a = __builtin_amdgcn_mfma_f32_16x16x32_bf16(qv1.v, pb1, a, 0,0,0);
        #pragma unroll
        for (int r=0;r<4;++r) bd[(quad*4+r)*260 + ti*16 + l16] = a[r];
    }
    for (int i = tid; i < 16*328/4; i += 256)
        ((unsigned long long*)pl)[i] = 0ULL;
    __syncthreads();                                     // barrier 1

    int Ns = 2*w2 + 16;
    int stiles = (Ns + 15) >> 4;
    int s_lo = t0 - w2;
    float scv[5][4];
    float mx[4] = {-1e30f,-1e30f,-1e30f,-1e30f};
    #pragma unroll
    for (int ii = 0; ii < 5; ++ii){
        int ti = wv + ii*4;
        if (ti < stiles){
            int s = s_lo + ti*16 + l16;
            int sc = s < 0 ? 0 : (s > TT-1 ? TT-1 : s);
            const unsigned short* kr = kB + (size_t)sc*DK + quad*8;
            bf16x8 kb0 = *(const bf16x8*)kr;
            bf16x8 kb1 = *(const bf16x8*)(kr + 32);
            floatx4 a = {0.f,0.f,0.f,0.f};
            a = __builtin_amdgcn_mfma_f32_16x16x32_bf16(qu0.v, kb0, a, 0,0,0);
            a = __builtin_amdgcn_mfma_f32_16x16x32_bf16(qu1.v, kb1, a, 0,0,0);
            #pragma unroll
            for (int r=0;r<4;++r){
                int row = quad*4 + r;
                int nrel = ti*16 + l16 - row;
                bool ok = (nrel >= 0) && (nrel <= 2*w2) && (s >= 0) && (s <= TT-1);
                int idx = row*260 + nrel;
                idx = idx < 0 ? 0 : (idx > 16*260-1 ? 16*260-1 : idx);
                float bdv = bd[idx];
                float sc_ = ok ? (a[r] + bdv) * 0.125f : -1e30f;
                scv[ii][r] = sc_;
                mx[r] = fmaxf(mx[r], sc_);
            }
        } else {
            #pragma unroll
            for (int r=0;r<4;++r) scv[ii][r] = -1e30f;
        }
    }
    #pragma unroll
    for (int off=1; off<16; off<<=1){
        #pragma unroll
        for (int r=0;r<4;++r) mx[r] = fmaxf(mx[r], __shfl_xor(mx[r], off));
    }
    if (l16 == 0){
        #pragma unroll
        for (int r=0;r<4;++r) mxs[wv][quad*4+r] = mx[r];
    }
    __syncthreads();                                     // barrier 2
    float gmx[4];
    #pragma unroll
    for (int r=0;r<4;++r){
        int row = quad*4 + r;
        gmx[r] = fmaxf(fmaxf(mxs[0][row], mxs[1][row]), fmaxf(mxs[2][row], mxs[3][row]));
    }

    int s0a = s_lo & ~31;
    int pad_lo = s_lo - s0a;
    int ktiles = (pad_lo + Ns + 31) >> 5;

    float sm[4] = {0.f,0.f,0.f,0.f};
    #pragma unroll
    for (int ii = 0; ii < 5; ++ii){
        int ti = wv + ii*4;
        if (ti < stiles){
            #pragma unroll
            for (int r=0;r<4;++r){
                float e = __expf(scv[ii][r] - gmx[r]);
                sm[r] += e;
                pl[(quad*4+r)*328 + pad_lo + ti*16 + l16] = f2b(e);
            }
        }
    }
    #pragma unroll
    for (int off=1; off<16; off<<=1){
        #pragma unroll
        for (int r=0;r<4;++r) sm[r] += __shfl_xor(sm[r], off);
    }
    if (l16 == 0){
        #pragma unroll
        for (int r=0;r<4;++r) sms[wv][quad*4+r] = sm[r];
    }
    __syncthreads();                                     // barrier 3

    floatx4 oacc = {0.f,0.f,0.f,0.f};
    for (int kt = 0; kt < ktiles; ++kt){
        bf16x8 pa = *(const bf16x8*)&pl[l16*328 + kt*32 + quad*8];
        int sidx = s0a + kt*32 + quad*8 + 128;
        bf16x8 vb = *(const bf16x8*)(vB + (size_t)(wv*16 + l16)*VTP + sidx);
        oacc = __builtin_amdgcn_mfma_f32_16x16x32_bf16(pa, vb, oacc, 0,0,0);
    }
    #pragma unroll
    for (int r=0;r<4;++r){
        int row = quad*4 + r;
        float sum = sms[0][row] + sms[1][row] + sms[2][row] + sms[3][row];
        float rinv = sum > 0.f ? 1.0f/sum : 0.0f;
        int t = t0 + row;
        if (t <= TT-1)
            out[(((size_t)(b*TT + t))*HH + h)*DK + wv*16 + l16] = f2b(oacc[r] * rinv);
    }
}

// ---------------- launcher ----------------
extern "C" void kernel_launch(void* const* d_in, const int* in_sizes, int n_in,
                              void* d_out, int out_size, void* d_ws, size_t ws_size,
                              hipStream_t stream){
    const float* x    = (const float*)d_in[0];
    const float* ln1g = (const float*)d_in[2];
    const float* ln1b = (const float*)d_in[3];
    const float* wq   = (const float*)d_in[4];
    const float* bq   = (const float*)d_in[5];
    const float* wk   = (const float*)d_in[6];
    const float* bk   = (const float*)d_in[7];
    const float* wvv  = (const float*)d_in[8];
    const float* bv   = (const float*)d_in[9];
    const float* wo   = (const float*)d_in[10];
    const float* bo   = (const float*)d_in[11];
    const float* wpos = (const float*)d_in[12];
    const float* pbu  = (const float*)d_in[13];
    const float* pbv  = (const float*)d_in[14];
    const float* ln2g = (const float*)d_in[15];
    const float* ln2b = (const float*)d_in[16];
    const float* w1   = (const float*)d_in[17];
    const float* b1   = (const float*)d_in[18];
    const float* w2   = (const float*)d_in[19];
    const float* b2   = (const float*)d_in[20];

    const int NTOK = BB*TT;            // 2000

    float* x_cur = (float*)d_out;      // residual in d_out (fp32)

    // ws layout — total 30,936,576 B
    char* ws = (char*)d_ws;
    unsigned short* qbuf  = (unsigned short*)(ws);              // (b,h,t,d) q / mlp hidden
    unsigned short* kbuf  = (unsigned short*)(ws + 3072000);    // (b,h,t,d)
    unsigned short* vTbuf = (unsigned short*)(ws + 6144000);    // (b,h,d,t+128) 4,030,464 B
    unsigned short* hbuf  = (unsigned short*)(ws + 10174464);   // ln out / attn out
    unsigned short* ppbuf = (unsigned short*)(ws + 13246464);   // (l,h,n,d) 783,360 B
    unsigned short* pebuf = (unsigned short*)(ws + 14029824);   // 391,680 B
    unsigned short* wtbuf = (unsigned short*)(ws + 14421504);   // 14 * 1,179,648 B
    #define WT(t_,l_) (wtbuf + (size_t)((l_)*7 + (t_))*WELEM)

    dim3 blk(256);
    // merged preamble: wconv (z<14) + scale (z=14) + pe (z=15)
    prep_kernel<<<dim3(12,12,16), blk, 0, stream>>>(wq, wk, wvv, wo, wpos, w1, w2,
                                                    wtbuf, x, x_cur, pebuf);
    // both layers' pos projections in one dispatch (z = layer)
    gemm_kernel<3><<<dim3(2,12,2), blk, 0, stream>>>(pebuf, WT(4,0), nullptr, ppbuf, nullptr, PEROWS);

    dim3 gBig(16, 12);
    dim3 gQKV(16, 36);
    dim3 gAttn(63, BB, HH);

    for (int l = 0; l < LL; ++l){
        long dl = (long)l*DD;
        long pl_ = (long)l*HH*DK;

        ln_kernel<<<NTOK, blk, 0, stream>>>(x_cur, ln1g + dl, ln1b + dl, hbuf);
        gemm_qkv_kernel<<<gQKV, blk, 0, stream>>>(hbuf, WT(0,l), bq + dl, bk + dl, bv + dl,
                                                  qbuf, kbuf, vTbuf);

        attn_kernel<<<gAttn, blk, 0, stream>>>(qbuf, kbuf, vTbuf, ppbuf + (size_t)l*PPL,
                                               pbu + pl_, pbv + pl_, hbuf);

        gemm_kernel<2><<<gBig, blk, 0, stream>>>(hbuf, WT(3,l), bo + dl, nullptr, x_cur, NTOK);

        ln_kernel<<<NTOK, blk, 0, stream>>>(x_cur, ln2g + dl, ln2b + dl, hbuf);
        gemm_kernel<1><<<gBig, blk, 0, stream>>>(hbuf, WT(5,l), b1 + dl, qbuf, nullptr, NTOK);
        gemm_kernel<2><<<gBig, blk, 0, stream>>>(qbuf, WT(6,l), b2 + dl, nullptr, x_cur, NTOK);
    }
}

// Round 12
// 316.436 us; speedup vs baseline: 2.4265x; 1.0743x over previous
//
#include <hip/hip_runtime.h>

// ---------------- constants ----------------
#define TT 1000
#define BB 2
#define DD 768
#define HH 12
#define DK 64
#define LL 2
#define WELEM 589824          // 768*768
#define PEROWS 255            // rel positions -127..127
#define VTP 1312              // t-stride in vT layout (with 128 margin both sides)
#define LDSZ2 9216            // per-buffer elems: 64*72 (A) + 64*72 (B)
#define PPL 195840            // per-layer pp elems: HH*PEROWS*DK

typedef __bf16 bf16x8 __attribute__((ext_vector_type(8)));
typedef float floatx4 __attribute__((ext_vector_type(4)));

__device__ __constant__ int HALFW[12] = {3,7,15,31,63,127,3,7,15,31,63,127};
__device__ __constant__ int HORD[12]  = {5,11,4,10,3,9,2,8,1,7,0,6};   // heavy bands first

// ---------------- helpers ----------------
__device__ __forceinline__ float b2f(unsigned short u){
    union { unsigned int i; float f; } x; x.i = ((unsigned int)u) << 16; return x.f;
}
__device__ __forceinline__ unsigned short f2b(float f){
    union { float f; unsigned int i; } x; x.f = f;
    unsigned int i = x.i;
    i += 0x7fffu + ((i >> 16) & 1u);   // RNE
    return (unsigned short)(i >> 16);
}

// ---------------- merged preamble: z<14 wconv slice; z=14 x-scale; z=15 pe ----------------
__global__ __launch_bounds__(256)
void prep_kernel(const float* s0, const float* s1, const float* s2, const float* s3,
                 const float* s4, const float* s5, const float* s6,
                 unsigned short* __restrict__ dst,
                 const float* __restrict__ x, float* __restrict__ xc,
                 unsigned short* __restrict__ pe){
    int z = blockIdx.z;
    int tid = threadIdx.x;
    if (z < 14){
        const float* srcs[7] = {s0,s1,s2,s3,s4,s5,s6};
        const float* src = srcs[z % 7] + (size_t)(z / 7)*WELEM;
        unsigned short* d = dst + (size_t)z*WELEM;
        int k0 = blockIdx.x*64, n0 = blockIdx.y*64;
        __shared__ __align__(16) unsigned short tile[64][72];
        int r = tid >> 2, c = tid & 3;
        const float4* sp = (const float4*)(src + (size_t)(k0+r)*DD + n0 + c*16);
        float4 f0 = sp[0], f1 = sp[1], f2 = sp[2], f3 = sp[3];
        unsigned short u[16];
        u[0]=f2b(f0.x); u[1]=f2b(f0.y); u[2]=f2b(f0.z); u[3]=f2b(f0.w);
        u[4]=f2b(f1.x); u[5]=f2b(f1.y); u[6]=f2b(f1.z); u[7]=f2b(f1.w);
        u[8]=f2b(f2.x); u[9]=f2b(f2.y); u[10]=f2b(f2.z); u[11]=f2b(f2.w);
        u[12]=f2b(f3.x); u[13]=f2b(f3.y); u[14]=f2b(f3.z); u[15]=f2b(f3.w);
        *(int4*)&tile[r][c*16]   = *(int4*)&u[0];
        *(int4*)&tile[r][c*16+8] = *(int4*)&u[8];
        __syncthreads();
        unsigned short tmp[16];
        #pragma unroll
        for (int i=0;i<16;++i) tmp[i] = tile[c*16+i][r];
        int4* dp = (int4*)(d + (size_t)(n0+r)*DD + k0 + c*16);
        dp[0] = *(int4*)&tmp[0];
        dp[1] = *(int4*)&tmp[8];
    } else if (z == 14){
        int id = blockIdx.y*12 + blockIdx.x;          // 0..143
        for (int i = id*256 + tid; i < 384000; i += 36864){
            float4 v = ((const float4*)x)[i];
            v.x *= 27.712812921102035f; v.y *= 27.712812921102035f;
            v.z *= 27.712812921102035f; v.w *= 27.712812921102035f;
            ((float4*)xc)[i] = v;
        }
    } else {
        int bid = blockIdx.y*12 + blockIdx.x;         // 0..143
        #pragma unroll
        for (int rr = 0; rr < 2; ++rr){
            int row = bid*2 + rr;
            if (row < PEROWS){
                float pos = (float)(127 - row);
                int i = tid;
                float dv = expf((float)(2*i) * (-9.210340371976184f / 768.0f));
                float ang = pos * dv;
                pe[(size_t)row*DD + 2*i]   = f2b(sinf(ang));
                pe[(size_t)row*DD + 2*i+1] = f2b(cosf(ang));
                if (tid < 128){
                    int j = 256 + tid;
                    float dv2 = expf((float)(2*j) * (-9.210340371976184f / 768.0f));
                    float an2 = pos * dv2;
                    pe[(size_t)row*DD + 2*j]   = f2b(sinf(an2));
                    pe[(size_t)row*DD + 2*j+1] = f2b(cosf(an2));
                }
            }
        }
    }
}

// ---------------- LayerNorm: fp32 in -> bf16 out ----------------
__global__ __launch_bounds__(256)
void ln_kernel(const float* __restrict__ x, const float* __restrict__ g,
               const float* __restrict__ bb, unsigned short* __restrict__ out){
    int row = blockIdx.x;
    const float* xr = x + (size_t)row*DD;
    int tid = threadIdx.x;
    float v0 = xr[tid], v1 = xr[tid+256], v2 = xr[tid+512];
    float s = v0+v1+v2, ss = v0*v0+v1*v1+v2*v2;
    #pragma unroll
    for (int o=1;o<64;o<<=1){ s += __shfl_xor(s,o); ss += __shfl_xor(ss,o); }
    __shared__ float rs[4], rss[4];
    int wv = tid>>6, lane = tid&63;
    if (lane==0){ rs[wv]=s; rss[wv]=ss; }
    __syncthreads();
    s  = rs[0]+rs[1]+rs[2]+rs[3];
    ss = rss[0]+rss[1]+rss[2]+rss[3];
    float mean = s * (1.0f/768.0f);
    float var  = ss * (1.0f/768.0f) - mean*mean;
    float inv  = 1.0f / sqrtf(var + 1e-5f);
    unsigned short* orow = out + (size_t)row*DD;
    #pragma unroll
    for (int kk=0;kk<3;++kk){
        int i = tid + 256*kk;
        float v = (kk==0?v0:(kk==1?v1:v2));
        orow[i] = f2b((v - mean)*inv*g[i] + bb[i]);
    }
}

// ======== pipelined GEMM core: 64x64 tile, BK=64, dbuf LDS (stride 72), reg prefetch ========
// 4 waves; wave wv computes rows 16wv..16wv+15 of the 64-row tile.
#define GEMM_PIPE64(A_, Bt_, n0_, M_)                                           \
    int tid = threadIdx.x;                                                      \
    int m0 = blockIdx.x*64;                                                     \
    int wv = tid>>6, lane = tid&63;                                             \
    int quad = lane>>4, l16 = lane&15;                                          \
    int ar = tid>>2;                                                            \
    int ac = (tid&3)*16;                                                        \
    floatx4 acc[4];                                                             \
    _Pragma("unroll")                                                           \
    for (int ni=0;ni<4;++ni) acc[ni] = (floatx4){0.f,0.f,0.f,0.f};              \
    {                                                                           \
      int r0 = m0 + ar;      if (r0 > (M_)-1) r0 = (M_)-1;                      \
      const unsigned short* Ap0 = (A_) + (size_t)r0*768 + ac;                   \
      const unsigned short* Bpp = (Bt_) + (size_t)((n0_)+ar)*768 + ac;          \
      int4 pa0 = *(const int4*)Ap0, pa1 = *(const int4*)(Ap0+8);                \
      int4 pb0 = *(const int4*)Bpp, pb1 = *(const int4*)(Bpp+8);                \
      for (int s=0; s<12; ++s){                                                 \
        unsigned short* Asb = sh + (s&1)*LDSZ2;                                 \
        unsigned short* Bsb = Asb + 4608;                                       \
        *(int4*)&Asb[ar*72 + ac]     = pa0;                                     \
        *(int4*)&Asb[ar*72 + ac + 8] = pa1;                                     \
        *(int4*)&Bsb[ar*72 + ac]     = pb0;                                     \
        *(int4*)&Bsb[ar*72 + ac + 8] = pb1;                                     \
        __syncthreads();                                                        \
        if (s < 11){                                                            \
          int off = (s+1)*64;                                                   \
          pa0 = *(const int4*)(Ap0+off); pa1 = *(const int4*)(Ap0+off+8);       \
          pb0 = *(const int4*)(Bpp+off); pb1 = *(const int4*)(Bpp+off+8);       \
        }                                                                       \
        _Pragma("unroll")                                                       \
        for (int kh=0; kh<2; ++kh){                                             \
          bf16x8 af = *(const bf16x8*)&Asb[(16*wv + l16)*72 + kh*32 + quad*8];  \
          _Pragma("unroll")                                                     \
          for (int ni=0; ni<4; ++ni){                                           \
            bf16x8 bfv = *(const bf16x8*)&Bsb[(16*ni + l16)*72 + kh*32 + quad*8]; \
            acc[ni] = __builtin_amdgcn_mfma_f32_16x16x32_bf16(af, bfv, acc[ni], 0,0,0); \
          }                                                                     \
        }                                                                       \
      }                                                                         \
    }

// ---------------- standalone GEMM (N=768) ----------------
// MODE 1: bf16(gelu). MODE 2: resid += (plain). MODE 3: pe-projection, z = layer.
template<int MODE>
__global__ __launch_bounds__(256)
void gemm_kernel(const unsigned short* __restrict__ A, const unsigned short* __restrict__ Bt,
                 const float* __restrict__ bias, unsigned short* __restrict__ outb,
                 float* __restrict__ resid, int M){
    __shared__ __align__(16) unsigned short sh[2*LDSZ2];
    int n0 = blockIdx.y*64;
    int zz = blockIdx.z;
    const unsigned short* Bt_ = Bt;
    unsigned short* outb_ = outb;
    if (MODE == 3){ Bt_ = Bt + (size_t)zz*7*WELEM; outb_ = outb + (size_t)zz*PPL; }
    GEMM_PIPE64(A, Bt_, n0, M)
    float bfv_[4];
    #pragma unroll
    for (int ni=0;ni<4;++ni) bfv_[ni] = bias ? bias[n0 + 16*ni + l16] : 0.0f;
    #pragma unroll
    for (int rr=0;rr<4;++rr){
        int row = m0 + 16*wv + 4*quad + rr;
        if (row >= M) continue;
        #pragma unroll
        for (int ni=0;ni<4;++ni){
            int col = n0 + 16*ni + l16;
            float v = acc[ni][rr] + bfv_[ni];
            if (MODE == 1)      outb_[(size_t)row*768 + col] = f2b(0.5f*v*(1.0f + erff(v*0.70710678118654752f)));
            else if (MODE == 2) resid[(size_t)row*768 + col] += v;
            else {
                int h = col >> 6, d = col & 63;
                outb_[((size_t)h*PEROWS + row)*DK + d] = f2b(v);
            }
        }
    }
}

// ---------------- fused QKV GEMM: q,k -> (b,h,t,d); v -> (b,h,d,t+128) margin layout ----------------
__global__ __launch_bounds__(256)
void gemm_qkv_kernel(const unsigned short* __restrict__ A, const unsigned short* __restrict__ Bt,
                     const float* __restrict__ bq, const float* __restrict__ bk, const float* __restrict__ bv,
                     unsigned short* __restrict__ qout, unsigned short* __restrict__ kout,
                     unsigned short* __restrict__ vout){
    __shared__ __align__(16) unsigned short sh[2*LDSZ2];
    int n0 = blockIdx.y*64;
    GEMM_PIPE64(A, Bt, n0, 2000)
    int sec = blockIdx.y / 12;            // 0=q 1=k 2=v
    int col0 = n0 - sec*768;
    int h = col0 >> 6;
    const float* bias = (sec==0) ? bq : (sec==1) ? bk : bv;
    float bfv_[4];
    #pragma unroll
    for (int ni=0;ni<4;++ni) bfv_[ni] = bias[col0 + 16*ni + l16];
    if (sec != 2){
        unsigned short* outp = (sec==0) ? qout : kout;
        #pragma unroll
        for (int rr=0;rr<4;++rr){
            int row = m0 + 16*wv + 4*quad + rr;
            if (row >= 2000) continue;
            int b = row / TT, tl = row - b*TT;
            #pragma unroll
            for (int ni=0;ni<4;++ni){
                int d = 16*ni + l16;
                outp[(((size_t)(b*HH + h))*TT + tl)*DK + d] = f2b(acc[ni][rr] + bfv_[ni]);
            }
        }
    } else {
        // V: acc tile -> LDS buf0 region (stride 66; last K-step used buf1 -> disjoint), then (d,t+128) store
        #pragma unroll
        for (int rr=0;rr<4;++rr){
            int rt = 16*wv + 4*quad + rr;
            #pragma unroll
            for (int ni=0;ni<4;++ni)
                sh[rt*66 + 16*ni + l16] = f2b(acc[ni][rr] + bfv_[ni]);
        }
        __syncthreads();
        #pragma unroll
        for (int it=0; it<16; ++it){
            int idx = it*256 + tid;                // 64*64 = 4096 = 16*256
            int d = idx >> 6, rt = idx & 63;
            int row = m0 + rt;
            if (row < 2000){
                int b = row / TT, tl = row - b*TT;
                vout[(((size_t)(b*HH + h))*DK + d)*VTP + tl + 128] = sh[rt*66 + d];
            }
        }
    }
}

// ---------------- MFMA banded rel-pos attention: 4 waves cooperate on one 16-row t-tile ----------------
__global__ __launch_bounds__(256)
void attn_kernel(const unsigned short* __restrict__ q, const unsigned short* __restrict__ k,
                 const unsigned short* __restrict__ vT, const unsigned short* __restrict__ pp,
                 const float* __restrict__ pbu, const float* __restrict__ pbv,
                 unsigned short* __restrict__ out){
    int b = blockIdx.y, h = HORD[blockIdx.z];
    int t0 = blockIdx.x * 16;
    int w2 = HALFW[h];
    int tid = threadIdx.x;
    int wv = tid >> 6, lane = tid & 63;
    int l16 = lane & 15, quad = lane >> 4;

    const unsigned short* qB = q  + ((size_t)(b*HH + h))*TT*DK;
    const unsigned short* kB = k  + ((size_t)(b*HH + h))*TT*DK;
    const unsigned short* vB = vT + ((size_t)(b*HH + h))*DK*VTP;
    const unsigned short* pB = pp + (size_t)h*PEROWS*DK;

    __shared__ __align__(16) float bd[16*260];
    __shared__ __align__(16) unsigned short pl[16*328];
    __shared__ float mxs[4][16];
    __shared__ float sms[4][16];

    int tq = t0 + l16; if (tq > TT-1) tq = TT-1;
    union { int4 i; unsigned short u[8]; } r0, r1;
    r0.i = *(const int4*)(qB + (size_t)tq*DK + quad*8);
    r1.i = *(const int4*)(qB + (size_t)tq*DK + 32 + quad*8);
    const float* pu = pbu + h*DK + quad*8;
    const float* pv = pbv + h*DK + quad*8;
    union { unsigned short u[8]; bf16x8 v; } qu0, qu1, qv0, qv1;
    #pragma unroll
    for (int i=0;i<8;++i){
        float a0 = b2f(r0.u[i]), a1 = b2f(r1.u[i]);
        qu0.u[i] = f2b(a0 + pu[i]);
        qu1.u[i] = f2b(a1 + pu[32+i]);
        qv0.u[i] = f2b(a0 + pv[i]);
        qv1.u[i] = f2b(a1 + pv[32+i]);
    }

    int Nn = 2*w2 + 1;
    int ntiles = (Nn + 15) >> 4;
    for (int ti = wv; ti < ntiles; ti += 4){
        int n = 127 - w2 + ti*16 + l16; if (n > PEROWS-1) n = PEROWS-1;
        const unsigned short* pr = pB + (size_t)n*DK + quad*8;
        bf16x8 pb0 = *(const bf16x8*)pr;
        bf16x8 pb1 = *(const bf16x8*)(pr + 32);
        floatx4 a = {0.f,0.f,0.f,0.f};
        a = __builtin_amdgcn_mfma_f32_16x16x32_bf16(qv0.v, pb0, a, 0,0,0);
        a = __builtin_amdgcn_mfma_f32_16x16x32_bf16(qv1.v, pb1, a, 0,0,0);
        #pragma unroll
        for (int r=0;r<4;++r) bd[(quad*4+r)*260 + ti*16 + l16] = a[r];
    }
    for (int i = tid; i < 16*328/4; i += 256)
        ((unsigned long long*)pl)[i] = 0ULL;
    __syncthreads();                                     // barrier 1

    int Ns = 2*w2 + 16;
    int stiles = (Ns + 15) >> 4;
    int s_lo = t0 - w2;
    float scv[5][4];
    float mx[4] = {-1e30f,-1e30f,-1e30f,-1e30f};
    #pragma unroll
    for (int ii = 0; ii < 5; ++ii){
        int ti = wv + ii*4;
        if (ti < stiles){
            int s = s_lo + ti*16 + l16;
            int sc = s < 0 ? 0 : (s > TT-1 ? TT-1 : s);
            const unsigned short* kr = kB + (size_t)sc*DK + quad*8;
            bf16x8 kb0 = *(const bf16x8*)kr;
            bf16x8 kb1 = *(const bf16x8*)(kr + 32);
            floatx4 a = {0.f,0.f,0.f,0.f};
            a = __builtin_amdgcn_mfma_f32_16x16x32_bf16(qu0.v, kb0, a, 0,0,0);
            a = __builtin_amdgcn_mfma_f32_16x16x32_bf16(qu1.v, kb1, a, 0,0,0);
            #pragma unroll
            for (int r=0;r<4;++r){
                int row = quad*4 + r;
                int nrel = ti*16 + l16 - row;
                bool ok = (nrel >= 0) && (nrel <= 2*w2) && (s >= 0) && (s <= TT-1);
                int idx = row*260 + nrel;
                idx = idx < 0 ? 0 : (idx > 16*260-1 ? 16*260-1 : idx);
                float bdv = bd[idx];
                float sc_ = ok ? (a[r] + bdv) * 0.125f : -1e30f;
                scv[ii][r] = sc_;
                mx[r] = fmaxf(mx[r], sc_);
            }
        } else {
            #pragma unroll
            for (int r=0;r<4;++r) scv[ii][r] = -1e30f;
        }
    }
    #pragma unroll
    for (int off=1; off<16; off<<=1){
        #pragma unroll
        for (int r=0;r<4;++r) mx[r] = fmaxf(mx[r], __shfl_xor(mx[r], off));
    }
    if (l16 == 0){
        #pragma unroll
        for (int r=0;r<4;++r) mxs[wv][quad*4+r] = mx[r];
    }
    __syncthreads();                                     // barrier 2
    float gmx[4];
    #pragma unroll
    for (int r=0;r<4;++r){
        int row = quad*4 + r;
        gmx[r] = fmaxf(fmaxf(mxs[0][row], mxs[1][row]), fmaxf(mxs[2][row], mxs[3][row]));
    }

    int s0a = s_lo & ~31;
    int pad_lo = s_lo - s0a;
    int ktiles = (pad_lo + Ns + 31) >> 5;

    float sm[4] = {0.f,0.f,0.f,0.f};
    #pragma unroll
    for (int ii = 0; ii < 5; ++ii){
        int ti = wv + ii*4;
        if (ti < stiles){
            #pragma unroll
            for (int r=0;r<4;++r){
                float e = __expf(scv[ii][r] - gmx[r]);
                sm[r] += e;
                pl[(quad*4+r)*328 + pad_lo + ti*16 + l16] = f2b(e);
            }
        }
    }
    #pragma unroll
    for (int off=1; off<16; off<<=1){
        #pragma unroll
        for (int r=0;r<4;++r) sm[r] += __shfl_xor(sm[r], off);
    }
    if (l16 == 0){
        #pragma unroll
        for (int r=0;r<4;++r) sms[wv][quad*4+r] = sm[r];
    }
    __syncthreads();                                     // barrier 3

    floatx4 oacc = {0.f,0.f,0.f,0.f};
    for (int kt = 0; kt < ktiles; ++kt){
        bf16x8 pa = *(const bf16x8*)&pl[l16*328 + kt*32 + quad*8];
        int sidx = s0a + kt*32 + quad*8 + 128;
        bf16x8 vb = *(const bf16x8*)(vB + (size_t)(wv*16 + l16)*VTP + sidx);
        oacc = __builtin_amdgcn_mfma_f32_16x16x32_bf16(pa, vb, oacc, 0,0,0);
    }
    #pragma unroll
    for (int r=0;r<4;++r){
        int row = quad*4 + r;
        float sum = sms[0][row] + sms[1][row] + sms[2][row] + sms[3][row];
        float rinv = sum > 0.f ? 1.0f/sum : 0.0f;
        int t = t0 + row;
        if (t <= TT-1)
            out[(((size_t)(b*TT + t))*HH + h)*DK + wv*16 + l16] = f2b(oacc[r] * rinv);
    }
}

// ---------------- launcher ----------------
extern "C" void kernel_launch(void* const* d_in, const int* in_sizes, int n_in,
                              void* d_out, int out_size, void* d_ws, size_t ws_size,
                              hipStream_t stream){
    const float* x    = (const float*)d_in[0];
    const float* ln1g = (const float*)d_in[2];
    const float* ln1b = (const float*)d_in[3];
    const float* wq   = (const float*)d_in[4];
    const float* bq   = (const float*)d_in[5];
    const float* wk   = (const float*)d_in[6];
    const float* bk   = (const float*)d_in[7];
    const float* wvv  = (const float*)d_in[8];
    const float* bv   = (const float*)d_in[9];
    const float* wo   = (const float*)d_in[10];
    const float* bo   = (const float*)d_in[11];
    const float* wpos = (const float*)d_in[12];
    const float* pbu  = (const float*)d_in[13];
    const float* pbv  = (const float*)d_in[14];
    const float* ln2g = (const float*)d_in[15];
    const float* ln2b = (const float*)d_in[16];
    const float* w1   = (const float*)d_in[17];
    const float* b1   = (const float*)d_in[18];
    const float* w2   = (const float*)d_in[19];
    const float* b2   = (const float*)d_in[20];

    const int NTOK = BB*TT;            // 2000

    float* x_cur = (float*)d_out;      // residual in d_out (fp32)

    // ws layout — total 30,936,576 B
    char* ws = (char*)d_ws;
    unsigned short* qbuf  = (unsigned short*)(ws);              // (b,h,t,d) q / mlp hidden
    unsigned short* kbuf  = (unsigned short*)(ws + 3072000);    // (b,h,t,d)
    unsigned short* vTbuf = (unsigned short*)(ws + 6144000);    // (b,h,d,t+128) 4,030,464 B
    unsigned short* hbuf  = (unsigned short*)(ws + 10174464);   // ln out / attn out
    unsigned short* ppbuf = (unsigned short*)(ws + 13246464);   // (l,h,n,d) 783,360 B
    unsigned short* pebuf = (unsigned short*)(ws + 14029824);   // 391,680 B
    unsigned short* wtbuf = (unsigned short*)(ws + 14421504);   // 14 * 1,179,648 B
    #define WT(t_,l_) (wtbuf + (size_t)((l_)*7 + (t_))*WELEM)

    dim3 blk(256);
    // merged preamble: wconv (z<14) + scale (z=14) + pe (z=15)
    prep_kernel<<<dim3(12,12,16), blk, 0, stream>>>(wq, wk, wvv, wo, wpos, w1, w2,
                                                    wtbuf, x, x_cur, pebuf);
    // both layers' pos projections in one dispatch (z = layer)
    gemm_kernel<3><<<dim3(4,12,2), blk, 0, stream>>>(pebuf, WT(4,0), nullptr, ppbuf, nullptr, PEROWS);

    dim3 gBig(32, 12);                 // 64x64 tiles
    dim3 gQKV(32, 36);
    dim3 gAttn(63, BB, HH);

    for (int l = 0; l < LL; ++l){
        long dl = (long)l*DD;
        long pl_ = (long)l*HH*DK;

        ln_kernel<<<NTOK, blk, 0, stream>>>(x_cur, ln1g + dl, ln1b + dl, hbuf);
        gemm_qkv_kernel<<<gQKV, blk, 0, stream>>>(hbuf, WT(0,l), bq + dl, bk + dl, bv + dl,
                                                  qbuf, kbuf, vTbuf);

        attn_kernel<<<gAttn, blk, 0, stream>>>(qbuf, kbuf, vTbuf, ppbuf + (size_t)l*PPL,
                                               pbu + pl_, pbv + pl_, hbuf);

        gemm_kernel<2><<<gBig, blk, 0, stream>>>(hbuf, WT(3,l), bo + dl, nullptr, x_cur, NTOK);

        ln_kernel<<<NTOK, blk, 0, stream>>>(x_cur, ln2g + dl, ln2b + dl, hbuf);
        gemm_kernel<1><<<gBig, blk, 0, stream>>>(hbuf, WT(5,l), b1 + dl, qbuf, nullptr, NTOK);
        gemm_kernel<2><<<gBig, blk, 0, stream>>>(qbuf, WT(6,l), b2 + dl, nullptr, x_cur, NTOK);
    }
}